// Round 10
// baseline (518.120 us; speedup 1.0000x reference)
//
#include <hip/hip_runtime.h>
#include <cstdint>
#include <cstddef>

// ---------- types / helpers ----------
typedef __bf16 bf16x8 __attribute__((ext_vector_type(8)));
typedef float  floatx4 __attribute__((ext_vector_type(4)));
typedef float  floatx2 __attribute__((ext_vector_type(2)));
typedef float  floatx16 __attribute__((ext_vector_type(16)));
typedef int    intx4v __attribute__((ext_vector_type(4)));
typedef int    intx8 __attribute__((ext_vector_type(8)));
typedef unsigned short ushort8 __attribute__((ext_vector_type(8)));
typedef unsigned short ushort4v __attribute__((ext_vector_type(4)));

__device__ __forceinline__ float bflo(unsigned int u) {
    union { unsigned int u32; float f; } x; x.u32 = u << 16; return x.f;
}
__device__ __forceinline__ float bfhi(unsigned int u) {
    union { unsigned int u32; float f; } x; x.u32 = u & 0xffff0000u; return x.f;
}
__device__ __forceinline__ unsigned short f2bf(float f) {
    union { float f; unsigned int u; } x; x.f = f;
    unsigned int u = x.u;
    unsigned int r = (u + 0x7fffu + ((u >> 16) & 1u)) >> 16;   // RNE
    return (unsigned short)r;
}
__device__ __forceinline__ unsigned char f2fp8(float f) {
    unsigned int pk = __builtin_amdgcn_cvt_pk_fp8_f32(f, f, 0, false);
    return (unsigned char)(pk & 0xff);
}
// decode 4 fp8(e4m3) packed in u32 -> 4 floats
__device__ __forceinline__ void fp8x4_dec(unsigned int u, float* f) {
    floatx2 lo = __builtin_amdgcn_cvt_pk_f32_fp8(u, false);
    floatx2 hi = __builtin_amdgcn_cvt_pk_f32_fp8(u, true);
    f[0] = lo[0]; f[1] = lo[1]; f[2] = hi[0]; f[3] = hi[1];
}

#define GLOBAL_U32 const __attribute__((address_space(1))) unsigned int*
#define LDS_U32 __attribute__((address_space(3))) unsigned int*
__device__ __forceinline__ void async_cp16(const void* g, void* l) {
    __builtin_amdgcn_global_load_lds((GLOBAL_U32)g, (LDS_U32)l, 16, 0, 0);
}

#define UHAT_SCALE 64.0f
#define UHAT_INV   (1.0f / 64.0f)
#define W2_SCALE   16.0f
#define W2_INV     (1.0f / 16.0f)

// ---------- prep: conv1 (blocks 0..1023, oh-split x4) + w2t fp8 (1024..1535) + S012 zero ----------
__global__ __launch_bounds__(256) void prep_k(const float* __restrict__ x,
                                              const float* __restrict__ w1c,
                                              const float* __restrict__ b1c,
                                              const float* __restrict__ w2,
                                              unsigned char* __restrict__ h1t8,
                                              unsigned char* __restrict__ w2t8,
                                              float* __restrict__ S012) {
    const int blk = blockIdx.x, t = threadIdx.x;
    // zero routing accumulators: 122880 floats = 1536 blocks x 80
    if (t < 80) S012[blk * 80 + t] = 0.f;
    __shared__ float shm[10368];
    if (blk < 1024) {
        // conv1 (oh-split x4): x[256,1,28,28]*w[256,1,9,9] -> h1t8 fp8 [b][20][20][256]
        const int b = blk >> 2, hh = blk & 3;
        const int oh0 = hh * 5;
        for (int idx = t; idx < 364; idx += 256) shm[idx] = x[b * 784 + oh0 * 28 + idx];
        __syncthreads();
        const float* wr = w1c + t * 81;               // thread t = output channel t
        const float bv = b1c[t];
        for (int ohl = 0; ohl < 5; ++ohl) {
            float acc[20];
#pragma unroll
            for (int ow = 0; ow < 20; ++ow) acc[ow] = bv;
#pragma unroll
            for (int kh = 0; kh < 9; ++kh) {
                float xr[28];
                const float* xrow = &shm[(ohl + kh) * 28];
#pragma unroll
                for (int q = 0; q < 7; ++q) *(float4*)&xr[q * 4] = *(const float4*)&xrow[q * 4];
#pragma unroll
                for (int kw = 0; kw < 9; ++kw) {
                    const float wv = wr[kh * 9 + kw];
#pragma unroll
                    for (int ow = 0; ow < 20; ++ow) acc[ow] = fmaf(xr[ow + kw], wv, acc[ow]);
                }
            }
            unsigned char* orow = h1t8 + (size_t)((b * 20 + oh0 + ohl) * 20) * 256 + t;
#pragma unroll
            for (int ow = 0; ow < 20; ++ow) orow[ow * 256] = f2fp8(acc[ow]);
        }
    } else {
        // w2 transform: OIHW fp32 [oc][ic][81] -> fp8 [oc][tap*256+ic], x16 scale
        const int id = blk - 1024;
        const int oc = id >> 1, half = id & 1;
        const float* src = w2 + (size_t)oc * 20736 + half * 128 * 81;
        for (int idx = t; idx < 10368; idx += 256) shm[idx] = src[idx];
        __syncthreads();
        unsigned char* dst = w2t8 + (size_t)oc * 20736 + half * 128;
        for (int idx = t; idx < 10368; idx += 256) {
            const int tap = idx >> 7, icl = idx & 127;
            dst[tap * 256 + icl] = f2fp8(shm[icl * 81 + tap] * W2_SCALE);
        }
    }
}

// ---------- conv2 implicit GEMM, MX-scaled fp8 MFMA, ZERO-LDS ----------
// v4: within a block every staged byte was single-use -> LDS was a pure relay.
// Each lane loads its fragment slices (2x16B per row per K-step) DIRECTLY from
// L2-resident h1t8/w2t8. No barriers in the K-loop -> compiler pipelines loads
// freely across chunks. Tile 128M x 128OC, split-K x4, 576 blocks (round-4 map).
// Same bytes, same MFMA order as the LDS version -> bit-identical outputs.
__device__ __forceinline__ int c2_rowbase(int m) {
    const int b = m / 36, sp = m % 36;
    const int oh = sp / 6, ow = sp % 6;
    return (b * 400 + oh * 40 + ow * 2) * 256;        // byte offset into h1t8 (1 B/elem)
}

__global__ __launch_bounds__(256, 3) void conv2_k(const unsigned char* __restrict__ h1t8,
                                                  const unsigned char* __restrict__ w2t8,
                                                  unsigned short* __restrict__ part) {
    const int t = threadIdx.x;
    // 576 ids: 2 bx-siblings of one (by,z) sit 8 apart (same XCD) -> A-slice L2-shared.
    const int id = blockIdx.x;                        // 0..575
    const int G = id >> 4;                            // 0..35
    const int bx = (id >> 3) & 1;                     // 0..1 (128-oc tile)
    const int s = id & 7;
    const int by = 2 * G + (s >> 2);                  // 0..71
    const int z  = ((s & 3) + by) & 3;                // 0..3
    const int oc0 = bx * 128;

    const int lane = t & 63, l31 = lane & 31, h = lane >> 5;
    const int wave = t >> 6;
    const int wM = (wave & 1) * 64, wOC = (wave >> 1) * 64;

    // per-lane row base pointers (h*32 folds the lane-half k-offset into the base)
    const unsigned char* aRow0 = w2t8 + (size_t)(oc0 + wOC + l31) * 20736 + h * 32;
    const unsigned char* aRow1 = w2t8 + (size_t)(oc0 + wOC + 32 + l31) * 20736 + h * 32;
    const unsigned char* bRow0 = h1t8 + c2_rowbase(by * 128 + wM + l31) + h * 32;
    const unsigned char* bRow1 = h1t8 + c2_rowbase(by * 128 + wM + 32 + l31) + h * 32;

    floatx16 acc[2][2];                               // [oc-tile i][m-tile j]
#pragma unroll
    for (int i = 0; i < 2; ++i)
#pragma unroll
        for (int j = 0; j < 2; ++j)
#pragma unroll
            for (int r = 0; r < 16; ++r) acc[i][j][r] = 0.f;

    // K = 162 chunks of 128; split 4 ways: 40/41/40/41
    const int q0 = (162 * z) >> 2, q1 = (162 * (z + 1)) >> 2;
    for (int q = q0; q < q1; ++q) {
        const int tap = q >> 1;                       // BK=128 = half a tap; never crosses
        const int kh = tap / 9, kw = tap - 9 * kh;
        const int offB = (kh * 20 + kw) * 256 + (q & 1) * 128;   // within-m-row (h1t8)
        const int offA = q * 128;                                 // within-oc-row (w2t8)
        // load all 16 x 16B fragment slices of this chunk (no LDS, no barriers)
        intx4v av[2][2][2], bv[2][2][2];              // [tile][st][p]
#pragma unroll
        for (int st = 0; st < 2; ++st)
#pragma unroll
            for (int p = 0; p < 2; ++p) {
                const int d = st * 64 + p * 16;
                av[0][st][p] = *(const intx4v*)(aRow0 + offA + d);
                av[1][st][p] = *(const intx4v*)(aRow1 + offA + d);
                bv[0][st][p] = *(const intx4v*)(bRow0 + offB + d);
                bv[1][st][p] = *(const intx4v*)(bRow1 + offB + d);
            }
#pragma unroll
        for (int st = 0; st < 2; ++st) {
            intx8 aF[2], bF[2];
#pragma unroll
            for (int i = 0; i < 2; ++i) {
                aF[i] = (intx8){av[i][st][0][0], av[i][st][0][1], av[i][st][0][2], av[i][st][0][3],
                                av[i][st][1][0], av[i][st][1][1], av[i][st][1][2], av[i][st][1][3]};
                bF[i] = (intx8){bv[i][st][0][0], bv[i][st][0][1], bv[i][st][0][2], bv[i][st][0][3],
                                bv[i][st][1][0], bv[i][st][1][1], bv[i][st][1][2], bv[i][st][1][3]};
            }
#pragma unroll
            for (int i = 0; i < 2; ++i)
#pragma unroll
                for (int j = 0; j < 2; ++j)
                    acc[i][j] = __builtin_amdgcn_mfma_scale_f32_32x32x64_f8f6f4(
                        aF[i], bF[j], acc[i][j], 0, 0, 0, 127, 0, 127);
        }
    }

    // epilogue: D col(lane&31)=m, row=(reg&3)+8*(reg>>2)+4*h = oc; undo W2 scale
    unsigned short* pz = part + (size_t)z * 2359296;
#pragma unroll
    for (int i = 0; i < 2; ++i) {
#pragma unroll
        for (int j = 0; j < 2; ++j) {
            const int m = by * 128 + wM + j * 32 + l31;
#pragma unroll
            for (int rg = 0; rg < 4; ++rg) {
                const int oc = oc0 + wOC + i * 32 + rg * 8 + 4 * h;
                ushort4v pk;
#pragma unroll
                for (int rr = 0; rr < 4; ++rr) pk[rr] = f2bf(acc[i][j][rg * 4 + rr] * W2_INV);
                *(ushort4v*)(pz + (size_t)m * 256 + oc) = pk;
            }
        }
    }
}

// ---------- reduce split-K(bf16 x4) + bias + squash(axis=w) -> u[b][1152][8] (half-split x2) ----------
__global__ __launch_bounds__(256) void squash_u_k(const unsigned short* __restrict__ part,
                                                  const float* __restrict__ bias,
                                                  float* __restrict__ u) {
    const int bb = blockIdx.x, t = threadIdx.x;
    const int b = bb >> 1, h = bb & 1;
    __shared__ float hs[4608];
    const size_t base = (size_t)b * 9216 + h * 4608;
    for (int q = t; q < 2304; q += 256) {
        const int idx = q * 2;
        float v0 = bias[idx & 255], v1 = bias[(idx + 1) & 255];
#pragma unroll
        for (int z = 0; z < 4; ++z) {
            const unsigned int uu = *(const unsigned int*)(part + (size_t)z * 2359296 + base + idx);
            v0 += bflo(uu);
            v1 += bfhi(uu);
        }
        hs[idx] = v0; hs[idx + 1] = v1;
    }
    __syncthreads();
    for (int gq = t; gq < 768; gq += 256) {           // groups (c, oh-local), squash over ow(6)
        const int c = gq / 3, ohl = gq % 3;
        const int oh = h * 3 + ohl;
        float s[6], sq = 0.f;
#pragma unroll
        for (int ow = 0; ow < 6; ++ow) { s[ow] = hs[(ohl * 6 + ow) * 256 + c]; sq = fmaf(s[ow], s[ow], sq); }
        const float norm = sqrtf(sq);
        const float f = (sq / (1.0f + sq)) / (norm + 1e-7f);
        float* up = u + (size_t)b * 9216 + c * 36 + oh * 6;
#pragma unroll
        for (int ow = 0; ow < 6; ++ow) up[ow] = s[ow] * f;
    }
}

// ---------- u_hat fp8: uhat8[i][b][40 u32] = e4m3(64 * W_i u_b) ----------
__global__ __launch_bounds__(256) void uhat_k(const float* __restrict__ Wc,
                                              const float* __restrict__ u,
                                              unsigned int* __restrict__ uhat8) {
    const int i = blockIdx.x, t = threadIdx.x;       // t = b
    __shared__ float Wl[1280];                       // [o][d*8+e]
    for (int idx = t; idx < 1280; idx += 256) {
        const int o = idx >> 7, r = idx & 127;
        Wl[idx] = Wc[((size_t)o * 1152 + i) * 128 + r];
    }
    float ur[8];
    *(float4*)&ur[0] = *(const float4*)(u + (size_t)t * 9216 + i * 8);
    *(float4*)&ur[4] = *(const float4*)(u + (size_t)t * 9216 + i * 8 + 4);
    __syncthreads();
    unsigned int* row = uhat8 + ((size_t)i * 256 + t) * 40;
#pragma unroll 1
    for (int o = 0; o < 10; ++o) {
        float vals[16];
#pragma unroll
        for (int d = 0; d < 16; ++d) {
            const float* wp = &Wl[o * 128 + d * 8];
            float a = 0.f;
#pragma unroll
            for (int e = 0; e < 8; ++e) a = fmaf(wp[e], ur[e], a);
            vals[d] = a * UHAT_SCALE;
        }
        uint4 pk;
        unsigned int w;
#pragma unroll
        for (int q = 0; q < 4; ++q) {
            w = 0;
            w = __builtin_amdgcn_cvt_pk_fp8_f32(vals[q * 4 + 0], vals[q * 4 + 1], w, false);
            w = __builtin_amdgcn_cvt_pk_fp8_f32(vals[q * 4 + 2], vals[q * 4 + 3], w, true);
            if (q == 0) pk.x = w; else if (q == 1) pk.y = w; else if (q == 2) pk.z = w; else pk.w = w;
        }
        *(uint4*)(row + o * 4) = pk;
    }
}

// ---------- routing iteration 0: S0[b][160] = 0.1 * sum_i u_hat ----------
__global__ __launch_bounds__(256) void route_iter0_k(const unsigned int* __restrict__ uhat8,
                                                     float* __restrict__ S0) {
    const int b = blockIdx.x, i0 = blockIdx.y * 128, t = threadIdx.x;
    const int th = t & 127, hi = t >> 7;
    if (th >= 40) return;                             // th = od-quad
    const unsigned int* p = uhat8 + ((size_t)(i0 + hi * 64) * 256 + b) * 40 + th;
    float a0 = 0.f, a1 = 0.f, a2 = 0.f, a3 = 0.f;
#pragma unroll 4
    for (int i = 0; i < 64; ++i) {
        float f[4];
        fp8x4_dec(p[(size_t)i * 10240], f);
        a0 += f[0]; a1 += f[1]; a2 += f[2]; a3 += f[3];
    }
    const float sc = 0.1f * UHAT_INV;
    atomicAdd(&S0[b * 160 + 4 * th + 0], sc * a0);
    atomicAdd(&S0[b * 160 + 4 * th + 1], sc * a1);
    atomicAdd(&S0[b * 160 + 4 * th + 2], sc * a2);
    atomicAdd(&S0[b * 160 + 4 * th + 3], sc * a3);
}

// ---------- fused routing iteration: squash(S_in) + logit update + softmax + weighted sum ----------
template <int ITER>
__global__ __launch_bounds__(256) void route_iter_k(const unsigned int* __restrict__ uhat8,
                                                    const float* __restrict__ S_in,
                                                    float* __restrict__ BL,
                                                    float* __restrict__ S_out) {
    const int b = blockIdx.x, i0 = blockIdx.y * 128, t = threadIdx.x;
    __shared__ __align__(16) unsigned int Ul8[128 * 40];     // 20480 B, [i_local][40 u32]
    __shared__ float Vl[160];
    __shared__ float cT[10 * 132];
    __shared__ float dots[128 * 10];

    // stage slab (i0..i0+127, b): rows of 160 B at 40960 B stride; 1280 16B units.
    const unsigned int* ub = uhat8 + ((size_t)i0 * 256 + b) * 40;
#pragma unroll
    for (int rep = 0; rep < 5; ++rep) {
        const int c = rep * 256 + t;
        const int row = c / 10, q = c - row * 10;
        async_cp16(ub + (size_t)row * 10240 + q * 4, (char*)Ul8 + c * 16);
    }

    // phase 0: squash S_in -> Vl (redundant per block; 160 floats)
    if (t < 160) {
        const float x = S_in[b * 160 + t];
        float sq = x * x;
        sq += __shfl_xor(sq, 1, 16);
        sq += __shfl_xor(sq, 2, 16);
        sq += __shfl_xor(sq, 4, 16);
        sq += __shfl_xor(sq, 8, 16);
        const float norm = sqrtf(sq);
        const float f = (sq / (1.f + sq)) / (norm + 1e-7f);
        Vl[t] = x * f;
    }
    __syncthreads();                                  // drains async + Vl visible

    // p1a mapping: o = t%10 fixed per thread, strip s = t/10 (250 active)
    const int o = t % 10, s = t / 10;
    float vr[16];
    if (t < 250) {
#pragma unroll
        for (int q = 0; q < 4; ++q)
            *(float4*)&vr[q * 4] = *(const float4*)(&Vl[o * 16 + q * 4]);
    }

    // p1a: dots[i][o] = (1/64) * sum_d uq[i,o,d] * v[o,d]
    if (t < 250) {
#pragma unroll
        for (int rep = 0; rep < 6; ++rep) {
            const int i = s + 25 * rep;
            if (i < 128) {
                const uint4 uu = *(const uint4*)(Ul8 + i * 40 + o * 4);
                float f[16];
                fp8x4_dec(uu.x, f);
                fp8x4_dec(uu.y, f + 4);
                fp8x4_dec(uu.z, f + 8);
                fp8x4_dec(uu.w, f + 12);
                float dot = 0.f;
#pragma unroll
                for (int d = 0; d < 16; ++d) dot = fmaf(f[d], vr[d], dot);
                dots[i * 10 + o] = dot * UHAT_INV;
            }
        }
    }
    __syncthreads();

    // p1b: per-i logits + softmax -> cT[o][i]
    if (t < 128) {
        float bl[10];
#pragma unroll
        for (int oo = 0; oo < 10; ++oo) bl[oo] = dots[t * 10 + oo];
        if (ITER == 2) {
#pragma unroll
            for (int oo = 0; oo < 10; ++oo) bl[oo] += BL[(size_t)b * 11520 + oo * 1152 + i0 + t];
        } else {
#pragma unroll
            for (int oo = 0; oo < 10; ++oo) BL[(size_t)b * 11520 + oo * 1152 + i0 + t] = bl[oo];
        }
        float mx = bl[0];
#pragma unroll
        for (int oo = 1; oo < 10; ++oo) mx = fmaxf(mx, bl[oo]);
        float ex[10], sum = 0.f;
#pragma unroll
        for (int oo = 0; oo < 10; ++oo) { ex[oo] = expf(bl[oo] - mx); sum += ex[oo]; }
        const float inv = 1.f / sum;
#pragma unroll
        for (int oo = 0; oo < 10; ++oo) cT[oo * 132 + t] = ex[oo] * inv;
    }
    __syncthreads();

    // p2: S_out[b][160] += (1/64) * sum_i c[i][o] * uq[i][od]  (two 64-i halves)
    const int th = t & 127, hi = t >> 7;
    if (th < 40) {                                    // th = od-quad, o = th>>2
        const int oq = th >> 2;
        const unsigned int* base = Ul8 + hi * 64 * 40 + th;
        const float* cb = &cT[oq * 132 + hi * 64];
        float a0 = 0.f, a1 = 0.f, a2 = 0.f, a3 = 0.f;
#pragma unroll 4
        for (int ii = 0; ii < 64; ++ii) {
            const float c = cb[ii];
            float f[4];
            fp8x4_dec(base[ii * 40], f);
            a0 = fmaf(c, f[0], a0);
            a1 = fmaf(c, f[1], a1);
            a2 = fmaf(c, f[2], a2);
            a3 = fmaf(c, f[3], a3);
        }
        atomicAdd(&S_out[b * 160 + 4 * th + 0], a0 * UHAT_INV);
        atomicAdd(&S_out[b * 160 + 4 * th + 1], a1 * UHAT_INV);
        atomicAdd(&S_out[b * 160 + 4 * th + 2], a2 * UHAT_INV);
        atomicAdd(&S_out[b * 160 + 4 * th + 3], a3 * UHAT_INV);
    }
}

// ---------- final: squash S2 -> lengths, argmax + fused decoder layer 1 ----------
__global__ __launch_bounds__(512) void final_k(const float* __restrict__ S,
                                               const float* __restrict__ w1,
                                               const float* __restrict__ b1,
                                               float* __restrict__ out_len,
                                               float* __restrict__ h1d) {
    const int b = blockIdx.x, t = threadIdx.x;
    __shared__ float v_s[160];
    __shared__ float len_s[10];
    __shared__ int sel_s;
    if (t < 160) {
        const float x = S[b * 160 + t];
        float sq = x * x;
        sq += __shfl_xor(sq, 1, 16);
        sq += __shfl_xor(sq, 2, 16);
        sq += __shfl_xor(sq, 4, 16);
        sq += __shfl_xor(sq, 8, 16);
        const float norm = sqrtf(sq);
        const float f = (sq / (1.f + sq)) / (norm + 1e-7f);
        v_s[t] = x * f;
        if ((t & 15) == 0) {
            const float len = f * norm;
            len_s[t >> 4] = len;
            out_len[b * 10 + (t >> 4)] = len;
        }
    }
    __syncthreads();
    if (t == 0) {
        float best = len_s[0]; int bi = 0;
        for (int oo = 1; oo < 10; ++oo) if (len_s[oo] > best) { best = len_s[oo]; bi = oo; }
        sel_s = bi;
    }
    __syncthreads();
    const int s = sel_s;
    float acc = b1[t];
    const float* wrow = w1 + (size_t)(s * 16) * 512 + t;
#pragma unroll
    for (int j = 0; j < 16; ++j) acc = fmaf(v_s[s * 16 + j], wrow[j * 512], acc);
    h1d[(size_t)b * 512 + t] = fmaxf(acc, 0.f);
}

// ---------- decoder GEMM v3: 8m x 64n tile, per-wave K-split x4, ping-pong float4 B batches ----------
template <int ACT>
__global__ __launch_bounds__(256) void mlp3_k(const float* __restrict__ A,
                                              const float* __restrict__ Bm,
                                              const float* __restrict__ bias,
                                              float* __restrict__ C, int N, int K) {
    extern __shared__ float Asm[];                    // 8*(K+4) floats; tail-reused for reduce
    const int t = threadIdx.x;
    const int m0 = blockIdx.y * 8, n0 = blockIdx.x * 64;
    const int RS = K + 4;
    const int k4 = K >> 2;
    for (int i = t; i < 8 * k4; i += 256) {           // stage A tile, float4 units
        const int r = i / k4, c = i - r * k4;
        *(float4*)&Asm[r * RS + c * 4] = *(const float4*)&A[(size_t)(m0 + r) * K + c * 4];
    }
    __syncthreads();
    const int lane = t & 63, w = t >> 6;
    const int mq = lane >> 4, nq = lane & 15;
    const int n = n0 + nq * 4;
    const int ncl = (n + 3 < N) ? n : (N - 4);        // clamp base col (16B-aligned, safe)
    const float* bp = Bm + ncl;
    const float* asA = &Asm[(mq * 2 + 0) * RS];
    const float* asB = &Asm[(mq * 2 + 1) * RS];
    const int kQ = K >> 2;                            // per-wave chunk (128 or 256)
    const int kBeg = w * kQ;
    const int nBat2 = kQ >> 4;                        // double-batches of 16 k
    float4 acc0 = {0.f, 0.f, 0.f, 0.f}, acc1 = {0.f, 0.f, 0.f, 0.f};
    float4 ba[8], bb[8];
#pragma unroll
    for (int d = 0; d < 8; ++d) ba[d] = *(const float4*)&bp[(size_t)(kBeg + d) * N];

#define MLP3_FMA(BATCH, KB)                                                       \
    _Pragma("unroll")                                                             \
    for (int d = 0; d < 8; ++d) {                                                 \
        const float4 b = BATCH[d];                                                \
        const float a0 = asA[(KB) + d];                                           \
        const float a1 = asB[(KB) + d];                                           \
        acc0.x = fmaf(a0, b.x, acc0.x); acc0.y = fmaf(a0, b.y, acc0.y);           \
        acc0.z = fmaf(a0, b.z, acc0.z); acc0.w = fmaf(a0, b.w, acc0.w);           \
        acc1.x = fmaf(a1, b.x, acc1.x); acc1.y = fmaf(a1, b.y, acc1.y);           \
        acc1.z = fmaf(a1, b.z, acc1.z); acc1.w = fmaf(a1, b.w, acc1.w);           \
    }

    int k = kBeg;
#pragma unroll 1
    for (int it = 0; it < nBat2; ++it) {
#pragma unroll
        for (int d = 0; d < 8; ++d) bb[d] = *(const float4*)&bp[(size_t)(k + 8 + d) * N];
        MLP3_FMA(ba, k)
        if (it + 1 < nBat2) {
#pragma unroll
            for (int d = 0; d < 8; ++d) ba[d] = *(const float4*)&bp[(size_t)(k + 16 + d) * N];
        }
        MLP3_FMA(bb, k + 8)
        k += 16;
    }
#undef MLP3_FMA

    // cross-wave k-quarter reduce via LDS (reuses Asm; 4*64*8 floats = 8 KB)
    __syncthreads();                                  // all waves done reading Asm
    float* red = Asm;
    float* my = &red[(size_t)(w * 64 + lane) * 8];
    my[0] = acc0.x; my[1] = acc0.y; my[2] = acc0.z; my[3] = acc0.w;
    my[4] = acc1.x; my[5] = acc1.y; my[6] = acc1.z; my[7] = acc1.w;
    __syncthreads();
    if (t < 64) {
        float o[8];
#pragma unroll
        for (int x = 0; x < 8; ++x)
            o[x] = red[(size_t)t * 8 + x] + red[(size_t)(64 + t) * 8 + x]
                 + red[(size_t)(128 + t) * 8 + x] + red[(size_t)(192 + t) * 8 + x];
        const int nn = n0 + (t & 15) * 4;
#pragma unroll
        for (int rm = 0; rm < 2; ++rm) {
            const int m = m0 + (t >> 4) * 2 + rm;
#pragma unroll
            for (int rn = 0; rn < 4; ++rn) {
                const int ncol = nn + rn;
                if (ncol < N) {
                    float v = o[rm * 4 + rn] + bias[ncol];
                    if (ACT == 0) v = fmaxf(v, 0.f);
                    else v = 1.f / (1.f + expf(-v));
                    C[(size_t)m * N + ncol] = v;
                }
            }
        }
    }
}

// ---------- launcher ----------
extern "C" void kernel_launch(void* const* d_in, const int* in_sizes, int n_in,
                              void* d_out, int out_size, void* d_ws, size_t ws_size,
                              hipStream_t stream) {
    const float* x   = (const float*)d_in[0];
    const float* w1  = (const float*)d_in[1];
    const float* b1  = (const float*)d_in[2];
    const float* w2  = (const float*)d_in[3];
    const float* b2  = (const float*)d_in[4];
    const float* Wc  = (const float*)d_in[5];
    const float* dw1 = (const float*)d_in[6];
    const float* db1 = (const float*)d_in[7];
    const float* dw2 = (const float*)d_in[8];
    const float* db2 = (const float*)d_in[9];
    const float* dw3 = (const float*)d_in[10];
    const float* db3 = (const float*)d_in[11];
    float* out = (float*)d_out;

    // workspace layout (round-4 style, lifetimes stream-serial):
    char* ws = (char*)d_ws;
    unsigned char* H1T8 = (unsigned char*)(ws + 0);            // 26,214,400 B fp8
    unsigned char* W2T8 = (unsigned char*)(ws + 26214400);     //  5,308,416 B fp8 (x16)
    unsigned short* PART = (unsigned short*)(ws + 31522816);   // 18,874,368 B bf16, z=4
    unsigned int*   UHAT = (unsigned int*)(ws + 0);            // 47,185,920 B fp8 (aliases dead staging)
    float* U    = (float*)(ws + 50397184);                     //  9,437,184 B (after PART; dead after uhat_k)
    float* BL   = (float*)(ws + 59834368);                     // 11,796,480 B (live iter1->iter2)
    float* S012 = (float*)(ws + 71630848);                     //    491,520 B (zeroed by prep_k)
    float* H1D  = (float*)(ws + 59834368);                     //    524,288 B (dead-BL space, after iter2)
    float* H2D  = (float*)(ws + 60358656);                     //  1,048,576 B

    float* S0 = S012, *S1 = S012 + 40960, *S2 = S012 + 81920;

    prep_k<<<1536, 256, 0, stream>>>(x, w1, b1, w2, H1T8, W2T8, S012);
    conv2_k<<<576, 256, 0, stream>>>(H1T8, W2T8, PART);
    squash_u_k<<<512, 256, 0, stream>>>(PART, b2, U);
    uhat_k<<<1152, 256, 0, stream>>>(Wc, U, UHAT);
    route_iter0_k<<<dim3(256, 9), 256, 0, stream>>>(UHAT, S0);
    route_iter_k<1><<<dim3(256, 9), 256, 0, stream>>>(UHAT, S0, BL, S1);
    route_iter_k<2><<<dim3(256, 9), 256, 0, stream>>>(UHAT, S1, BL, S2);
    final_k<<<256, 512, 0, stream>>>(S2, dw1, db1, out, H1D);
    mlp3_k<0><<<dim3(16, 32), 256, 8 * 516 * 4, stream>>>(H1D, dw2, db2, H2D, 1024, 512);
    mlp3_k<1><<<dim3(13, 32), 256, 8 * 1028 * 4, stream>>>(H2D, dw3, db3, out + 2560, 784, 1024);
}

// Round 11
// 350.474 us; speedup vs baseline: 1.4783x; 1.4783x over previous
//
#include <hip/hip_runtime.h>
#include <cstdint>
#include <cstddef>

// ---------- types / helpers ----------
typedef __bf16 bf16x8 __attribute__((ext_vector_type(8)));
typedef float  floatx4 __attribute__((ext_vector_type(4)));
typedef float  floatx2 __attribute__((ext_vector_type(2)));
typedef float  floatx16 __attribute__((ext_vector_type(16)));
typedef int    intx4v __attribute__((ext_vector_type(4)));
typedef int    intx8 __attribute__((ext_vector_type(8)));
typedef unsigned short ushort8 __attribute__((ext_vector_type(8)));
typedef unsigned short ushort4v __attribute__((ext_vector_type(4)));

__device__ __forceinline__ float bflo(unsigned int u) {
    union { unsigned int u32; float f; } x; x.u32 = u << 16; return x.f;
}
__device__ __forceinline__ float bfhi(unsigned int u) {
    union { unsigned int u32; float f; } x; x.u32 = u & 0xffff0000u; return x.f;
}
__device__ __forceinline__ unsigned short f2bf(float f) {
    union { float f; unsigned int u; } x; x.f = f;
    unsigned int u = x.u;
    unsigned int r = (u + 0x7fffu + ((u >> 16) & 1u)) >> 16;   // RNE
    return (unsigned short)r;
}
__device__ __forceinline__ unsigned char f2fp8(float f) {
    unsigned int pk = __builtin_amdgcn_cvt_pk_fp8_f32(f, f, 0, false);
    return (unsigned char)(pk & 0xff);
}
// decode 4 fp8(e4m3) packed in u32 -> 4 floats
__device__ __forceinline__ void fp8x4_dec(unsigned int u, float* f) {
    floatx2 lo = __builtin_amdgcn_cvt_pk_f32_fp8(u, false);
    floatx2 hi = __builtin_amdgcn_cvt_pk_f32_fp8(u, true);
    f[0] = lo[0]; f[1] = lo[1]; f[2] = hi[0]; f[3] = hi[1];
}

#define GLOBAL_U32 const __attribute__((address_space(1))) unsigned int*
#define LDS_U32 __attribute__((address_space(3))) unsigned int*
__device__ __forceinline__ void async_cp16(const void* g, void* l) {
    __builtin_amdgcn_global_load_lds((GLOBAL_U32)g, (LDS_U32)l, 16, 0, 0);
}

#define UHAT_SCALE 64.0f
#define UHAT_INV   (1.0f / 64.0f)
#define W2_SCALE   16.0f
#define W2_INV     (1.0f / 16.0f)

// ---------- prep: conv1 (blocks 0..511) + w2t fp8 (blocks 512..1023) + S012 zero ----------
__global__ __launch_bounds__(256) void prep_k(const float* __restrict__ x,
                                              const float* __restrict__ w1c,
                                              const float* __restrict__ b1c,
                                              const float* __restrict__ w2,
                                              unsigned char* __restrict__ h1t8,
                                              unsigned char* __restrict__ w2t8,
                                              float* __restrict__ S012) {
    const int blk = blockIdx.x, t = threadIdx.x;
    // zero routing accumulators: 122880 floats = 1024 blocks x 120
    if (t < 120) S012[blk * 120 + t] = 0.f;
    __shared__ float shm[10368];
    if (blk < 512) {
        // conv1 (oh-split x2): x[256,1,28,28]*w[256,1,9,9] -> h1t8 fp8 [b][20][20][256]
        const int b = blk >> 1, hh = blk & 1;
        const int oh0 = hh * 10;
        for (int idx = t; idx < 504; idx += 256) shm[idx] = x[b * 784 + oh0 * 28 + idx];
        __syncthreads();
        const float* wr = w1c + t * 81;               // thread t = output channel t
        const float bv = b1c[t];
        for (int ohl = 0; ohl < 10; ++ohl) {
            float acc[20];
#pragma unroll
            for (int ow = 0; ow < 20; ++ow) acc[ow] = bv;
#pragma unroll
            for (int kh = 0; kh < 9; ++kh) {
                float xr[28];
                const float* xrow = &shm[(ohl + kh) * 28];
#pragma unroll
                for (int q = 0; q < 7; ++q) *(float4*)&xr[q * 4] = *(const float4*)&xrow[q * 4];
#pragma unroll
                for (int kw = 0; kw < 9; ++kw) {
                    const float wv = wr[kh * 9 + kw];
#pragma unroll
                    for (int ow = 0; ow < 20; ++ow) acc[ow] = fmaf(xr[ow + kw], wv, acc[ow]);
                }
            }
            unsigned char* orow = h1t8 + (size_t)((b * 20 + oh0 + ohl) * 20) * 256 + t;
#pragma unroll
            for (int ow = 0; ow < 20; ++ow) orow[ow * 256] = f2fp8(acc[ow]);
        }
    } else {
        // w2 transform: OIHW fp32 [oc][ic][81] -> fp8 [oc][tap*256+ic], x16 scale
        const int id = blk - 512;
        const int oc = id >> 1, half = id & 1;
        const float* src = w2 + (size_t)oc * 20736 + half * 128 * 81;
        for (int idx = t; idx < 10368; idx += 256) shm[idx] = src[idx];
        __syncthreads();
        unsigned char* dst = w2t8 + (size_t)oc * 20736 + half * 128;
        for (int idx = t; idx < 10368; idx += 256) {
            const int tap = idx >> 7, icl = idx & 127;
            dst[tap * 256 + icl] = f2fp8(shm[icl * 81 + tap] * W2_SCALE);
        }
    }
}

// ---------- conv2 implicit GEMM, MX-scaled fp8 MFMA (unit scales): proven-best structure ----------
// tile 128M x 128OC, 4 waves (64x64 each), split-K x4, BK=128, XOR-swizzled LDS slots.
// (Rounds 1,2,9,10 confirmed: dbuf/counted-vmcnt/zero-LDS all regress; this is the local opt.)
__device__ __forceinline__ int c2_rowbase(int m) {
    const int b = m / 36, sp = m % 36;
    const int oh = sp / 6, ow = sp % 6;
    return (b * 400 + oh * 40 + ow * 2) * 256;        // byte offset into h1t8 (1 B/elem)
}

__global__ __launch_bounds__(256) void conv2_k(const unsigned char* __restrict__ h1t8,
                                               const unsigned char* __restrict__ w2t8,
                                               unsigned short* __restrict__ part) {
    const int t = threadIdx.x;
    const int id = blockIdx.x;                        // 0..575
    const int G = id >> 4;                            // 0..35
    const int bx = (id >> 3) & 1;                     // 0..1 (128-oc tile)
    const int s = id & 7;
    const int by = 2 * G + (s >> 2);                  // 0..71
    const int z  = ((s & 3) + by) & 3;                // 0..3
    __shared__ unsigned char At[128 * 128];           // m rows, 128 fp8 (16 KB)
    __shared__ unsigned char Bt[128 * 128];           // oc rows (16 KB)

    const int oc0 = bx * 128;

    int aRB[4], bBase[4];
#pragma unroll
    for (int k = 0; k < 4; ++k) {
        const int a = t + 256 * k;
        const int r = a >> 3, sg = a & 7;
        const int u = sg ^ (r & 7);
        aRB[k] = c2_rowbase(by * 128 + r) + u * 16;
        bBase[k] = (oc0 + r) * 20736 + u * 16;
    }

    const int lane = t & 63, l31 = lane & 31, h = lane >> 5;
    const int wave = t >> 6;
    const int wM = (wave & 1) * 64, wOC = (wave >> 1) * 64;

    int aO[2][2][2], bO[2][2][2];
#pragma unroll
    for (int i = 0; i < 2; ++i) {
        const int Ra = wOC + i * 32 + l31;            // oc row (A-operand from Bt)
        const int Rb = wM + i * 32 + l31;             // m row  (B-operand from At)
#pragma unroll
        for (int st = 0; st < 2; ++st)
#pragma unroll
            for (int p = 0; p < 2; ++p) {
                const int c = st * 4 + h * 2 + p;
                aO[st][i][p] = Ra * 128 + ((c ^ (Ra & 7)) << 4);
                bO[st][i][p] = Rb * 128 + ((c ^ (Rb & 7)) << 4);
            }
    }

    floatx16 acc[2][2];                               // [oc-tile][m-tile]
#pragma unroll
    for (int i = 0; i < 2; ++i)
#pragma unroll
        for (int j = 0; j < 2; ++j)
#pragma unroll
            for (int r = 0; r < 16; ++r) acc[i][j][r] = 0.f;

    const int q0 = (162 * z) >> 2, q1 = (162 * (z + 1)) >> 2;
    for (int q = q0; q < q1; ++q) {
        const int tap = q >> 1;                       // BK=128 = half a tap; never crosses
        const int kh = tap / 9, kw = tap - 9 * kh;
        const int aoffB = (kh * 20 + kw) * 256 + (q & 1) * 128;
        __syncthreads();
#pragma unroll
        for (int k = 0; k < 4; ++k)
            async_cp16(h1t8 + aRB[k] + aoffB, At + (t + 256 * k) * 16);
#pragma unroll
        for (int k = 0; k < 4; ++k)
            async_cp16(w2t8 + bBase[k] + q * 128, Bt + (t + 256 * k) * 16);
        __syncthreads();
#pragma unroll
        for (int st = 0; st < 2; ++st) {
            intx8 aF[2], bF[2];
#pragma unroll
            for (int i = 0; i < 2; ++i) {
                const intx4v alo = *(const intx4v*)(Bt + aO[st][i][0]);
                const intx4v ahi = *(const intx4v*)(Bt + aO[st][i][1]);
                aF[i] = (intx8){alo[0], alo[1], alo[2], alo[3], ahi[0], ahi[1], ahi[2], ahi[3]};
                const intx4v blo = *(const intx4v*)(At + bO[st][i][0]);
                const intx4v bhi = *(const intx4v*)(At + bO[st][i][1]);
                bF[i] = (intx8){blo[0], blo[1], blo[2], blo[3], bhi[0], bhi[1], bhi[2], bhi[3]};
            }
#pragma unroll
            for (int i = 0; i < 2; ++i)
#pragma unroll
                for (int j = 0; j < 2; ++j)
                    acc[i][j] = __builtin_amdgcn_mfma_scale_f32_32x32x64_f8f6f4(
                        aF[i], bF[j], acc[i][j], 0, 0, 0, 127, 0, 127);
        }
    }

    // epilogue: D col(lane&31)=m, row=(reg&3)+8*(reg>>2)+4*h = oc; undo W2 scale
    unsigned short* pz = part + (size_t)z * 2359296;
#pragma unroll
    for (int i = 0; i < 2; ++i) {
#pragma unroll
        for (int j = 0; j < 2; ++j) {
            const int m = by * 128 + wM + j * 32 + l31;
#pragma unroll
            for (int rg = 0; rg < 4; ++rg) {
                const int oc = oc0 + wOC + i * 32 + rg * 8 + 4 * h;
                ushort4v pk;
#pragma unroll
                for (int rr = 0; rr < 4; ++rr) pk[rr] = f2bf(acc[i][j][rg * 4 + rr] * W2_INV);
                *(ushort4v*)(pz + (size_t)m * 256 + oc) = pk;
            }
        }
    }
}

// ---------- reduce split-K(bf16 x4) + bias + squash(axis=w) -> u[b][1152][8] (half-split x2) ----------
__global__ __launch_bounds__(256) void squash_u_k(const unsigned short* __restrict__ part,
                                                  const float* __restrict__ bias,
                                                  float* __restrict__ u) {
    const int bb = blockIdx.x, t = threadIdx.x;
    const int b = bb >> 1, h = bb & 1;
    __shared__ float hs[4608];
    const size_t base = (size_t)b * 9216 + h * 4608;
    for (int q = t; q < 2304; q += 256) {
        const int idx = q * 2;
        float v0 = bias[idx & 255], v1 = bias[(idx + 1) & 255];
#pragma unroll
        for (int z = 0; z < 4; ++z) {
            const unsigned int uu = *(const unsigned int*)(part + (size_t)z * 2359296 + base + idx);
            v0 += bflo(uu);
            v1 += bfhi(uu);
        }
        hs[idx] = v0; hs[idx + 1] = v1;
    }
    __syncthreads();
    for (int gq = t; gq < 768; gq += 256) {           // groups (c, oh-local), squash over ow(6)
        const int c = gq / 3, ohl = gq % 3;
        const int oh = h * 3 + ohl;
        float s[6], sq = 0.f;
#pragma unroll
        for (int ow = 0; ow < 6; ++ow) { s[ow] = hs[(ohl * 6 + ow) * 256 + c]; sq = fmaf(s[ow], s[ow], sq); }
        const float norm = sqrtf(sq);
        const float f = (sq / (1.0f + sq)) / (norm + 1e-7f);
        float* up = u + (size_t)b * 9216 + c * 36 + oh * 6;
#pragma unroll
        for (int ow = 0; ow < 6; ++ow) up[ow] = s[ow] * f;
    }
}

// ---------- u_hat fp8: uhat8[i][b][40 u32] = e4m3(64 * W_i u_b) ----------
__global__ __launch_bounds__(256) void uhat_k(const float* __restrict__ Wc,
                                              const float* __restrict__ u,
                                              unsigned int* __restrict__ uhat8) {
    const int i = blockIdx.x, t = threadIdx.x;       // t = b
    __shared__ float Wl[1280];                       // [o][d*8+e]
    for (int idx = t; idx < 1280; idx += 256) {
        const int o = idx >> 7, r = idx & 127;
        Wl[idx] = Wc[((size_t)o * 1152 + i) * 128 + r];
    }
    float ur[8];
    *(float4*)&ur[0] = *(const float4*)(u + (size_t)t * 9216 + i * 8);
    *(float4*)&ur[4] = *(const float4*)(u + (size_t)t * 9216 + i * 8 + 4);
    __syncthreads();
    unsigned int* row = uhat8 + ((size_t)i * 256 + t) * 40;
#pragma unroll 1
    for (int o = 0; o < 10; ++o) {
        float vals[16];
#pragma unroll
        for (int d = 0; d < 16; ++d) {
            const float* wp = &Wl[o * 128 + d * 8];
            float a = 0.f;
#pragma unroll
            for (int e = 0; e < 8; ++e) a = fmaf(wp[e], ur[e], a);
            vals[d] = a * UHAT_SCALE;
        }
        uint4 pk;
        unsigned int w;
#pragma unroll
        for (int q = 0; q < 4; ++q) {
            w = 0;
            w = __builtin_amdgcn_cvt_pk_fp8_f32(vals[q * 4 + 0], vals[q * 4 + 1], w, false);
            w = __builtin_amdgcn_cvt_pk_fp8_f32(vals[q * 4 + 2], vals[q * 4 + 3], w, true);
            if (q == 0) pk.x = w; else if (q == 1) pk.y = w; else if (q == 2) pk.z = w; else pk.w = w;
        }
        *(uint4*)(row + o * 4) = pk;
    }
}

// ---------- routing iteration 0: S0[b][160] = 0.1 * sum_i u_hat (LDS-staged, coalesced) ----------
// Old version read UHAT with 4B-granular loads at 40KB stride (64 cache lines per
// wave-instr). New: stage the 128x160B slab coalesced (same pattern as route_iter_k),
// reduce from LDS in the SAME i-order -> bit-identical S0.
__global__ __launch_bounds__(256) void route_iter0_k(const unsigned int* __restrict__ uhat8,
                                                     float* __restrict__ S0) {
    const int b = blockIdx.x, i0 = blockIdx.y * 128, t = threadIdx.x;
    __shared__ __align__(16) unsigned int Ul8[128 * 40];     // 20480 B, [i_local][40 u32]
    const unsigned int* ub = uhat8 + ((size_t)i0 * 256 + b) * 40;
#pragma unroll
    for (int rep = 0; rep < 5; ++rep) {
        const int c = rep * 256 + t;
        const int row = c / 10, q = c - row * 10;
        async_cp16(ub + (size_t)row * 10240 + q * 4, (char*)Ul8 + c * 16);
    }
    __syncthreads();                                  // drains async -> slab visible
    const int th = t & 127, hi = t >> 7;
    if (th < 40) {                                    // th = od-quad
        const unsigned int* p = Ul8 + hi * 64 * 40 + th;
        float a0 = 0.f, a1 = 0.f, a2 = 0.f, a3 = 0.f;
#pragma unroll 4
        for (int i = 0; i < 64; ++i) {
            float f[4];
            fp8x4_dec(p[i * 40], f);
            a0 += f[0]; a1 += f[1]; a2 += f[2]; a3 += f[3];
        }
        const float sc = 0.1f * UHAT_INV;
        atomicAdd(&S0[b * 160 + 4 * th + 0], sc * a0);
        atomicAdd(&S0[b * 160 + 4 * th + 1], sc * a1);
        atomicAdd(&S0[b * 160 + 4 * th + 2], sc * a2);
        atomicAdd(&S0[b * 160 + 4 * th + 3], sc * a3);
    }
}

// ---------- fused routing iteration: squash(S_in) + logit update + softmax + weighted sum ----------
template <int ITER>
__global__ __launch_bounds__(256) void route_iter_k(const unsigned int* __restrict__ uhat8,
                                                    const float* __restrict__ S_in,
                                                    float* __restrict__ BL,
                                                    float* __restrict__ S_out) {
    const int b = blockIdx.x, i0 = blockIdx.y * 128, t = threadIdx.x;
    __shared__ __align__(16) unsigned int Ul8[128 * 40];     // 20480 B, [i_local][40 u32]
    __shared__ float Vl[160];
    __shared__ float cT[10 * 132];
    __shared__ float dots[128 * 10];

    // stage slab (i0..i0+127, b): rows of 160 B at 40960 B stride; 1280 16B units.
    const unsigned int* ub = uhat8 + ((size_t)i0 * 256 + b) * 40;
#pragma unroll
    for (int rep = 0; rep < 5; ++rep) {
        const int c = rep * 256 + t;
        const int row = c / 10, q = c - row * 10;
        async_cp16(ub + (size_t)row * 10240 + q * 4, (char*)Ul8 + c * 16);
    }

    // phase 0: squash S_in -> Vl (redundant per block; 160 floats)
    if (t < 160) {
        const float x = S_in[b * 160 + t];
        float sq = x * x;
        sq += __shfl_xor(sq, 1, 16);
        sq += __shfl_xor(sq, 2, 16);
        sq += __shfl_xor(sq, 4, 16);
        sq += __shfl_xor(sq, 8, 16);
        const float norm = sqrtf(sq);
        const float f = (sq / (1.f + sq)) / (norm + 1e-7f);
        Vl[t] = x * f;
    }
    __syncthreads();                                  // drains async + Vl visible

    // p1a mapping: o = t%10 fixed per thread, strip s = t/10 (250 active)
    const int o = t % 10, s = t / 10;
    float vr[16];
    if (t < 250) {
#pragma unroll
        for (int q = 0; q < 4; ++q)
            *(float4*)&vr[q * 4] = *(const float4*)(&Vl[o * 16 + q * 4]);
    }

    // p1a: dots[i][o] = (1/64) * sum_d uq[i,o,d] * v[o,d]
    if (t < 250) {
#pragma unroll
        for (int rep = 0; rep < 6; ++rep) {
            const int i = s + 25 * rep;
            if (i < 128) {
                const uint4 uu = *(const uint4*)(Ul8 + i * 40 + o * 4);
                float f[16];
                fp8x4_dec(uu.x, f);
                fp8x4_dec(uu.y, f + 4);
                fp8x4_dec(uu.z, f + 8);
                fp8x4_dec(uu.w, f + 12);
                float dot = 0.f;
#pragma unroll
                for (int d = 0; d < 16; ++d) dot = fmaf(f[d], vr[d], dot);
                dots[i * 10 + o] = dot * UHAT_INV;
            }
        }
    }
    __syncthreads();

    // p1b: per-i logits + softmax -> cT[o][i]
    if (t < 128) {
        float bl[10];
#pragma unroll
        for (int oo = 0; oo < 10; ++oo) bl[oo] = dots[t * 10 + oo];
        if (ITER == 2) {
#pragma unroll
            for (int oo = 0; oo < 10; ++oo) bl[oo] += BL[(size_t)b * 11520 + oo * 1152 + i0 + t];
        } else {
#pragma unroll
            for (int oo = 0; oo < 10; ++oo) BL[(size_t)b * 11520 + oo * 1152 + i0 + t] = bl[oo];
        }
        float mx = bl[0];
#pragma unroll
        for (int oo = 1; oo < 10; ++oo) mx = fmaxf(mx, bl[oo]);
        float ex[10], sum = 0.f;
#pragma unroll
        for (int oo = 0; oo < 10; ++oo) { ex[oo] = expf(bl[oo] - mx); sum += ex[oo]; }
        const float inv = 1.f / sum;
#pragma unroll
        for (int oo = 0; oo < 10; ++oo) cT[oo * 132 + t] = ex[oo] * inv;
    }
    __syncthreads();

    // p2: S_out[b][160] += (1/64) * sum_i c[i][o] * uq[i][od]  (two 64-i halves)
    const int th = t & 127, hi = t >> 7;
    if (th < 40) {                                    // th = od-quad, o = th>>2
        const int oq = th >> 2;
        const unsigned int* base = Ul8 + hi * 64 * 40 + th;
        const float* cb = &cT[oq * 132 + hi * 64];
        float a0 = 0.f, a1 = 0.f, a2 = 0.f, a3 = 0.f;
#pragma unroll 4
        for (int ii = 0; ii < 64; ++ii) {
            const float c = cb[ii];
            float f[4];
            fp8x4_dec(base[ii * 40], f);
            a0 = fmaf(c, f[0], a0);
            a1 = fmaf(c, f[1], a1);
            a2 = fmaf(c, f[2], a2);
            a3 = fmaf(c, f[3], a3);
        }
        atomicAdd(&S_out[b * 160 + 4 * th + 0], a0 * UHAT_INV);
        atomicAdd(&S_out[b * 160 + 4 * th + 1], a1 * UHAT_INV);
        atomicAdd(&S_out[b * 160 + 4 * th + 2], a2 * UHAT_INV);
        atomicAdd(&S_out[b * 160 + 4 * th + 3], a3 * UHAT_INV);
    }
}

// ---------- final: squash S2 -> lengths, argmax + fused decoder layer 1 ----------
__global__ __launch_bounds__(512) void final_k(const float* __restrict__ S,
                                               const float* __restrict__ w1,
                                               const float* __restrict__ b1,
                                               float* __restrict__ out_len,
                                               float* __restrict__ h1d) {
    const int b = blockIdx.x, t = threadIdx.x;
    __shared__ float v_s[160];
    __shared__ float len_s[10];
    __shared__ int sel_s;
    if (t < 160) {
        const float x = S[b * 160 + t];
        float sq = x * x;
        sq += __shfl_xor(sq, 1, 16);
        sq += __shfl_xor(sq, 2, 16);
        sq += __shfl_xor(sq, 4, 16);
        sq += __shfl_xor(sq, 8, 16);
        const float norm = sqrtf(sq);
        const float f = (sq / (1.f + sq)) / (norm + 1e-7f);
        v_s[t] = x * f;
        if ((t & 15) == 0) {
            const float len = f * norm;
            len_s[t >> 4] = len;
            out_len[b * 10 + (t >> 4)] = len;
        }
    }
    __syncthreads();
    if (t == 0) {
        float best = len_s[0]; int bi = 0;
        for (int oo = 1; oo < 10; ++oo) if (len_s[oo] > best) { best = len_s[oo]; bi = oo; }
        sel_s = bi;
    }
    __syncthreads();
    const int s = sel_s;
    float acc = b1[t];
    const float* wrow = w1 + (size_t)(s * 16) * 512 + t;
#pragma unroll
    for (int j = 0; j < 16; ++j) acc = fmaf(v_s[s * 16 + j], wrow[j * 512], acc);
    h1d[(size_t)b * 512 + t] = fmaxf(acc, 0.f);
}

// ---------- decoder GEMM v3: 8m x 64n tile, per-wave K-split x4, ping-pong float4 B batches ----------
template <int ACT>
__global__ __launch_bounds__(256) void mlp3_k(const float* __restrict__ A,
                                              const float* __restrict__ Bm,
                                              const float* __restrict__ bias,
                                              float* __restrict__ C, int N, int K) {
    extern __shared__ float Asm[];                    // 8*(K+4) floats; tail-reused for reduce
    const int t = threadIdx.x;
    const int m0 = blockIdx.y * 8, n0 = blockIdx.x * 64;
    const int RS = K + 4;
    const int k4 = K >> 2;
    for (int i = t; i < 8 * k4; i += 256) {           // stage A tile, float4 units
        const int r = i / k4, c = i - r * k4;
        *(float4*)&Asm[r * RS + c * 4] = *(const float4*)&A[(size_t)(m0 + r) * K + c * 4];
    }
    __syncthreads();
    const int lane = t & 63, w = t >> 6;
    const int mq = lane >> 4, nq = lane & 15;
    const int n = n0 + nq * 4;
    const int ncl = (n + 3 < N) ? n : (N - 4);        // clamp base col (16B-aligned, safe)
    const float* bp = Bm + ncl;
    const float* asA = &Asm[(mq * 2 + 0) * RS];
    const float* asB = &Asm[(mq * 2 + 1) * RS];
    const int kQ = K >> 2;                            // per-wave chunk (128 or 256)
    const int kBeg = w * kQ;
    const int nBat2 = kQ >> 4;                        // double-batches of 16 k
    float4 acc0 = {0.f, 0.f, 0.f, 0.f}, acc1 = {0.f, 0.f, 0.f, 0.f};
    float4 ba[8], bb[8];
#pragma unroll
    for (int d = 0; d < 8; ++d) ba[d] = *(const float4*)&bp[(size_t)(kBeg + d) * N];

#define MLP3_FMA(BATCH, KB)                                                       \
    _Pragma("unroll")                                                             \
    for (int d = 0; d < 8; ++d) {                                                 \
        const float4 b = BATCH[d];                                                \
        const float a0 = asA[(KB) + d];                                           \
        const float a1 = asB[(KB) + d];                                           \
        acc0.x = fmaf(a0, b.x, acc0.x); acc0.y = fmaf(a0, b.y, acc0.y);           \
        acc0.z = fmaf(a0, b.z, acc0.z); acc0.w = fmaf(a0, b.w, acc0.w);           \
        acc1.x = fmaf(a1, b.x, acc1.x); acc1.y = fmaf(a1, b.y, acc1.y);           \
        acc1.z = fmaf(a1, b.z, acc1.z); acc1.w = fmaf(a1, b.w, acc1.w);           \
    }

    int k = kBeg;
#pragma unroll 1
    for (int it = 0; it < nBat2; ++it) {
#pragma unroll
        for (int d = 0; d < 8; ++d) bb[d] = *(const float4*)&bp[(size_t)(k + 8 + d) * N];
        MLP3_FMA(ba, k)
        if (it + 1 < nBat2) {
#pragma unroll
            for (int d = 0; d < 8; ++d) ba[d] = *(const float4*)&bp[(size_t)(k + 16 + d) * N];
        }
        MLP3_FMA(bb, k + 8)
        k += 16;
    }
#undef MLP3_FMA

    // cross-wave k-quarter reduce via LDS (reuses Asm; 4*64*8 floats = 8 KB)
    __syncthreads();                                  // all waves done reading Asm
    float* red = Asm;
    float* my = &red[(size_t)(w * 64 + lane) * 8];
    my[0] = acc0.x; my[1] = acc0.y; my[2] = acc0.z; my[3] = acc0.w;
    my[4] = acc1.x; my[5] = acc1.y; my[6] = acc1.z; my[7] = acc1.w;
    __syncthreads();
    if (t < 64) {
        float o[8];
#pragma unroll
        for (int x = 0; x < 8; ++x)
            o[x] = red[(size_t)t * 8 + x] + red[(size_t)(64 + t) * 8 + x]
                 + red[(size_t)(128 + t) * 8 + x] + red[(size_t)(192 + t) * 8 + x];
        const int nn = n0 + (t & 15) * 4;
#pragma unroll
        for (int rm = 0; rm < 2; ++rm) {
            const int m = m0 + (t >> 4) * 2 + rm;
#pragma unroll
            for (int rn = 0; rn < 4; ++rn) {
                const int ncol = nn + rn;
                if (ncol < N) {
                    float v = o[rm * 4 + rn] + bias[ncol];
                    if (ACT == 0) v = fmaxf(v, 0.f);
                    else v = 1.f / (1.f + expf(-v));
                    C[(size_t)m * N + ncol] = v;
                }
            }
        }
    }
}

// ---------- launcher ----------
extern "C" void kernel_launch(void* const* d_in, const int* in_sizes, int n_in,
                              void* d_out, int out_size, void* d_ws, size_t ws_size,
                              hipStream_t stream) {
    const float* x   = (const float*)d_in[0];
    const float* w1  = (const float*)d_in[1];
    const float* b1  = (const float*)d_in[2];
    const float* w2  = (const float*)d_in[3];
    const float* b2  = (const float*)d_in[4];
    const float* Wc  = (const float*)d_in[5];
    const float* dw1 = (const float*)d_in[6];
    const float* db1 = (const float*)d_in[7];
    const float* dw2 = (const float*)d_in[8];
    const float* db2 = (const float*)d_in[9];
    const float* dw3 = (const float*)d_in[10];
    const float* db3 = (const float*)d_in[11];
    float* out = (float*)d_out;

    char* ws = (char*)d_ws;
    unsigned char* H1T8 = (unsigned char*)(ws + 0);            // 26,214,400 B fp8
    unsigned char* W2T8 = (unsigned char*)(ws + 26214400);     //  5,308,416 B fp8 (x16)
    unsigned short* PART = (unsigned short*)(ws + 31522816);   // 18,874,368 B bf16, z=4
    unsigned int*   UHAT = (unsigned int*)(ws + 0);            // 47,185,920 B fp8 (aliases dead staging)
    float* U    = (float*)(ws + 50397184);                     //  9,437,184 B (after PART; dead after uhat_k)
    float* BL   = (float*)(ws + 59834368);                     // 11,796,480 B (live iter1->iter2)
    float* S012 = (float*)(ws + 71630848);                     //    491,520 B (zeroed by prep_k)
    float* H1D  = (float*)(ws + 59834368);                     //    524,288 B (dead-BL space, after iter2)
    float* H2D  = (float*)(ws + 60358656);                     //  1,048,576 B

    float* S0 = S012, *S1 = S012 + 40960, *S2 = S012 + 81920;

    prep_k<<<1024, 256, 0, stream>>>(x, w1, b1, w2, H1T8, W2T8, S012);
    conv2_k<<<576, 256, 0, stream>>>(H1T8, W2T8, PART);
    squash_u_k<<<512, 256, 0, stream>>>(PART, b2, U);
    uhat_k<<<1152, 256, 0, stream>>>(Wc, U, UHAT);
    route_iter0_k<<<dim3(256, 9), 256, 0, stream>>>(UHAT, S0);
    route_iter_k<1><<<dim3(256, 9), 256, 0, stream>>>(UHAT, S0, BL, S1);
    route_iter_k<2><<<dim3(256, 9), 256, 0, stream>>>(UHAT, S1, BL, S2);
    final_k<<<256, 512, 0, stream>>>(S2, dw1, db1, out, H1D);
    mlp3_k<0><<<dim3(16, 32), 256, 8 * 516 * 4, stream>>>(H1D, dw2, db2, H2D, 1024, 512);
    mlp3_k<1><<<dim3(13, 32), 256, 8 * 1028 * 4, stream>>>(H2D, dw3, db3, out + 2560, 784, 1024);
}

// Round 12
// 329.747 us; speedup vs baseline: 1.5713x; 1.0629x over previous
//
#include <hip/hip_runtime.h>
#include <cstdint>
#include <cstddef>

// ---------- types / helpers ----------
typedef __bf16 bf16x8 __attribute__((ext_vector_type(8)));
typedef short  shortx8 __attribute__((ext_vector_type(8)));
typedef float  floatx4 __attribute__((ext_vector_type(4)));
typedef float  floatx2 __attribute__((ext_vector_type(2)));
typedef float  floatx16 __attribute__((ext_vector_type(16)));
typedef int    intx4v __attribute__((ext_vector_type(4)));
typedef int    intx8 __attribute__((ext_vector_type(8)));
typedef unsigned short ushort8 __attribute__((ext_vector_type(8)));
typedef unsigned short ushort4v __attribute__((ext_vector_type(4)));

__device__ __forceinline__ float bflo(unsigned int u) {
    union { unsigned int u32; float f; } x; x.u32 = u << 16; return x.f;
}
__device__ __forceinline__ float bfhi(unsigned int u) {
    union { unsigned int u32; float f; } x; x.u32 = u & 0xffff0000u; return x.f;
}
__device__ __forceinline__ unsigned short f2bf(float f) {
    union { float f; unsigned int u; } x; x.f = f;
    unsigned int u = x.u;
    unsigned int r = (u + 0x7fffu + ((u >> 16) & 1u)) >> 16;   // RNE
    return (unsigned short)r;
}
__device__ __forceinline__ unsigned char f2fp8(float f) {
    unsigned int pk = __builtin_amdgcn_cvt_pk_fp8_f32(f, f, 0, false);
    return (unsigned char)(pk & 0xff);
}
// decode 4 fp8(e4m3) packed in u32 -> 4 floats
__device__ __forceinline__ void fp8x4_dec(unsigned int u, float* f) {
    floatx2 lo = __builtin_amdgcn_cvt_pk_f32_fp8(u, false);
    floatx2 hi = __builtin_amdgcn_cvt_pk_f32_fp8(u, true);
    f[0] = lo[0]; f[1] = lo[1]; f[2] = hi[0]; f[3] = hi[1];
}

#define GLOBAL_U32 const __attribute__((address_space(1))) unsigned int*
#define LDS_U32 __attribute__((address_space(3))) unsigned int*
__device__ __forceinline__ void async_cp16(const void* g, void* l) {
    __builtin_amdgcn_global_load_lds((GLOBAL_U32)g, (LDS_U32)l, 16, 0, 0);
}

#define UHAT_SCALE 64.0f
#define UHAT_INV   (1.0f / 64.0f)
#define W2_SCALE   16.0f
#define W2_INV     (1.0f / 16.0f)

// ---------- prep: conv1 via bf16 MFMA (blocks 0..511) + w2t fp8 (512..1023) + S012 zero ----------
// conv1 = implicit GEMM: D[ch][spatial] = w1[ch][tap] x patch[spatial][tap], K=81 pad 96.
// Operand convention copied from the WORKING conv2_k: first operand rows -> D reg-rows (ch),
// second operand rows -> D col (spatial). Pad taps zeroed on the WEIGHT side (A-garbage x 0 = 0;
// xs zero-padded to 1024 so pad-tap reads are finite).
__global__ __launch_bounds__(256) void prep_k(const float* __restrict__ x,
                                              const float* __restrict__ w1c,
                                              const float* __restrict__ b1c,
                                              const float* __restrict__ w2,
                                              unsigned char* __restrict__ h1t8,
                                              unsigned char* __restrict__ w2t8,
                                              float* __restrict__ S012) {
    const int blk = blockIdx.x, t = threadIdx.x;
    // zero routing accumulators: 122880 floats = 1024 blocks x 120
    if (t < 120) S012[blk * 120 + t] = 0.f;
    if (blk < 512) {
        // block = (image b, ch-half): M=400 spatial, N=128 ch, K=96 (81 real taps)
        __shared__ float xs[1024];                    // 28x28 image + zero pad
        __shared__ unsigned short wb[96 * 132];       // [tap][ch-local] bf16, stride 132
        const int b = blk >> 1, ch0 = (blk & 1) * 128;
        for (int i = t; i < 1024; i += 256) xs[i] = (i < 784) ? x[b * 784 + i] : 0.f;
        for (int i = t; i < 96 * 132; i += 256) wb[i] = 0;
        __syncthreads();
        for (int i = t; i < 81 * 128; i += 256) {
            const int tap = i >> 7, chl = i & 127;
            wb[tap * 132 + chl] = f2bf(w1c[(size_t)(ch0 + chl) * 81 + tap]);
        }
        __syncthreads();
        const int lane = t & 63, l15 = lane & 15, g = lane >> 4;
        const int wave = t >> 6;
        const int n0l = wave * 32;                    // wave owns 32 local ch (2 N-tiles)
        // per-lane tap -> x-offset (independent of mt)
        int xoff[3][8];
#pragma unroll
        for (int kk = 0; kk < 3; ++kk)
#pragma unroll
            for (int e = 0; e < 8; ++e) {
                const int tap = kk * 32 + g * 8 + e;
                const int kh = tap / 9, kw = tap - 9 * kh;
                xoff[kk][e] = kh * 28 + kw;
            }
        // weight fragments (ch rows over k), reused across all 25 M-tiles
        shortx8 bF[2][3];
#pragma unroll
        for (int nt = 0; nt < 2; ++nt)
#pragma unroll
            for (int kk = 0; kk < 3; ++kk) {
                shortx8 v;
#pragma unroll
                for (int e = 0; e < 8; ++e) {
                    const int tap = kk * 32 + g * 8 + e;
                    v[e] = (short)wb[tap * 132 + n0l + nt * 16 + l15];
                }
                bF[nt][kk] = v;
            }
        float bv[2][4];
#pragma unroll
        for (int nt = 0; nt < 2; ++nt)
#pragma unroll
            for (int r = 0; r < 4; ++r)
                bv[nt][r] = b1c[ch0 + n0l + nt * 16 + g * 4 + r];
        for (int mt = 0; mt < 25; ++mt) {
            const int s = mt * 16 + l15;              // spatial: A-load row AND D col
            const int oh = s / 20, ow = s - 20 * oh;
            const int s2 = oh * 28 + ow;
            shortx8 aF[3];
#pragma unroll
            for (int kk = 0; kk < 3; ++kk) {
                shortx8 v;
#pragma unroll
                for (int e = 0; e < 8; ++e) v[e] = (short)f2bf(xs[s2 + xoff[kk][e]]);
                aF[kk] = v;
            }
            const size_t sbase = ((size_t)(b * 20 + oh) * 20 + ow) * 256 + ch0 + n0l + g * 4;
#pragma unroll
            for (int nt = 0; nt < 2; ++nt) {
                floatx4 acc = (floatx4){0.f, 0.f, 0.f, 0.f};
#pragma unroll
                for (int kk = 0; kk < 3; ++kk)
                    acc = __builtin_amdgcn_mfma_f32_16x16x32_bf16(bF[nt][kk], aF[kk], acc, 0, 0, 0);
                unsigned int w = 0;
                w = __builtin_amdgcn_cvt_pk_fp8_f32(acc[0] + bv[nt][0], acc[1] + bv[nt][1], w, false);
                w = __builtin_amdgcn_cvt_pk_fp8_f32(acc[2] + bv[nt][2], acc[3] + bv[nt][3], w, true);
                *(unsigned int*)(h1t8 + sbase + nt * 16) = w;
            }
        }
    } else {
        // w2 transform: OIHW fp32 [oc][ic][81] -> fp8 [oc][tap*256+ic], x16 scale
        __shared__ float shm[10368];
        const int id = blk - 512;
        const int oc = id >> 1, half = id & 1;
        const float* src = w2 + (size_t)oc * 20736 + half * 128 * 81;
        for (int idx = t; idx < 10368; idx += 256) shm[idx] = src[idx];
        __syncthreads();
        unsigned char* dst = w2t8 + (size_t)oc * 20736 + half * 128;
        for (int idx = t; idx < 10368; idx += 256) {
            const int tap = idx >> 7, icl = idx & 127;
            dst[tap * 256 + icl] = f2fp8(shm[icl * 81 + tap] * W2_SCALE);
        }
    }
}

// ---------- conv2 implicit GEMM, MX-scaled fp8 MFMA (unit scales): proven-best structure ----------
// tile 128M x 128OC, 4 waves (64x64 each), split-K x4, BK=128, XOR-swizzled LDS slots.
// (Rounds 1,2,9,10 confirmed: dbuf/counted-vmcnt/zero-LDS all regress; this is the local opt.)
__device__ __forceinline__ int c2_rowbase(int m) {
    const int b = m / 36, sp = m % 36;
    const int oh = sp / 6, ow = sp % 6;
    return (b * 400 + oh * 40 + ow * 2) * 256;        // byte offset into h1t8 (1 B/elem)
}

__global__ __launch_bounds__(256) void conv2_k(const unsigned char* __restrict__ h1t8,
                                               const unsigned char* __restrict__ w2t8,
                                               unsigned short* __restrict__ part) {
    const int t = threadIdx.x;
    const int id = blockIdx.x;                        // 0..575
    const int G = id >> 4;                            // 0..35
    const int bx = (id >> 3) & 1;                     // 0..1 (128-oc tile)
    const int s = id & 7;
    const int by = 2 * G + (s >> 2);                  // 0..71
    const int z  = ((s & 3) + by) & 3;                // 0..3
    __shared__ unsigned char At[128 * 128];           // m rows, 128 fp8 (16 KB)
    __shared__ unsigned char Bt[128 * 128];           // oc rows (16 KB)

    const int oc0 = bx * 128;

    int aRB[4], bBase[4];
#pragma unroll
    for (int k = 0; k < 4; ++k) {
        const int a = t + 256 * k;
        const int r = a >> 3, sg = a & 7;
        const int u = sg ^ (r & 7);
        aRB[k] = c2_rowbase(by * 128 + r) + u * 16;
        bBase[k] = (oc0 + r) * 20736 + u * 16;
    }

    const int lane = t & 63, l31 = lane & 31, h = lane >> 5;
    const int wave = t >> 6;
    const int wM = (wave & 1) * 64, wOC = (wave >> 1) * 64;

    int aO[2][2][2], bO[2][2][2];
#pragma unroll
    for (int i = 0; i < 2; ++i) {
        const int Ra = wOC + i * 32 + l31;            // oc row (A-operand from Bt)
        const int Rb = wM + i * 32 + l31;             // m row  (B-operand from At)
#pragma unroll
        for (int st = 0; st < 2; ++st)
#pragma unroll
            for (int p = 0; p < 2; ++p) {
                const int c = st * 4 + h * 2 + p;
                aO[st][i][p] = Ra * 128 + ((c ^ (Ra & 7)) << 4);
                bO[st][i][p] = Rb * 128 + ((c ^ (Rb & 7)) << 4);
            }
    }

    floatx16 acc[2][2];                               // [oc-tile][m-tile]
#pragma unroll
    for (int i = 0; i < 2; ++i)
#pragma unroll
        for (int j = 0; j < 2; ++j)
#pragma unroll
            for (int r = 0; r < 16; ++r) acc[i][j][r] = 0.f;

    const int q0 = (162 * z) >> 2, q1 = (162 * (z + 1)) >> 2;
    for (int q = q0; q < q1; ++q) {
        const int tap = q >> 1;                       // BK=128 = half a tap; never crosses
        const int kh = tap / 9, kw = tap - 9 * kh;
        const int aoffB = (kh * 20 + kw) * 256 + (q & 1) * 128;
        __syncthreads();
#pragma unroll
        for (int k = 0; k < 4; ++k)
            async_cp16(h1t8 + aRB[k] + aoffB, At + (t + 256 * k) * 16);
#pragma unroll
        for (int k = 0; k < 4; ++k)
            async_cp16(w2t8 + bBase[k] + q * 128, Bt + (t + 256 * k) * 16);
        __syncthreads();
#pragma unroll
        for (int st = 0; st < 2; ++st) {
            intx8 aF[2], bF[2];
#pragma unroll
            for (int i = 0; i < 2; ++i) {
                const intx4v alo = *(const intx4v*)(Bt + aO[st][i][0]);
                const intx4v ahi = *(const intx4v*)(Bt + aO[st][i][1]);
                aF[i] = (intx8){alo[0], alo[1], alo[2], alo[3], ahi[0], ahi[1], ahi[2], ahi[3]};
                const intx4v blo = *(const intx4v*)(At + bO[st][i][0]);
                const intx4v bhi = *(const intx4v*)(At + bO[st][i][1]);
                bF[i] = (intx8){blo[0], blo[1], blo[2], blo[3], bhi[0], bhi[1], bhi[2], bhi[3]};
            }
#pragma unroll
            for (int i = 0; i < 2; ++i)
#pragma unroll
                for (int j = 0; j < 2; ++j)
                    acc[i][j] = __builtin_amdgcn_mfma_scale_f32_32x32x64_f8f6f4(
                        aF[i], bF[j], acc[i][j], 0, 0, 0, 127, 0, 127);
        }
    }

    // epilogue: D col(lane&31)=m, row=(reg&3)+8*(reg>>2)+4*h = oc; undo W2 scale
    unsigned short* pz = part + (size_t)z * 2359296;
#pragma unroll
    for (int i = 0; i < 2; ++i) {
#pragma unroll
        for (int j = 0; j < 2; ++j) {
            const int m = by * 128 + wM + j * 32 + l31;
#pragma unroll
            for (int rg = 0; rg < 4; ++rg) {
                const int oc = oc0 + wOC + i * 32 + rg * 8 + 4 * h;
                ushort4v pk;
#pragma unroll
                for (int rr = 0; rr < 4; ++rr) pk[rr] = f2bf(acc[i][j][rg * 4 + rr] * W2_INV);
                *(ushort4v*)(pz + (size_t)m * 256 + oc) = pk;
            }
        }
    }
}

// ---------- reduce split-K(bf16 x4) + bias + squash(axis=w) -> u[b][1152][8] (half-split x2) ----------
__global__ __launch_bounds__(256) void squash_u_k(const unsigned short* __restrict__ part,
                                                  const float* __restrict__ bias,
                                                  float* __restrict__ u) {
    const int bb = blockIdx.x, t = threadIdx.x;
    const int b = bb >> 1, h = bb & 1;
    __shared__ float hs[4608];
    const size_t base = (size_t)b * 9216 + h * 4608;
    for (int q = t; q < 2304; q += 256) {
        const int idx = q * 2;
        float v0 = bias[idx & 255], v1 = bias[(idx + 1) & 255];
#pragma unroll
        for (int z = 0; z < 4; ++z) {
            const unsigned int uu = *(const unsigned int*)(part + (size_t)z * 2359296 + base + idx);
            v0 += bflo(uu);
            v1 += bfhi(uu);
        }
        hs[idx] = v0; hs[idx + 1] = v1;
    }
    __syncthreads();
    for (int gq = t; gq < 768; gq += 256) {           // groups (c, oh-local), squash over ow(6)
        const int c = gq / 3, ohl = gq % 3;
        const int oh = h * 3 + ohl;
        float s[6], sq = 0.f;
#pragma unroll
        for (int ow = 0; ow < 6; ++ow) { s[ow] = hs[(ohl * 6 + ow) * 256 + c]; sq = fmaf(s[ow], s[ow], sq); }
        const float norm = sqrtf(sq);
        const float f = (sq / (1.0f + sq)) / (norm + 1e-7f);
        float* up = u + (size_t)b * 9216 + c * 36 + oh * 6;
#pragma unroll
        for (int ow = 0; ow < 6; ++ow) up[ow] = s[ow] * f;
    }
}

// ---------- u_hat fp8: uhat8[i][b][40 u32] = e4m3(64 * W_i u_b) ----------
__global__ __launch_bounds__(256) void uhat_k(const float* __restrict__ Wc,
                                              const float* __restrict__ u,
                                              unsigned int* __restrict__ uhat8) {
    const int i = blockIdx.x, t = threadIdx.x;       // t = b
    __shared__ float Wl[1280];                       // [o][d*8+e]
    for (int idx = t; idx < 1280; idx += 256) {
        const int o = idx >> 7, r = idx & 127;
        Wl[idx] = Wc[((size_t)o * 1152 + i) * 128 + r];
    }
    float ur[8];
    *(float4*)&ur[0] = *(const float4*)(u + (size_t)t * 9216 + i * 8);
    *(float4*)&ur[4] = *(const float4*)(u + (size_t)t * 9216 + i * 8 + 4);
    __syncthreads();
    unsigned int* row = uhat8 + ((size_t)i * 256 + t) * 40;
#pragma unroll 1
    for (int o = 0; o < 10; ++o) {
        float vals[16];
#pragma unroll
        for (int d = 0; d < 16; ++d) {
            const float* wp = &Wl[o * 128 + d * 8];
            float a = 0.f;
#pragma unroll
            for (int e = 0; e < 8; ++e) a = fmaf(wp[e], ur[e], a);
            vals[d] = a * UHAT_SCALE;
        }
        uint4 pk;
        unsigned int w;
#pragma unroll
        for (int q = 0; q < 4; ++q) {
            w = 0;
            w = __builtin_amdgcn_cvt_pk_fp8_f32(vals[q * 4 + 0], vals[q * 4 + 1], w, false);
            w = __builtin_amdgcn_cvt_pk_fp8_f32(vals[q * 4 + 2], vals[q * 4 + 3], w, true);
            if (q == 0) pk.x = w; else if (q == 1) pk.y = w; else if (q == 2) pk.z = w; else pk.w = w;
        }
        *(uint4*)(row + o * 4) = pk;
    }
}

// ---------- routing iteration 0: S0[b][160] = 0.1 * sum_i u_hat (LDS-staged, coalesced) ----------
__global__ __launch_bounds__(256) void route_iter0_k(const unsigned int* __restrict__ uhat8,
                                                     float* __restrict__ S0) {
    const int b = blockIdx.x, i0 = blockIdx.y * 128, t = threadIdx.x;
    __shared__ __align__(16) unsigned int Ul8[128 * 40];     // 20480 B, [i_local][40 u32]
    const unsigned int* ub = uhat8 + ((size_t)i0 * 256 + b) * 40;
#pragma unroll
    for (int rep = 0; rep < 5; ++rep) {
        const int c = rep * 256 + t;
        const int row = c / 10, q = c - row * 10;
        async_cp16(ub + (size_t)row * 10240 + q * 4, (char*)Ul8 + c * 16);
    }
    __syncthreads();                                  // drains async -> slab visible
    const int th = t & 127, hi = t >> 7;
    if (th < 40) {                                    // th = od-quad
        const unsigned int* p = Ul8 + hi * 64 * 40 + th;
        float a0 = 0.f, a1 = 0.f, a2 = 0.f, a3 = 0.f;
#pragma unroll 4
        for (int i = 0; i < 64; ++i) {
            float f[4];
            fp8x4_dec(p[i * 40], f);
            a0 += f[0]; a1 += f[1]; a2 += f[2]; a3 += f[3];
        }
        const float sc = 0.1f * UHAT_INV;
        atomicAdd(&S0[b * 160 + 4 * th + 0], sc * a0);
        atomicAdd(&S0[b * 160 + 4 * th + 1], sc * a1);
        atomicAdd(&S0[b * 160 + 4 * th + 2], sc * a2);
        atomicAdd(&S0[b * 160 + 4 * th + 3], sc * a3);
    }
}

// ---------- fused routing iteration: squash(S_in) + logit update + softmax + weighted sum ----------
template <int ITER>
__global__ __launch_bounds__(256) void route_iter_k(const unsigned int* __restrict__ uhat8,
                                                    const float* __restrict__ S_in,
                                                    float* __restrict__ BL,
                                                    float* __restrict__ S_out) {
    const int b = blockIdx.x, i0 = blockIdx.y * 128, t = threadIdx.x;
    __shared__ __align__(16) unsigned int Ul8[128 * 40];     // 20480 B, [i_local][40 u32]
    __shared__ float Vl[160];
    __shared__ float cT[10 * 132];
    __shared__ float dots[128 * 10];

    // stage slab (i0..i0+127, b): rows of 160 B at 40960 B stride; 1280 16B units.
    const unsigned int* ub = uhat8 + ((size_t)i0 * 256 + b) * 40;
#pragma unroll
    for (int rep = 0; rep < 5; ++rep) {
        const int c = rep * 256 + t;
        const int row = c / 10, q = c - row * 10;
        async_cp16(ub + (size_t)row * 10240 + q * 4, (char*)Ul8 + c * 16);
    }

    // phase 0: squash S_in -> Vl (redundant per block; 160 floats)
    if (t < 160) {
        const float x = S_in[b * 160 + t];
        float sq = x * x;
        sq += __shfl_xor(sq, 1, 16);
        sq += __shfl_xor(sq, 2, 16);
        sq += __shfl_xor(sq, 4, 16);
        sq += __shfl_xor(sq, 8, 16);
        const float norm = sqrtf(sq);
        const float f = (sq / (1.f + sq)) / (norm + 1e-7f);
        Vl[t] = x * f;
    }
    __syncthreads();                                  // drains async + Vl visible

    // p1a mapping: o = t%10 fixed per thread, strip s = t/10 (250 active)
    const int o = t % 10, s = t / 10;
    float vr[16];
    if (t < 250) {
#pragma unroll
        for (int q = 0; q < 4; ++q)
            *(float4*)&vr[q * 4] = *(const float4*)(&Vl[o * 16 + q * 4]);
    }

    // p1a: dots[i][o] = (1/64) * sum_d uq[i,o,d] * v[o,d]
    if (t < 250) {
#pragma unroll
        for (int rep = 0; rep < 6; ++rep) {
            const int i = s + 25 * rep;
            if (i < 128) {
                const uint4 uu = *(const uint4*)(Ul8 + i * 40 + o * 4);
                float f[16];
                fp8x4_dec(uu.x, f);
                fp8x4_dec(uu.y, f + 4);
                fp8x4_dec(uu.z, f + 8);
                fp8x4_dec(uu.w, f + 12);
                float dot = 0.f;
#pragma unroll
                for (int d = 0; d < 16; ++d) dot = fmaf(f[d], vr[d], dot);
                dots[i * 10 + o] = dot * UHAT_INV;
            }
        }
    }
    __syncthreads();

    // p1b: per-i logits + softmax -> cT[o][i]
    if (t < 128) {
        float bl[10];
#pragma unroll
        for (int oo = 0; oo < 10; ++oo) bl[oo] = dots[t * 10 + oo];
        if (ITER == 2) {
#pragma unroll
            for (int oo = 0; oo < 10; ++oo) bl[oo] += BL[(size_t)b * 11520 + oo * 1152 + i0 + t];
        } else {
#pragma unroll
            for (int oo = 0; oo < 10; ++oo) BL[(size_t)b * 11520 + oo * 1152 + i0 + t] = bl[oo];
        }
        float mx = bl[0];
#pragma unroll
        for (int oo = 1; oo < 10; ++oo) mx = fmaxf(mx, bl[oo]);
        float ex[10], sum = 0.f;
#pragma unroll
        for (int oo = 0; oo < 10; ++oo) { ex[oo] = expf(bl[oo] - mx); sum += ex[oo]; }
        const float inv = 1.f / sum;
#pragma unroll
        for (int oo = 0; oo < 10; ++oo) cT[oo * 132 + t] = ex[oo] * inv;
    }
    __syncthreads();

    // p2: S_out[b][160] += (1/64) * sum_i c[i][o] * uq[i][od]  (two 64-i halves)
    const int th = t & 127, hi = t >> 7;
    if (th < 40) {                                    // th = od-quad, o = th>>2
        const int oq = th >> 2;
        const unsigned int* base = Ul8 + hi * 64 * 40 + th;
        const float* cb = &cT[oq * 132 + hi * 64];
        float a0 = 0.f, a1 = 0.f, a2 = 0.f, a3 = 0.f;
#pragma unroll 4
        for (int ii = 0; ii < 64; ++ii) {
            const float c = cb[ii];
            float f[4];
            fp8x4_dec(base[ii * 40], f);
            a0 = fmaf(c, f[0], a0);
            a1 = fmaf(c, f[1], a1);
            a2 = fmaf(c, f[2], a2);
            a3 = fmaf(c, f[3], a3);
        }
        atomicAdd(&S_out[b * 160 + 4 * th + 0], a0 * UHAT_INV);
        atomicAdd(&S_out[b * 160 + 4 * th + 1], a1 * UHAT_INV);
        atomicAdd(&S_out[b * 160 + 4 * th + 2], a2 * UHAT_INV);
        atomicAdd(&S_out[b * 160 + 4 * th + 3], a3 * UHAT_INV);
    }
}

// ---------- final: squash S2 -> lengths, argmax + fused decoder layer 1 ----------
__global__ __launch_bounds__(512) void final_k(const float* __restrict__ S,
                                               const float* __restrict__ w1,
                                               const float* __restrict__ b1,
                                               float* __restrict__ out_len,
                                               float* __restrict__ h1d) {
    const int b = blockIdx.x, t = threadIdx.x;
    __shared__ float v_s[160];
    __shared__ float len_s[10];
    __shared__ int sel_s;
    if (t < 160) {
        const float x = S[b * 160 + t];
        float sq = x * x;
        sq += __shfl_xor(sq, 1, 16);
        sq += __shfl_xor(sq, 2, 16);
        sq += __shfl_xor(sq, 4, 16);
        sq += __shfl_xor(sq, 8, 16);
        const float norm = sqrtf(sq);
        const float f = (sq / (1.f + sq)) / (norm + 1e-7f);
        v_s[t] = x * f;
        if ((t & 15) == 0) {
            const float len = f * norm;
            len_s[t >> 4] = len;
            out_len[b * 10 + (t >> 4)] = len;
        }
    }
    __syncthreads();
    if (t == 0) {
        float best = len_s[0]; int bi = 0;
        for (int oo = 1; oo < 10; ++oo) if (len_s[oo] > best) { best = len_s[oo]; bi = oo; }
        sel_s = bi;
    }
    __syncthreads();
    const int s = sel_s;
    float acc = b1[t];
    const float* wrow = w1 + (size_t)(s * 16) * 512 + t;
#pragma unroll
    for (int j = 0; j < 16; ++j) acc = fmaf(v_s[s * 16 + j], wrow[j * 512], acc);
    h1d[(size_t)b * 512 + t] = fmaxf(acc, 0.f);
}

// ---------- decoder GEMM v3: 8m x 64n tile, per-wave K-split x4, ping-pong float4 B batches ----------
template <int ACT>
__global__ __launch_bounds__(256) void mlp3_k(const float* __restrict__ A,
                                              const float* __restrict__ Bm,
                                              const float* __restrict__ bias,
                                              float* __restrict__ C, int N, int K) {
    extern __shared__ float Asm[];                    // 8*(K+4) floats; tail-reused for reduce
    const int t = threadIdx.x;
    const int m0 = blockIdx.y * 8, n0 = blockIdx.x * 64;
    const int RS = K + 4;
    const int k4 = K >> 2;
    for (int i = t; i < 8 * k4; i += 256) {           // stage A tile, float4 units
        const int r = i / k4, c = i - r * k4;
        *(float4*)&Asm[r * RS + c * 4] = *(const float4*)&A[(size_t)(m0 + r) * K + c * 4];
    }
    __syncthreads();
    const int lane = t & 63, w = t >> 6;
    const int mq = lane >> 4, nq = lane & 15;
    const int n = n0 + nq * 4;
    const int ncl = (n + 3 < N) ? n : (N - 4);        // clamp base col (16B-aligned, safe)
    const float* bp = Bm + ncl;
    const float* asA = &Asm[(mq * 2 + 0) * RS];
    const float* asB = &Asm[(mq * 2 + 1) * RS];
    const int kQ = K >> 2;                            // per-wave chunk (128 or 256)
    const int kBeg = w * kQ;
    const int nBat2 = kQ >> 4;                        // double-batches of 16 k
    float4 acc0 = {0.f, 0.f, 0.f, 0.f}, acc1 = {0.f, 0.f, 0.f, 0.f};
    float4 ba[8], bb[8];
#pragma unroll
    for (int d = 0; d < 8; ++d) ba[d] = *(const float4*)&bp[(size_t)(kBeg + d) * N];

#define MLP3_FMA(BATCH, KB)                                                       \
    _Pragma("unroll")                                                             \
    for (int d = 0; d < 8; ++d) {                                                 \
        const float4 b = BATCH[d];                                                \
        const float a0 = asA[(KB) + d];                                           \
        const float a1 = asB[(KB) + d];                                           \
        acc0.x = fmaf(a0, b.x, acc0.x); acc0.y = fmaf(a0, b.y, acc0.y);           \
        acc0.z = fmaf(a0, b.z, acc0.z); acc0.w = fmaf(a0, b.w, acc0.w);           \
        acc1.x = fmaf(a1, b.x, acc1.x); acc1.y = fmaf(a1, b.y, acc1.y);           \
        acc1.z = fmaf(a1, b.z, acc1.z); acc1.w = fmaf(a1, b.w, acc1.w);           \
    }

    int k = kBeg;
#pragma unroll 1
    for (int it = 0; it < nBat2; ++it) {
#pragma unroll
        for (int d = 0; d < 8; ++d) bb[d] = *(const float4*)&bp[(size_t)(k + 8 + d) * N];
        MLP3_FMA(ba, k)
        if (it + 1 < nBat2) {
#pragma unroll
            for (int d = 0; d < 8; ++d) ba[d] = *(const float4*)&bp[(size_t)(k + 16 + d) * N];
        }
        MLP3_FMA(bb, k + 8)
        k += 16;
    }
#undef MLP3_FMA

    // cross-wave k-quarter reduce via LDS (reuses Asm; 4*64*8 floats = 8 KB)
    __syncthreads();                                  // all waves done reading Asm
    float* red = Asm;
    float* my = &red[(size_t)(w * 64 + lane) * 8];
    my[0] = acc0.x; my[1] = acc0.y; my[2] = acc0.z; my[3] = acc0.w;
    my[4] = acc1.x; my[5] = acc1.y; my[6] = acc1.z; my[7] = acc1.w;
    __syncthreads();
    if (t < 64) {
        float o[8];
#pragma unroll
        for (int x = 0; x < 8; ++x)
            o[x] = red[(size_t)t * 8 + x] + red[(size_t)(64 + t) * 8 + x]
                 + red[(size_t)(128 + t) * 8 + x] + red[(size_t)(192 + t) * 8 + x];
        const int nn = n0 + (t & 15) * 4;
#pragma unroll
        for (int rm = 0; rm < 2; ++rm) {
            const int m = m0 + (t >> 4) * 2 + rm;
#pragma unroll
            for (int rn = 0; rn < 4; ++rn) {
                const int ncol = nn + rn;
                if (ncol < N) {
                    float v = o[rm * 4 + rn] + bias[ncol];
                    if (ACT == 0) v = fmaxf(v, 0.f);
                    else v = 1.f / (1.f + expf(-v));
                    C[(size_t)m * N + ncol] = v;
                }
            }
        }
    }
}

// ---------- launcher ----------
extern "C" void kernel_launch(void* const* d_in, const int* in_sizes, int n_in,
                              void* d_out, int out_size, void* d_ws, size_t ws_size,
                              hipStream_t stream) {
    const float* x   = (const float*)d_in[0];
    const float* w1  = (const float*)d_in[1];
    const float* b1  = (const float*)d_in[2];
    const float* w2  = (const float*)d_in[3];
    const float* b2  = (const float*)d_in[4];
    const float* Wc  = (const float*)d_in[5];
    const float* dw1 = (const float*)d_in[6];
    const float* db1 = (const float*)d_in[7];
    const float* dw2 = (const float*)d_in[8];
    const float* db2 = (const float*)d_in[9];
    const float* dw3 = (const float*)d_in[10];
    const float* db3 = (const float*)d_in[11];
    float* out = (float*)d_out;

    char* ws = (char*)d_ws;
    unsigned char* H1T8 = (unsigned char*)(ws + 0);            // 26,214,400 B fp8
    unsigned char* W2T8 = (unsigned char*)(ws + 26214400);     //  5,308,416 B fp8 (x16)
    unsigned short* PART = (unsigned short*)(ws + 31522816);   // 18,874,368 B bf16, z=4
    unsigned int*   UHAT = (unsigned int*)(ws + 0);            // 47,185,920 B fp8 (aliases dead staging)
    float* U    = (float*)(ws + 50397184);                     //  9,437,184 B (after PART; dead after uhat_k)
    float* BL   = (float*)(ws + 59834368);                     // 11,796,480 B (live iter1->iter2)
    float* S012 = (float*)(ws + 71630848);                     //    491,520 B (zeroed by prep_k)
    float* H1D  = (float*)(ws + 59834368);                     //    524,288 B (dead-BL space, after iter2)
    float* H2D  = (float*)(ws + 60358656);                     //  1,048,576 B

    float* S0 = S012, *S1 = S012 + 40960, *S2 = S012 + 81920;

    prep_k<<<1024, 256, 0, stream>>>(x, w1, b1, w2, H1T8, W2T8, S012);
    conv2_k<<<576, 256, 0, stream>>>(H1T8, W2T8, PART);
    squash_u_k<<<512, 256, 0, stream>>>(PART, b2, U);
    uhat_k<<<1152, 256, 0, stream>>>(Wc, U, UHAT);
    route_iter0_k<<<dim3(256, 9), 256, 0, stream>>>(UHAT, S0);
    route_iter_k<1><<<dim3(256, 9), 256, 0, stream>>>(UHAT, S0, BL, S1);
    route_iter_k<2><<<dim3(256, 9), 256, 0, stream>>>(UHAT, S1, BL, S2);
    final_k<<<256, 512, 0, stream>>>(S2, dw1, db1, out, H1D);
    mlp3_k<0><<<dim3(16, 32), 256, 8 * 516 * 4, stream>>>(H1D, dw2, db2, H2D, 1024, 512);
    mlp3_k<1><<<dim3(13, 32), 256, 8 * 1028 * 4, stream>>>(H2D, dw3, db3, out + 2560, 784, 1024);
}

// Round 13
// 319.791 us; speedup vs baseline: 1.6202x; 1.0311x over previous
//
#include <hip/hip_runtime.h>
#include <cstdint>
#include <cstddef>

// ---------- types / helpers ----------
typedef __bf16 bf16x8 __attribute__((ext_vector_type(8)));
typedef short  shortx8 __attribute__((ext_vector_type(8)));
typedef float  floatx4 __attribute__((ext_vector_type(4)));
typedef float  floatx2 __attribute__((ext_vector_type(2)));
typedef float  floatx16 __attribute__((ext_vector_type(16)));
typedef int    intx4v __attribute__((ext_vector_type(4)));
typedef int    intx8 __attribute__((ext_vector_type(8)));
typedef unsigned short ushort8 __attribute__((ext_vector_type(8)));
typedef unsigned short ushort4v __attribute__((ext_vector_type(4)));

__device__ __forceinline__ float bflo(unsigned int u) {
    union { unsigned int u32; float f; } x; x.u32 = u << 16; return x.f;
}
__device__ __forceinline__ float bfhi(unsigned int u) {
    union { unsigned int u32; float f; } x; x.u32 = u & 0xffff0000u; return x.f;
}
__device__ __forceinline__ unsigned short f2bf(float f) {
    union { float f; unsigned int u; } x; x.f = f;
    unsigned int u = x.u;
    unsigned int r = (u + 0x7fffu + ((u >> 16) & 1u)) >> 16;   // RNE
    return (unsigned short)r;
}
__device__ __forceinline__ unsigned char f2fp8(float f) {
    unsigned int pk = __builtin_amdgcn_cvt_pk_fp8_f32(f, f, 0, false);
    return (unsigned char)(pk & 0xff);
}
// decode 4 fp8(e4m3) packed in u32 -> 4 floats
__device__ __forceinline__ void fp8x4_dec(unsigned int u, float* f) {
    floatx2 lo = __builtin_amdgcn_cvt_pk_f32_fp8(u, false);
    floatx2 hi = __builtin_amdgcn_cvt_pk_f32_fp8(u, true);
    f[0] = lo[0]; f[1] = lo[1]; f[2] = hi[0]; f[3] = hi[1];
}

#define GLOBAL_U32 const __attribute__((address_space(1))) unsigned int*
#define LDS_U32 __attribute__((address_space(3))) unsigned int*
__device__ __forceinline__ void async_cp16(const void* g, void* l) {
    __builtin_amdgcn_global_load_lds((GLOBAL_U32)g, (LDS_U32)l, 16, 0, 0);
}

#define UHAT_SCALE 64.0f
#define UHAT_INV   (1.0f / 64.0f)
#define W2_SCALE   16.0f
#define W2_INV     (1.0f / 16.0f)

// ---------- prep: conv1 via bf16 MFMA (blocks 0..511) + w2t fp8 (512..1023) ----------
__global__ __launch_bounds__(256) void prep_k(const float* __restrict__ x,
                                              const float* __restrict__ w1c,
                                              const float* __restrict__ b1c,
                                              const float* __restrict__ w2,
                                              unsigned char* __restrict__ h1t8,
                                              unsigned char* __restrict__ w2t8) {
    const int blk = blockIdx.x, t = threadIdx.x;
    if (blk < 512) {
        // block = (image b, ch-half): M=400 spatial, N=128 ch, K=96 (81 real taps)
        __shared__ float xs[1024];                    // 28x28 image + zero pad
        __shared__ unsigned short wb[96 * 132];       // [tap][ch-local] bf16, stride 132
        const int b = blk >> 1, ch0 = (blk & 1) * 128;
        for (int i = t; i < 1024; i += 256) xs[i] = (i < 784) ? x[b * 784 + i] : 0.f;
        for (int i = t; i < 96 * 132; i += 256) wb[i] = 0;
        __syncthreads();
        for (int i = t; i < 81 * 128; i += 256) {
            const int tap = i >> 7, chl = i & 127;
            wb[tap * 132 + chl] = f2bf(w1c[(size_t)(ch0 + chl) * 81 + tap]);
        }
        __syncthreads();
        const int lane = t & 63, l15 = lane & 15, g = lane >> 4;
        const int wave = t >> 6;
        const int n0l = wave * 32;                    // wave owns 32 local ch (2 N-tiles)
        int xoff[3][8];
#pragma unroll
        for (int kk = 0; kk < 3; ++kk)
#pragma unroll
            for (int e = 0; e < 8; ++e) {
                const int tap = kk * 32 + g * 8 + e;
                const int kh = tap / 9, kw = tap - 9 * kh;
                xoff[kk][e] = kh * 28 + kw;
            }
        shortx8 bF[2][3];
#pragma unroll
        for (int nt = 0; nt < 2; ++nt)
#pragma unroll
            for (int kk = 0; kk < 3; ++kk) {
                shortx8 v;
#pragma unroll
                for (int e = 0; e < 8; ++e) {
                    const int tap = kk * 32 + g * 8 + e;
                    v[e] = (short)wb[tap * 132 + n0l + nt * 16 + l15];
                }
                bF[nt][kk] = v;
            }
        float bv[2][4];
#pragma unroll
        for (int nt = 0; nt < 2; ++nt)
#pragma unroll
            for (int r = 0; r < 4; ++r)
                bv[nt][r] = b1c[ch0 + n0l + nt * 16 + g * 4 + r];
        for (int mt = 0; mt < 25; ++mt) {
            const int s = mt * 16 + l15;              // spatial: A-load row AND D col
            const int oh = s / 20, ow = s - 20 * oh;
            const int s2 = oh * 28 + ow;
            shortx8 aF[3];
#pragma unroll
            for (int kk = 0; kk < 3; ++kk) {
                shortx8 v;
#pragma unroll
                for (int e = 0; e < 8; ++e) v[e] = (short)f2bf(xs[s2 + xoff[kk][e]]);
                aF[kk] = v;
            }
            const size_t sbase = ((size_t)(b * 20 + oh) * 20 + ow) * 256 + ch0 + n0l + g * 4;
#pragma unroll
            for (int nt = 0; nt < 2; ++nt) {
                floatx4 acc = (floatx4){0.f, 0.f, 0.f, 0.f};
#pragma unroll
                for (int kk = 0; kk < 3; ++kk)
                    acc = __builtin_amdgcn_mfma_f32_16x16x32_bf16(bF[nt][kk], aF[kk], acc, 0, 0, 0);
                unsigned int w = 0;
                w = __builtin_amdgcn_cvt_pk_fp8_f32(acc[0] + bv[nt][0], acc[1] + bv[nt][1], w, false);
                w = __builtin_amdgcn_cvt_pk_fp8_f32(acc[2] + bv[nt][2], acc[3] + bv[nt][3], w, true);
                *(unsigned int*)(h1t8 + sbase + nt * 16) = w;
            }
        }
    } else {
        // w2 transform: OIHW fp32 [oc][ic][81] -> fp8 [oc][tap*256+ic], x16 scale
        __shared__ float shm[10368];
        const int id = blk - 512;
        const int oc = id >> 1, half = id & 1;
        const float* src = w2 + (size_t)oc * 20736 + half * 128 * 81;
        for (int idx = t; idx < 10368; idx += 256) shm[idx] = src[idx];
        __syncthreads();
        unsigned char* dst = w2t8 + (size_t)oc * 20736 + half * 128;
        for (int idx = t; idx < 10368; idx += 256) {
            const int tap = idx >> 7, icl = idx & 127;
            dst[tap * 256 + icl] = f2fp8(shm[icl * 81 + tap] * W2_SCALE);
        }
    }
}

// ---------- conv2 implicit GEMM, MX-scaled fp8 MFMA (unit scales): proven-best structure ----------
__device__ __forceinline__ int c2_rowbase(int m) {
    const int b = m / 36, sp = m % 36;
    const int oh = sp / 6, ow = sp % 6;
    return (b * 400 + oh * 40 + ow * 2) * 256;        // byte offset into h1t8 (1 B/elem)
}

__global__ __launch_bounds__(256) void conv2_k(const unsigned char* __restrict__ h1t8,
                                               const unsigned char* __restrict__ w2t8,
                                               unsigned short* __restrict__ part) {
    const int t = threadIdx.x;
    const int id = blockIdx.x;                        // 0..575
    const int G = id >> 4;                            // 0..35
    const int bx = (id >> 3) & 1;                     // 0..1 (128-oc tile)
    const int s = id & 7;
    const int by = 2 * G + (s >> 2);                  // 0..71
    const int z  = ((s & 3) + by) & 3;                // 0..3
    __shared__ unsigned char At[128 * 128];           // m rows, 128 fp8 (16 KB)
    __shared__ unsigned char Bt[128 * 128];           // oc rows (16 KB)

    const int oc0 = bx * 128;

    int aRB[4], bBase[4];
#pragma unroll
    for (int k = 0; k < 4; ++k) {
        const int a = t + 256 * k;
        const int r = a >> 3, sg = a & 7;
        const int u = sg ^ (r & 7);
        aRB[k] = c2_rowbase(by * 128 + r) + u * 16;
        bBase[k] = (oc0 + r) * 20736 + u * 16;
    }

    const int lane = t & 63, l31 = lane & 31, h = lane >> 5;
    const int wave = t >> 6;
    const int wM = (wave & 1) * 64, wOC = (wave >> 1) * 64;

    int aO[2][2][2], bO[2][2][2];
#pragma unroll
    for (int i = 0; i < 2; ++i) {
        const int Ra = wOC + i * 32 + l31;            // oc row (A-operand from Bt)
        const int Rb = wM + i * 32 + l31;             // m row  (B-operand from At)
#pragma unroll
        for (int st = 0; st < 2; ++st)
#pragma unroll
            for (int p = 0; p < 2; ++p) {
                const int c = st * 4 + h * 2 + p;
                aO[st][i][p] = Ra * 128 + ((c ^ (Ra & 7)) << 4);
                bO[st][i][p] = Rb * 128 + ((c ^ (Rb & 7)) << 4);
            }
    }

    floatx16 acc[2][2];                               // [oc-tile][m-tile]
#pragma unroll
    for (int i = 0; i < 2; ++i)
#pragma unroll
        for (int j = 0; j < 2; ++j)
#pragma unroll
            for (int r = 0; r < 16; ++r) acc[i][j][r] = 0.f;

    const int q0 = (162 * z) >> 2, q1 = (162 * (z + 1)) >> 2;
    for (int q = q0; q < q1; ++q) {
        const int tap = q >> 1;                       // BK=128 = half a tap; never crosses
        const int kh = tap / 9, kw = tap - 9 * kh;
        const int aoffB = (kh * 20 + kw) * 256 + (q & 1) * 128;
        __syncthreads();
#pragma unroll
        for (int k = 0; k < 4; ++k)
            async_cp16(h1t8 + aRB[k] + aoffB, At + (t + 256 * k) * 16);
#pragma unroll
        for (int k = 0; k < 4; ++k)
            async_cp16(w2t8 + bBase[k] + q * 128, Bt + (t + 256 * k) * 16);
        __syncthreads();
#pragma unroll
        for (int st = 0; st < 2; ++st) {
            intx8 aF[2], bF[2];
#pragma unroll
            for (int i = 0; i < 2; ++i) {
                const intx4v alo = *(const intx4v*)(Bt + aO[st][i][0]);
                const intx4v ahi = *(const intx4v*)(Bt + aO[st][i][1]);
                aF[i] = (intx8){alo[0], alo[1], alo[2], alo[3], ahi[0], ahi[1], ahi[2], ahi[3]};
                const intx4v blo = *(const intx4v*)(At + bO[st][i][0]);
                const intx4v bhi = *(const intx4v*)(At + bO[st][i][1]);
                bF[i] = (intx8){blo[0], blo[1], blo[2], blo[3], bhi[0], bhi[1], bhi[2], bhi[3]};
            }
#pragma unroll
            for (int i = 0; i < 2; ++i)
#pragma unroll
                for (int j = 0; j < 2; ++j)
                    acc[i][j] = __builtin_amdgcn_mfma_scale_f32_32x32x64_f8f6f4(
                        aF[i], bF[j], acc[i][j], 0, 0, 0, 127, 0, 127);
        }
    }

    // epilogue: D col(lane&31)=m, row=(reg&3)+8*(reg>>2)+4*h = oc; undo W2 scale
    unsigned short* pz = part + (size_t)z * 2359296;
#pragma unroll
    for (int i = 0; i < 2; ++i) {
#pragma unroll
        for (int j = 0; j < 2; ++j) {
            const int m = by * 128 + wM + j * 32 + l31;
#pragma unroll
            for (int rg = 0; rg < 4; ++rg) {
                const int oc = oc0 + wOC + i * 32 + rg * 8 + 4 * h;
                ushort4v pk;
#pragma unroll
                for (int rr = 0; rr < 4; ++rr) pk[rr] = f2bf(acc[i][j][rg * 4 + rr] * W2_INV);
                *(ushort4v*)(pz + (size_t)m * 256 + oc) = pk;
            }
        }
    }
}

// ---------- reduce split-K(bf16 x4) + bias + squash(axis=w) -> u[b][1152][8] (half-split x2) ----------
__global__ __launch_bounds__(256) void squash_u_k(const unsigned short* __restrict__ part,
                                                  const float* __restrict__ bias,
                                                  float* __restrict__ u) {
    const int bb = blockIdx.x, t = threadIdx.x;
    const int b = bb >> 1, h = bb & 1;
    __shared__ float hs[4608];
    const size_t base = (size_t)b * 9216 + h * 4608;
    for (int q = t; q < 2304; q += 256) {
        const int idx = q * 2;
        float v0 = bias[idx & 255], v1 = bias[(idx + 1) & 255];
#pragma unroll
        for (int z = 0; z < 4; ++z) {
            const unsigned int uu = *(const unsigned int*)(part + (size_t)z * 2359296 + base + idx);
            v0 += bflo(uu);
            v1 += bfhi(uu);
        }
        hs[idx] = v0; hs[idx + 1] = v1;
    }
    __syncthreads();
    for (int gq = t; gq < 768; gq += 256) {           // groups (c, oh-local), squash over ow(6)
        const int c = gq / 3, ohl = gq % 3;
        const int oh = h * 3 + ohl;
        float s[6], sq = 0.f;
#pragma unroll
        for (int ow = 0; ow < 6; ++ow) { s[ow] = hs[(ohl * 6 + ow) * 256 + c]; sq = fmaf(s[ow], s[ow], sq); }
        const float norm = sqrtf(sq);
        const float f = (sq / (1.0f + sq)) / (norm + 1e-7f);
        float* up = u + (size_t)b * 9216 + c * 36 + oh * 6;
#pragma unroll
        for (int ow = 0; ow < 6; ++ow) up[ow] = s[ow] * f;
    }
}

// ---------- u_hat fp8: uhat8[i][b][40 u32] = e4m3(64 * W_i u_b); LDS-staged coalesced write ----------
__global__ __launch_bounds__(256) void uhat_k(const float* __restrict__ Wc,
                                              const float* __restrict__ u,
                                              unsigned int* __restrict__ uhat8) {
    const int i = blockIdx.x, t = threadIdx.x;       // t = b
    __shared__ float Wl[1280];                       // [o][d*8+e]
    __shared__ __align__(16) unsigned int Ust[256 * 40];   // 40 KB staging
    for (int idx = t; idx < 1280; idx += 256) {
        const int o = idx >> 7, r = idx & 127;
        Wl[idx] = Wc[((size_t)o * 1152 + i) * 128 + r];
    }
    float ur[8];
    *(float4*)&ur[0] = *(const float4*)(u + (size_t)t * 9216 + i * 8);
    *(float4*)&ur[4] = *(const float4*)(u + (size_t)t * 9216 + i * 8 + 4);
    __syncthreads();
    unsigned int* myrow = Ust + t * 40;
#pragma unroll 1
    for (int o = 0; o < 10; ++o) {
        float vals[16];
#pragma unroll
        for (int d = 0; d < 16; ++d) {
            const float* wp = &Wl[o * 128 + d * 8];
            float a = 0.f;
#pragma unroll
            for (int e = 0; e < 8; ++e) a = fmaf(wp[e], ur[e], a);
            vals[d] = a * UHAT_SCALE;
        }
        uint4 pk;
        unsigned int w;
#pragma unroll
        for (int q = 0; q < 4; ++q) {
            w = 0;
            w = __builtin_amdgcn_cvt_pk_fp8_f32(vals[q * 4 + 0], vals[q * 4 + 1], w, false);
            w = __builtin_amdgcn_cvt_pk_fp8_f32(vals[q * 4 + 2], vals[q * 4 + 3], w, true);
            if (q == 0) pk.x = w; else if (q == 1) pk.y = w; else if (q == 2) pk.z = w; else pk.w = w;
        }
        *(uint4*)(myrow + o * 4) = pk;
    }
    __syncthreads();
    // linear copy-out: block-i region is contiguous (i*10240 u32); 2560 uint4 units
    unsigned int* gbase = uhat8 + (size_t)i * 10240;
    for (int u2 = t; u2 < 2560; u2 += 256)
        *(uint4*)(gbase + (size_t)u2 * 4) = *(const uint4*)(Ust + u2 * 4);
}

// ---------- fused routing (all 3 iterations), one block per batch image b ----------
// Routing is independent per b. S and v live in LDS; UHAT streamed 3x in 128-i chunks
// via double-buffered async staging (prefetch issued before compute phases). Logits BL
// stay in global (coalesced, same layout/precision as the split kernels).
__global__ __launch_bounds__(256) void route_all_k(const unsigned int* __restrict__ uhat8,
                                                   float* __restrict__ BL,
                                                   float* __restrict__ S2out) {
    const int b = blockIdx.x, t = threadIdx.x;
    __shared__ __align__(16) unsigned int Ul8[2][128 * 40];  // 2 x 20.5 KB chunk buffers
    __shared__ float Vl[160];
    __shared__ float cT[10 * 132];
    __shared__ float dots[128 * 10];                  // p1a output; reused as reduce scratch (960)

    // p2 roles: 240 active lanes = 3 k-segments x 2 halves x 40 od-quads
    const int seg = t / 80, rr = t - seg * 80;
    const int hi = rr / 40, th = rr - hi * 40;
    const int oq = th >> 2;
    const bool p2act = (t < 240);
    const int lo = (seg * 64) / 3, hiE = ((seg + 1) * 64) / 3;   // 0-21,21-42,42-64
    // p1a roles
    const int o = t % 10, sidx = t / 10;

    auto stage = [&](int buf, int chunk) {
        const unsigned int* ub = uhat8 + ((size_t)(chunk * 128) * 256 + b) * 40;
#pragma unroll
        for (int rep = 0; rep < 5; ++rep) {
            const int c = rep * 256 + t;
            const int row = c / 10, q = c - row * 10;
            async_cp16(ub + (size_t)row * 10240 + q * 4, (char*)Ul8[buf] + c * 16);
        }
    };

    // ---- iteration 0: S0 = (0.1/64) * sum_i dec(uhat) ----
    float a0 = 0.f, a1 = 0.f, a2 = 0.f, a3 = 0.f;
    stage(0, 0);
    __syncthreads();
    for (int ck = 0; ck < 9; ++ck) {
        const int cur = ck & 1;
        if (ck + 1 < 9) stage(cur ^ 1, ck + 1);
        if (p2act) {
            const unsigned int* base = Ul8[cur] + hi * 64 * 40 + th;
            for (int ii = lo; ii < hiE; ++ii) {
                float f[4];
                fp8x4_dec(base[ii * 40], f);
                a0 += f[0]; a1 += f[1]; a2 += f[2]; a3 += f[3];
            }
        }
        __syncthreads();                              // buf[cur] free + prefetch landed
    }
    if (p2act) {
        float* red = dots;
        const int rb = seg * 320 + hi * 160 + 4 * th;
        red[rb + 0] = a0; red[rb + 1] = a1; red[rb + 2] = a2; red[rb + 3] = a3;
    }
    __syncthreads();
    if (t < 160) {
        const float xv = 0.1f * UHAT_INV *
            (dots[t] + dots[160 + t] + dots[320 + t] + dots[480 + t] + dots[640 + t] + dots[800 + t]);
        float sq = xv * xv;
        sq += __shfl_xor(sq, 1, 16);
        sq += __shfl_xor(sq, 2, 16);
        sq += __shfl_xor(sq, 4, 16);
        sq += __shfl_xor(sq, 8, 16);
        const float norm = sqrtf(sq);
        const float f = (sq / (1.f + sq)) / (norm + 1e-7f);
        Vl[t] = xv * f;
    }
    __syncthreads();

    // ---- iterations 1 and 2 ----
    for (int it = 1; it <= 2; ++it) {
        float vr[16];
        if (t < 250) {
#pragma unroll
            for (int q = 0; q < 4; ++q)
                *(float4*)&vr[q * 4] = *(const float4*)(&Vl[o * 16 + q * 4]);
        }
        a0 = a1 = a2 = a3 = 0.f;
        stage(0, 0);
        __syncthreads();
        for (int ck = 0; ck < 9; ++ck) {
            const int cur = ck & 1;
            if (ck + 1 < 9) stage(cur ^ 1, ck + 1);
            // p1a: dots[i][o] = (1/64) * uhat[i,o,:] . v[o,:]
            if (t < 250) {
#pragma unroll
                for (int rep = 0; rep < 6; ++rep) {
                    const int i = sidx + 25 * rep;
                    if (i < 128) {
                        const uint4 uu = *(const uint4*)(Ul8[cur] + i * 40 + o * 4);
                        float f[16];
                        fp8x4_dec(uu.x, f);
                        fp8x4_dec(uu.y, f + 4);
                        fp8x4_dec(uu.z, f + 8);
                        fp8x4_dec(uu.w, f + 12);
                        float dot = 0.f;
#pragma unroll
                        for (int d = 0; d < 16; ++d) dot = fmaf(f[d], vr[d], dot);
                        dots[i * 10 + o] = dot * UHAT_INV;
                    }
                }
            }
            __syncthreads();
            // p1b: logits + softmax -> cT[o][i_local]
            if (t < 128) {
                float bl[10];
#pragma unroll
                for (int oo = 0; oo < 10; ++oo) bl[oo] = dots[t * 10 + oo];
                const size_t blb = (size_t)b * 11520 + (size_t)ck * 128 + t;
                if (it == 1) {
#pragma unroll
                    for (int oo = 0; oo < 10; ++oo) BL[blb + (size_t)oo * 1152] = bl[oo];
                } else {
#pragma unroll
                    for (int oo = 0; oo < 10; ++oo) bl[oo] += BL[blb + (size_t)oo * 1152];
                }
                float mx = bl[0];
#pragma unroll
                for (int oo = 1; oo < 10; ++oo) mx = fmaxf(mx, bl[oo]);
                float ex[10], sum = 0.f;
#pragma unroll
                for (int oo = 0; oo < 10; ++oo) { ex[oo] = expf(bl[oo] - mx); sum += ex[oo]; }
                const float inv = 1.f / sum;
#pragma unroll
                for (int oo = 0; oo < 10; ++oo) cT[oo * 132 + t] = ex[oo] * inv;
            }
            __syncthreads();
            // p2: accumulate S += c[i][o] * dec(uhat[i][od])
            if (p2act) {
                const unsigned int* base = Ul8[cur] + hi * 64 * 40 + th;
                const float* cb = &cT[oq * 132 + hi * 64];
                for (int ii = lo; ii < hiE; ++ii) {
                    const float c = cb[ii];
                    float f[4];
                    fp8x4_dec(base[ii * 40], f);
                    a0 = fmaf(c, f[0], a0);
                    a1 = fmaf(c, f[1], a1);
                    a2 = fmaf(c, f[2], a2);
                    a3 = fmaf(c, f[3], a3);
                }
            }
            __syncthreads();
        }
        if (p2act) {
            float* red = dots;
            const int rb = seg * 320 + hi * 160 + 4 * th;
            red[rb + 0] = a0; red[rb + 1] = a1; red[rb + 2] = a2; red[rb + 3] = a3;
        }
        __syncthreads();
        if (t < 160) {
            const float sv = UHAT_INV *
                (dots[t] + dots[160 + t] + dots[320 + t] + dots[480 + t] + dots[640 + t] + dots[800 + t]);
            if (it == 1) {
                float sq = sv * sv;
                sq += __shfl_xor(sq, 1, 16);
                sq += __shfl_xor(sq, 2, 16);
                sq += __shfl_xor(sq, 4, 16);
                sq += __shfl_xor(sq, 8, 16);
                const float norm = sqrtf(sq);
                const float f = (sq / (1.f + sq)) / (norm + 1e-7f);
                Vl[t] = sv * f;
            } else {
                S2out[b * 160 + t] = sv;
            }
        }
        __syncthreads();
    }
}

// ---------- final: squash S2 -> lengths, argmax + fused decoder layer 1 ----------
__global__ __launch_bounds__(512) void final_k(const float* __restrict__ S,
                                               const float* __restrict__ w1,
                                               const float* __restrict__ b1,
                                               float* __restrict__ out_len,
                                               float* __restrict__ h1d) {
    const int b = blockIdx.x, t = threadIdx.x;
    __shared__ float v_s[160];
    __shared__ float len_s[10];
    __shared__ int sel_s;
    if (t < 160) {
        const float x = S[b * 160 + t];
        float sq = x * x;
        sq += __shfl_xor(sq, 1, 16);
        sq += __shfl_xor(sq, 2, 16);
        sq += __shfl_xor(sq, 4, 16);
        sq += __shfl_xor(sq, 8, 16);
        const float norm = sqrtf(sq);
        const float f = (sq / (1.f + sq)) / (norm + 1e-7f);
        v_s[t] = x * f;
        if ((t & 15) == 0) {
            const float len = f * norm;
            len_s[t >> 4] = len;
            out_len[b * 10 + (t >> 4)] = len;
        }
    }
    __syncthreads();
    if (t == 0) {
        float best = len_s[0]; int bi = 0;
        for (int oo = 1; oo < 10; ++oo) if (len_s[oo] > best) { best = len_s[oo]; bi = oo; }
        sel_s = bi;
    }
    __syncthreads();
    const int s = sel_s;
    float acc = b1[t];
    const float* wrow = w1 + (size_t)(s * 16) * 512 + t;
#pragma unroll
    for (int j = 0; j < 16; ++j) acc = fmaf(v_s[s * 16 + j], wrow[j * 512], acc);
    h1d[(size_t)b * 512 + t] = fmaxf(acc, 0.f);
}

// ---------- decoder GEMM v3: 8m x 64n tile, per-wave K-split x4, ping-pong float4 B batches ----------
template <int ACT>
__global__ __launch_bounds__(256) void mlp3_k(const float* __restrict__ A,
                                              const float* __restrict__ Bm,
                                              const float* __restrict__ bias,
                                              float* __restrict__ C, int N, int K) {
    extern __shared__ float Asm[];                    // 8*(K+4) floats; tail-reused for reduce
    const int t = threadIdx.x;
    const int m0 = blockIdx.y * 8, n0 = blockIdx.x * 64;
    const int RS = K + 4;
    const int k4 = K >> 2;
    for (int i = t; i < 8 * k4; i += 256) {           // stage A tile, float4 units
        const int r = i / k4, c = i - r * k4;
        *(float4*)&Asm[r * RS + c * 4] = *(const float4*)&A[(size_t)(m0 + r) * K + c * 4];
    }
    __syncthreads();
    const int lane = t & 63, w = t >> 6;
    const int mq = lane >> 4, nq = lane & 15;
    const int n = n0 + nq * 4;
    const int ncl = (n + 3 < N) ? n : (N - 4);        // clamp base col (16B-aligned, safe)
    const float* bp = Bm + ncl;
    const float* asA = &Asm[(mq * 2 + 0) * RS];
    const float* asB = &Asm[(mq * 2 + 1) * RS];
    const int kQ = K >> 2;                            // per-wave chunk (128 or 256)
    const int kBeg = w * kQ;
    const int nBat2 = kQ >> 4;                        // double-batches of 16 k
    float4 acc0 = {0.f, 0.f, 0.f, 0.f}, acc1 = {0.f, 0.f, 0.f, 0.f};
    float4 ba[8], bb[8];
#pragma unroll
    for (int d = 0; d < 8; ++d) ba[d] = *(const float4*)&bp[(size_t)(kBeg + d) * N];

#define MLP3_FMA(BATCH, KB)                                                       \
    _Pragma("unroll")                                                             \
    for (int d = 0; d < 8; ++d) {                                                 \
        const float4 b = BATCH[d];                                                \
        const float a0 = asA[(KB) + d];                                           \
        const float a1 = asB[(KB) + d];                                           \
        acc0.x = fmaf(a0, b.x, acc0.x); acc0.y = fmaf(a0, b.y, acc0.y);           \
        acc0.z = fmaf(a0, b.z, acc0.z); acc0.w = fmaf(a0, b.w, acc0.w);           \
        acc1.x = fmaf(a1, b.x, acc1.x); acc1.y = fmaf(a1, b.y, acc1.y);           \
        acc1.z = fmaf(a1, b.z, acc1.z); acc1.w = fmaf(a1, b.w, acc1.w);           \
    }

    int k = kBeg;
#pragma unroll 1
    for (int it = 0; it < nBat2; ++it) {
#pragma unroll
        for (int d = 0; d < 8; ++d) bb[d] = *(const float4*)&bp[(size_t)(k + 8 + d) * N];
        MLP3_FMA(ba, k)
        if (it + 1 < nBat2) {
#pragma unroll
            for (int d = 0; d < 8; ++d) ba[d] = *(const float4*)&bp[(size_t)(k + 16 + d) * N];
        }
        MLP3_FMA(bb, k + 8)
        k += 16;
    }
#undef MLP3_FMA

    // cross-wave k-quarter reduce via LDS (reuses Asm; 4*64*8 floats = 8 KB)
    __syncthreads();                                  // all waves done reading Asm
    float* red = Asm;
    float* my = &red[(size_t)(w * 64 + lane) * 8];
    my[0] = acc0.x; my[1] = acc0.y; my[2] = acc0.z; my[3] = acc0.w;
    my[4] = acc1.x; my[5] = acc1.y; my[6] = acc1.z; my[7] = acc1.w;
    __syncthreads();
    if (t < 64) {
        float o[8];
#pragma unroll
        for (int x = 0; x < 8; ++x)
            o[x] = red[(size_t)t * 8 + x] + red[(size_t)(64 + t) * 8 + x]
                 + red[(size_t)(128 + t) * 8 + x] + red[(size_t)(192 + t) * 8 + x];
        const int nn = n0 + (t & 15) * 4;
#pragma unroll
        for (int rm = 0; rm < 2; ++rm) {
            const int m = m0 + (t >> 4) * 2 + rm;
#pragma unroll
            for (int rn = 0; rn < 4; ++rn) {
                const int ncol = nn + rn;
                if (ncol < N) {
                    float v = o[rm * 4 + rn] + bias[ncol];
                    if (ACT == 0) v = fmaxf(v, 0.f);
                    else v = 1.f / (1.f + expf(-v));
                    C[(size_t)m * N + ncol] = v;
                }
            }
        }
    }
}

// ---------- launcher ----------
extern "C" void kernel_launch(void* const* d_in, const int* in_sizes, int n_in,
                              void* d_out, int out_size, void* d_ws, size_t ws_size,
                              hipStream_t stream) {
    const float* x   = (const float*)d_in[0];
    const float* w1  = (const float*)d_in[1];
    const float* b1  = (const float*)d_in[2];
    const float* w2  = (const float*)d_in[3];
    const float* b2  = (const float*)d_in[4];
    const float* Wc  = (const float*)d_in[5];
    const float* dw1 = (const float*)d_in[6];
    const float* db1 = (const float*)d_in[7];
    const float* dw2 = (const float*)d_in[8];
    const float* db2 = (const float*)d_in[9];
    const float* dw3 = (const float*)d_in[10];
    const float* db3 = (const float*)d_in[11];
    float* out = (float*)d_out;

    char* ws = (char*)d_ws;
    unsigned char* H1T8 = (unsigned char*)(ws + 0);            // 26,214,400 B fp8
    unsigned char* W2T8 = (unsigned char*)(ws + 26214400);     //  5,308,416 B fp8 (x16)
    unsigned short* PART = (unsigned short*)(ws + 31522816);   // 18,874,368 B bf16, z=4
    unsigned int*   UHAT = (unsigned int*)(ws + 0);            // 47,185,920 B fp8 (aliases dead staging)
    float* U    = (float*)(ws + 50397184);                     //  9,437,184 B (after PART; dead after uhat_k)
    float* BL   = (float*)(ws + 59834368);                     // 11,796,480 B (live within route_all)
    float* S2   = (float*)(ws + 71958528);                     //    163,840 B (written by route_all)
    float* H1D  = (float*)(ws + 59834368);                     //    524,288 B (dead-BL space, after route_all)
    float* H2D  = (float*)(ws + 60358656);                     //  1,048,576 B

    prep_k<<<1024, 256, 0, stream>>>(x, w1, b1, w2, H1T8, W2T8);
    conv2_k<<<576, 256, 0, stream>>>(H1T8, W2T8, PART);
    squash_u_k<<<512, 256, 0, stream>>>(PART, b2, U);
    uhat_k<<<1152, 256, 0, stream>>>(Wc, U, UHAT);
    route_all_k<<<256, 256, 0, stream>>>(UHAT, BL, S2);
    final_k<<<256, 512, 0, stream>>>(S2, dw1, db1, out, H1D);
    mlp3_k<0><<<dim3(16, 32), 256, 8 * 516 * 4, stream>>>(H1D, dw2, db2, H2D, 1024, 512);
    mlp3_k<1><<<dim3(13, 32), 256, 8 * 1028 * 4, stream>>>(H2D, dw3, db3, out + 2560, 784, 1024);
}

// Round 14
// 313.091 us; speedup vs baseline: 1.6549x; 1.0214x over previous
//
#include <hip/hip_runtime.h>
#include <cstdint>
#include <cstddef>

// ---------- types / helpers ----------
typedef __bf16 bf16x8 __attribute__((ext_vector_type(8)));
typedef short  shortx8 __attribute__((ext_vector_type(8)));
typedef float  floatx4 __attribute__((ext_vector_type(4)));
typedef float  floatx2 __attribute__((ext_vector_type(2)));
typedef float  floatx16 __attribute__((ext_vector_type(16)));
typedef int    intx4v __attribute__((ext_vector_type(4)));
typedef int    intx8 __attribute__((ext_vector_type(8)));
typedef unsigned short ushort8 __attribute__((ext_vector_type(8)));
typedef unsigned short ushort4v __attribute__((ext_vector_type(4)));

__device__ __forceinline__ float bflo(unsigned int u) {
    union { unsigned int u32; float f; } x; x.u32 = u << 16; return x.f;
}
__device__ __forceinline__ float bfhi(unsigned int u) {
    union { unsigned int u32; float f; } x; x.u32 = u & 0xffff0000u; return x.f;
}
__device__ __forceinline__ unsigned short f2bf(float f) {
    union { float f; unsigned int u; } x; x.f = f;
    unsigned int u = x.u;
    unsigned int r = (u + 0x7fffu + ((u >> 16) & 1u)) >> 16;   // RNE
    return (unsigned short)r;
}
__device__ __forceinline__ unsigned char f2fp8(float f) {
    unsigned int pk = __builtin_amdgcn_cvt_pk_fp8_f32(f, f, 0, false);
    return (unsigned char)(pk & 0xff);
}
// decode 4 fp8(e4m3) packed in u32 -> 4 floats
__device__ __forceinline__ void fp8x4_dec(unsigned int u, float* f) {
    floatx2 lo = __builtin_amdgcn_cvt_pk_f32_fp8(u, false);
    floatx2 hi = __builtin_amdgcn_cvt_pk_f32_fp8(u, true);
    f[0] = lo[0]; f[1] = lo[1]; f[2] = hi[0]; f[3] = hi[1];
}

#define GLOBAL_U32 const __attribute__((address_space(1))) unsigned int*
#define LDS_U32 __attribute__((address_space(3))) unsigned int*
__device__ __forceinline__ void async_cp16(const void* g, void* l) {
    __builtin_amdgcn_global_load_lds((GLOBAL_U32)g, (LDS_U32)l, 16, 0, 0);
}

#define UHAT_SCALE 64.0f
#define UHAT_INV   (1.0f / 64.0f)
#define W2_SCALE   16.0f
#define W2_INV     (1.0f / 16.0f)

// ---------- prep: conv1 via bf16 MFMA (blocks 0..511) + w2t fp8 (512..1023) ----------
__global__ __launch_bounds__(256) void prep_k(const float* __restrict__ x,
                                              const float* __restrict__ w1c,
                                              const float* __restrict__ b1c,
                                              const float* __restrict__ w2,
                                              unsigned char* __restrict__ h1t8,
                                              unsigned char* __restrict__ w2t8) {
    const int blk = blockIdx.x, t = threadIdx.x;
    if (blk < 512) {
        // block = (image b, ch-half): M=400 spatial, N=128 ch, K=96 (81 real taps)
        __shared__ float xs[1024];                    // 28x28 image + zero pad
        __shared__ unsigned short wb[96 * 132];       // [tap][ch-local] bf16, stride 132
        const int b = blk >> 1, ch0 = (blk & 1) * 128;
        for (int i = t; i < 1024; i += 256) xs[i] = (i < 784) ? x[b * 784 + i] : 0.f;
        for (int i = t; i < 96 * 132; i += 256) wb[i] = 0;
        __syncthreads();
        for (int i = t; i < 81 * 128; i += 256) {
            const int tap = i >> 7, chl = i & 127;
            wb[tap * 132 + chl] = f2bf(w1c[(size_t)(ch0 + chl) * 81 + tap]);
        }
        __syncthreads();
        const int lane = t & 63, l15 = lane & 15, g = lane >> 4;
        const int wave = t >> 6;
        const int n0l = wave * 32;                    // wave owns 32 local ch (2 N-tiles)
        int xoff[3][8];
#pragma unroll
        for (int kk = 0; kk < 3; ++kk)
#pragma unroll
            for (int e = 0; e < 8; ++e) {
                const int tap = kk * 32 + g * 8 + e;
                const int kh = tap / 9, kw = tap - 9 * kh;
                xoff[kk][e] = kh * 28 + kw;
            }
        shortx8 bF[2][3];
#pragma unroll
        for (int nt = 0; nt < 2; ++nt)
#pragma unroll
            for (int kk = 0; kk < 3; ++kk) {
                shortx8 v;
#pragma unroll
                for (int e = 0; e < 8; ++e) {
                    const int tap = kk * 32 + g * 8 + e;
                    v[e] = (short)wb[tap * 132 + n0l + nt * 16 + l15];
                }
                bF[nt][kk] = v;
            }
        float bv[2][4];
#pragma unroll
        for (int nt = 0; nt < 2; ++nt)
#pragma unroll
            for (int r = 0; r < 4; ++r)
                bv[nt][r] = b1c[ch0 + n0l + nt * 16 + g * 4 + r];
        for (int mt = 0; mt < 25; ++mt) {
            const int s = mt * 16 + l15;              // spatial: A-load row AND D col
            const int oh = s / 20, ow = s - 20 * oh;
            const int s2 = oh * 28 + ow;
            shortx8 aF[3];
#pragma unroll
            for (int kk = 0; kk < 3; ++kk) {
                shortx8 v;
#pragma unroll
                for (int e = 0; e < 8; ++e) v[e] = (short)f2bf(xs[s2 + xoff[kk][e]]);
                aF[kk] = v;
            }
            const size_t sbase = ((size_t)(b * 20 + oh) * 20 + ow) * 256 + ch0 + n0l + g * 4;
#pragma unroll
            for (int nt = 0; nt < 2; ++nt) {
                floatx4 acc = (floatx4){0.f, 0.f, 0.f, 0.f};
#pragma unroll
                for (int kk = 0; kk < 3; ++kk)
                    acc = __builtin_amdgcn_mfma_f32_16x16x32_bf16(bF[nt][kk], aF[kk], acc, 0, 0, 0);
                unsigned int w = 0;
                w = __builtin_amdgcn_cvt_pk_fp8_f32(acc[0] + bv[nt][0], acc[1] + bv[nt][1], w, false);
                w = __builtin_amdgcn_cvt_pk_fp8_f32(acc[2] + bv[nt][2], acc[3] + bv[nt][3], w, true);
                *(unsigned int*)(h1t8 + sbase + nt * 16) = w;
            }
        }
    } else {
        // w2 transform: OIHW fp32 [oc][ic][81] -> fp8 [oc][tap*256+ic], x16 scale
        __shared__ float shm[10368];
        const int id = blk - 512;
        const int oc = id >> 1, half = id & 1;
        const float* src = w2 + (size_t)oc * 20736 + half * 128 * 81;
        for (int idx = t; idx < 10368; idx += 256) shm[idx] = src[idx];
        __syncthreads();
        unsigned char* dst = w2t8 + (size_t)oc * 20736 + half * 128;
        for (int idx = t; idx < 10368; idx += 256) {
            const int tap = idx >> 7, icl = idx & 127;
            dst[tap * 256 + icl] = f2fp8(shm[icl * 81 + tap] * W2_SCALE);
        }
    }
}

// ---------- conv2 implicit GEMM, MX-scaled fp8 MFMA (unit scales): proven-best structure ----------
__device__ __forceinline__ int c2_rowbase(int m) {
    const int b = m / 36, sp = m % 36;
    const int oh = sp / 6, ow = sp % 6;
    return (b * 400 + oh * 40 + ow * 2) * 256;        // byte offset into h1t8 (1 B/elem)
}

__global__ __launch_bounds__(256) void conv2_k(const unsigned char* __restrict__ h1t8,
                                               const unsigned char* __restrict__ w2t8,
                                               unsigned short* __restrict__ part) {
    const int t = threadIdx.x;
    const int id = blockIdx.x;                        // 0..575
    const int G = id >> 4;                            // 0..35
    const int bx = (id >> 3) & 1;                     // 0..1 (128-oc tile)
    const int s = id & 7;
    const int by = 2 * G + (s >> 2);                  // 0..71
    const int z  = ((s & 3) + by) & 3;                // 0..3
    __shared__ unsigned char At[128 * 128];           // m rows, 128 fp8 (16 KB)
    __shared__ unsigned char Bt[128 * 128];           // oc rows (16 KB)

    const int oc0 = bx * 128;

    int aRB[4], bBase[4];
#pragma unroll
    for (int k = 0; k < 4; ++k) {
        const int a = t + 256 * k;
        const int r = a >> 3, sg = a & 7;
        const int u = sg ^ (r & 7);
        aRB[k] = c2_rowbase(by * 128 + r) + u * 16;
        bBase[k] = (oc0 + r) * 20736 + u * 16;
    }

    const int lane = t & 63, l31 = lane & 31, h = lane >> 5;
    const int wave = t >> 6;
    const int wM = (wave & 1) * 64, wOC = (wave >> 1) * 64;

    int aO[2][2][2], bO[2][2][2];
#pragma unroll
    for (int i = 0; i < 2; ++i) {
        const int Ra = wOC + i * 32 + l31;            // oc row (A-operand from Bt)
        const int Rb = wM + i * 32 + l31;             // m row  (B-operand from At)
#pragma unroll
        for (int st = 0; st < 2; ++st)
#pragma unroll
            for (int p = 0; p < 2; ++p) {
                const int c = st * 4 + h * 2 + p;
                aO[st][i][p] = Ra * 128 + ((c ^ (Ra & 7)) << 4);
                bO[st][i][p] = Rb * 128 + ((c ^ (Rb & 7)) << 4);
            }
    }

    floatx16 acc[2][2];                               // [oc-tile][m-tile]
#pragma unroll
    for (int i = 0; i < 2; ++i)
#pragma unroll
        for (int j = 0; j < 2; ++j)
#pragma unroll
            for (int r = 0; r < 16; ++r) acc[i][j][r] = 0.f;

    const int q0 = (162 * z) >> 2, q1 = (162 * (z + 1)) >> 2;
    for (int q = q0; q < q1; ++q) {
        const int tap = q >> 1;                       // BK=128 = half a tap; never crosses
        const int kh = tap / 9, kw = tap - 9 * kh;
        const int aoffB = (kh * 20 + kw) * 256 + (q & 1) * 128;
        __syncthreads();
#pragma unroll
        for (int k = 0; k < 4; ++k)
            async_cp16(h1t8 + aRB[k] + aoffB, At + (t + 256 * k) * 16);
#pragma unroll
        for (int k = 0; k < 4; ++k)
            async_cp16(w2t8 + bBase[k] + q * 128, Bt + (t + 256 * k) * 16);
        __syncthreads();
#pragma unroll
        for (int st = 0; st < 2; ++st) {
            intx8 aF[2], bF[2];
#pragma unroll
            for (int i = 0; i < 2; ++i) {
                const intx4v alo = *(const intx4v*)(Bt + aO[st][i][0]);
                const intx4v ahi = *(const intx4v*)(Bt + aO[st][i][1]);
                aF[i] = (intx8){alo[0], alo[1], alo[2], alo[3], ahi[0], ahi[1], ahi[2], ahi[3]};
                const intx4v blo = *(const intx4v*)(At + bO[st][i][0]);
                const intx4v bhi = *(const intx4v*)(At + bO[st][i][1]);
                bF[i] = (intx8){blo[0], blo[1], blo[2], blo[3], bhi[0], bhi[1], bhi[2], bhi[3]};
            }
#pragma unroll
            for (int i = 0; i < 2; ++i)
#pragma unroll
                for (int j = 0; j < 2; ++j)
                    acc[i][j] = __builtin_amdgcn_mfma_scale_f32_32x32x64_f8f6f4(
                        aF[i], bF[j], acc[i][j], 0, 0, 0, 127, 0, 127);
        }
    }

    // epilogue: D col(lane&31)=m, row=(reg&3)+8*(reg>>2)+4*h = oc; undo W2 scale
    unsigned short* pz = part + (size_t)z * 2359296;
#pragma unroll
    for (int i = 0; i < 2; ++i) {
#pragma unroll
        for (int j = 0; j < 2; ++j) {
            const int m = by * 128 + wM + j * 32 + l31;
#pragma unroll
            for (int rg = 0; rg < 4; ++rg) {
                const int oc = oc0 + wOC + i * 32 + rg * 8 + 4 * h;
                ushort4v pk;
#pragma unroll
                for (int rr = 0; rr < 4; ++rr) pk[rr] = f2bf(acc[i][j][rg * 4 + rr] * W2_INV);
                *(ushort4v*)(pz + (size_t)m * 256 + oc) = pk;
            }
        }
    }
}

// ---------- reduce split-K(bf16 x4) + bias + squash(axis=w) -> u[b][1152][8] (half-split x2) ----------
__global__ __launch_bounds__(256) void squash_u_k(const unsigned short* __restrict__ part,
                                                  const float* __restrict__ bias,
                                                  float* __restrict__ u) {
    const int bb = blockIdx.x, t = threadIdx.x;
    const int b = bb >> 1, h = bb & 1;
    __shared__ float hs[4608];
    const size_t base = (size_t)b * 9216 + h * 4608;
    for (int q = t; q < 2304; q += 256) {
        const int idx = q * 2;
        float v0 = bias[idx & 255], v1 = bias[(idx + 1) & 255];
#pragma unroll
        for (int z = 0; z < 4; ++z) {
            const unsigned int uu = *(const unsigned int*)(part + (size_t)z * 2359296 + base + idx);
            v0 += bflo(uu);
            v1 += bfhi(uu);
        }
        hs[idx] = v0; hs[idx + 1] = v1;
    }
    __syncthreads();
    for (int gq = t; gq < 768; gq += 256) {           // groups (c, oh-local), squash over ow(6)
        const int c = gq / 3, ohl = gq % 3;
        const int oh = h * 3 + ohl;
        float s[6], sq = 0.f;
#pragma unroll
        for (int ow = 0; ow < 6; ++ow) { s[ow] = hs[(ohl * 6 + ow) * 256 + c]; sq = fmaf(s[ow], s[ow], sq); }
        const float norm = sqrtf(sq);
        const float f = (sq / (1.0f + sq)) / (norm + 1e-7f);
        float* up = u + (size_t)b * 9216 + c * 36 + oh * 6;
#pragma unroll
        for (int ow = 0; ow < 6; ++ow) up[ow] = s[ow] * f;
    }
}

// ---------- u_hat fp8, B-MAJOR layout: uhat8[b][i][40 u32] = e4m3(64 * W_i u_b) ----------
// Staged in LDS, copy-out scatters 160-B rows at 184320-B stride (fire-and-forget stores);
// buys route_all_k perfectly sequential per-b streaming reads.
__global__ __launch_bounds__(256) void uhat_k(const float* __restrict__ Wc,
                                              const float* __restrict__ u,
                                              unsigned int* __restrict__ uhat8) {
    const int i = blockIdx.x, t = threadIdx.x;       // t = b
    __shared__ float Wl[1280];                       // [o][d*8+e]
    __shared__ __align__(16) unsigned int Ust[256 * 40];   // 40 KB staging [b][40]
    for (int idx = t; idx < 1280; idx += 256) {
        const int o = idx >> 7, r = idx & 127;
        Wl[idx] = Wc[((size_t)o * 1152 + i) * 128 + r];
    }
    float ur[8];
    *(float4*)&ur[0] = *(const float4*)(u + (size_t)t * 9216 + i * 8);
    *(float4*)&ur[4] = *(const float4*)(u + (size_t)t * 9216 + i * 8 + 4);
    __syncthreads();
    unsigned int* myrow = Ust + t * 40;
#pragma unroll 1
    for (int o = 0; o < 10; ++o) {
        float vals[16];
#pragma unroll
        for (int d = 0; d < 16; ++d) {
            const float* wp = &Wl[o * 128 + d * 8];
            float a = 0.f;
#pragma unroll
            for (int e = 0; e < 8; ++e) a = fmaf(wp[e], ur[e], a);
            vals[d] = a * UHAT_SCALE;
        }
        uint4 pk;
        unsigned int w;
#pragma unroll
        for (int q = 0; q < 4; ++q) {
            w = 0;
            w = __builtin_amdgcn_cvt_pk_fp8_f32(vals[q * 4 + 0], vals[q * 4 + 1], w, false);
            w = __builtin_amdgcn_cvt_pk_fp8_f32(vals[q * 4 + 2], vals[q * 4 + 3], w, true);
            if (q == 0) pk.x = w; else if (q == 1) pk.y = w; else if (q == 2) pk.z = w; else pk.w = w;
        }
        *(uint4*)(myrow + o * 4) = pk;
    }
    __syncthreads();
    // copy-out: unit u2 = b*10 + q -> uhat8[b][i][q*4..q*4+3]
    for (int u2 = t; u2 < 2560; u2 += 256) {
        const int bb = u2 / 10, q = u2 - bb * 10;
        *(uint4*)(uhat8 + (size_t)bb * 46080 + (size_t)i * 40 + q * 4) = *(const uint4*)(Ust + u2 * 4);
    }
}

// ---------- fused routing (all 3 iterations), one block per batch image b ----------
// UHAT is b-major: block b streams its 184,320-B slab sequentially, 3x, in 128-i chunks
// via double-buffered async staging. LDS chunk image identical to old layout.
__global__ __launch_bounds__(256) void route_all_k(const unsigned int* __restrict__ uhat8,
                                                   float* __restrict__ BL,
                                                   float* __restrict__ S2out) {
    const int b = blockIdx.x, t = threadIdx.x;
    __shared__ __align__(16) unsigned int Ul8[2][128 * 40];  // 2 x 20.5 KB chunk buffers
    __shared__ float Vl[160];
    __shared__ float cT[10 * 132];
    __shared__ float dots[128 * 10];                  // p1a output; reused as reduce scratch (960)

    // p2 roles: 240 active lanes = 3 k-segments x 2 halves x 40 od-quads
    const int seg = t / 80, rr = t - seg * 80;
    const int hi = rr / 40, th = rr - hi * 40;
    const int oq = th >> 2;
    const bool p2act = (t < 240);
    const int lo = (seg * 64) / 3, hiE = ((seg + 1) * 64) / 3;   // 0-21,21-42,42-64
    // p1a roles
    const int o = t % 10, sidx = t / 10;

    const unsigned int* ubase = uhat8 + (size_t)b * 46080;   // b-major slab
    auto stage = [&](int buf, int chunk) {
        const unsigned int* ub = ubase + (size_t)chunk * 5120;  // 128 rows x 40 u32
#pragma unroll
        for (int rep = 0; rep < 5; ++rep) {
            const int c = rep * 256 + t;
            async_cp16(ub + (size_t)c * 4, (char*)Ul8[buf] + c * 16);
        }
    };

    // ---- iteration 0: S0 = (0.1/64) * sum_i dec(uhat) ----
    float a0 = 0.f, a1 = 0.f, a2 = 0.f, a3 = 0.f;
    stage(0, 0);
    __syncthreads();
    for (int ck = 0; ck < 9; ++ck) {
        const int cur = ck & 1;
        if (ck + 1 < 9) stage(cur ^ 1, ck + 1);
        if (p2act) {
            const unsigned int* base = Ul8[cur] + hi * 64 * 40 + th;
            for (int ii = lo; ii < hiE; ++ii) {
                float f[4];
                fp8x4_dec(base[ii * 40], f);
                a0 += f[0]; a1 += f[1]; a2 += f[2]; a3 += f[3];
            }
        }
        __syncthreads();                              // buf[cur] free + prefetch landed
    }
    if (p2act) {
        float* red = dots;
        const int rb = seg * 320 + hi * 160 + 4 * th;
        red[rb + 0] = a0; red[rb + 1] = a1; red[rb + 2] = a2; red[rb + 3] = a3;
    }
    __syncthreads();
    if (t < 160) {
        const float xv = 0.1f * UHAT_INV *
            (dots[t] + dots[160 + t] + dots[320 + t] + dots[480 + t] + dots[640 + t] + dots[800 + t]);
        float sq = xv * xv;
        sq += __shfl_xor(sq, 1, 16);
        sq += __shfl_xor(sq, 2, 16);
        sq += __shfl_xor(sq, 4, 16);
        sq += __shfl_xor(sq, 8, 16);
        const float norm = sqrtf(sq);
        const float f = (sq / (1.f + sq)) / (norm + 1e-7f);
        Vl[t] = xv * f;
    }
    __syncthreads();

    // ---- iterations 1 and 2 ----
    for (int it = 1; it <= 2; ++it) {
        float vr[16];
        if (t < 250) {
#pragma unroll
            for (int q = 0; q < 4; ++q)
                *(float4*)&vr[q * 4] = *(const float4*)(&Vl[o * 16 + q * 4]);
        }
        a0 = a1 = a2 = a3 = 0.f;
        stage(0, 0);
        __syncthreads();
        for (int ck = 0; ck < 9; ++ck) {
            const int cur = ck & 1;
            if (ck + 1 < 9) stage(cur ^ 1, ck + 1);
            // p1a: dots[i][o] = (1/64) * uhat[i,o,:] . v[o,:]
            if (t < 250) {
#pragma unroll
                for (int rep = 0; rep < 6; ++rep) {
                    const int i = sidx + 25 * rep;
                    if (i < 128) {
                        const uint4 uu = *(const uint4*)(Ul8[cur] + i * 40 + o * 4);
                        float f[16];
                        fp8x4_dec(uu.x, f);
                        fp8x4_dec(uu.y, f + 4);
                        fp8x4_dec(uu.z, f + 8);
                        fp8x4_dec(uu.w, f + 12);
                        float dot = 0.f;
#pragma unroll
                        for (int d = 0; d < 16; ++d) dot = fmaf(f[d], vr[d], dot);
                        dots[i * 10 + o] = dot * UHAT_INV;
                    }
                }
            }
            __syncthreads();
            // p1b: logits + softmax -> cT[o][i_local]
            if (t < 128) {
                float bl[10];
#pragma unroll
                for (int oo = 0; oo < 10; ++oo) bl[oo] = dots[t * 10 + oo];
                const size_t blb = (size_t)b * 11520 + (size_t)ck * 128 + t;
                if (it == 1) {
#pragma unroll
                    for (int oo = 0; oo < 10; ++oo) BL[blb + (size_t)oo * 1152] = bl[oo];
                } else {
#pragma unroll
                    for (int oo = 0; oo < 10; ++oo) bl[oo] += BL[blb + (size_t)oo * 1152];
                }
                float mx = bl[0];
#pragma unroll
                for (int oo = 1; oo < 10; ++oo) mx = fmaxf(mx, bl[oo]);
                float ex[10], sum = 0.f;
#pragma unroll
                for (int oo = 0; oo < 10; ++oo) { ex[oo] = expf(bl[oo] - mx); sum += ex[oo]; }
                const float inv = 1.f / sum;
#pragma unroll
                for (int oo = 0; oo < 10; ++oo) cT[oo * 132 + t] = ex[oo] * inv;
            }
            __syncthreads();
            // p2: accumulate S += c[i][o] * dec(uhat[i][od])
            if (p2act) {
                const unsigned int* base = Ul8[cur] + hi * 64 * 40 + th;
                const float* cb = &cT[oq * 132 + hi * 64];
                for (int ii = lo; ii < hiE; ++ii) {
                    const float c = cb[ii];
                    float f[4];
                    fp8x4_dec(base[ii * 40], f);
                    a0 = fmaf(c, f[0], a0);
                    a1 = fmaf(c, f[1], a1);
                    a2 = fmaf(c, f[2], a2);
                    a3 = fmaf(c, f[3], a3);
                }
            }
            __syncthreads();
        }
        if (p2act) {
            float* red = dots;
            const int rb = seg * 320 + hi * 160 + 4 * th;
            red[rb + 0] = a0; red[rb + 1] = a1; red[rb + 2] = a2; red[rb + 3] = a3;
        }
        __syncthreads();
        if (t < 160) {
            const float sv = UHAT_INV *
                (dots[t] + dots[160 + t] + dots[320 + t] + dots[480 + t] + dots[640 + t] + dots[800 + t]);
            if (it == 1) {
                float sq = sv * sv;
                sq += __shfl_xor(sq, 1, 16);
                sq += __shfl_xor(sq, 2, 16);
                sq += __shfl_xor(sq, 4, 16);
                sq += __shfl_xor(sq, 8, 16);
                const float norm = sqrtf(sq);
                const float f = (sq / (1.f + sq)) / (norm + 1e-7f);
                Vl[t] = sv * f;
            } else {
                S2out[b * 160 + t] = sv;
            }
        }
        __syncthreads();
    }
}

// ---------- final: squash S2 -> lengths, argmax + fused decoder layer 1 ----------
__global__ __launch_bounds__(512) void final_k(const float* __restrict__ S,
                                               const float* __restrict__ w1,
                                               const float* __restrict__ b1,
                                               float* __restrict__ out_len,
                                               float* __restrict__ h1d) {
    const int b = blockIdx.x, t = threadIdx.x;
    __shared__ float v_s[160];
    __shared__ float len_s[10];
    __shared__ int sel_s;
    if (t < 160) {
        const float x = S[b * 160 + t];
        float sq = x * x;
        sq += __shfl_xor(sq, 1, 16);
        sq += __shfl_xor(sq, 2, 16);
        sq += __shfl_xor(sq, 4, 16);
        sq += __shfl_xor(sq, 8, 16);
        const float norm = sqrtf(sq);
        const float f = (sq / (1.f + sq)) / (norm + 1e-7f);
        v_s[t] = x * f;
        if ((t & 15) == 0) {
            const float len = f * norm;
            len_s[t >> 4] = len;
            out_len[b * 10 + (t >> 4)] = len;
        }
    }
    __syncthreads();
    if (t == 0) {
        float best = len_s[0]; int bi = 0;
        for (int oo = 1; oo < 10; ++oo) if (len_s[oo] > best) { best = len_s[oo]; bi = oo; }
        sel_s = bi;
    }
    __syncthreads();
    const int s = sel_s;
    float acc = b1[t];
    const float* wrow = w1 + (size_t)(s * 16) * 512 + t;
#pragma unroll
    for (int j = 0; j < 16; ++j) acc = fmaf(v_s[s * 16 + j], wrow[j * 512], acc);
    h1d[(size_t)b * 512 + t] = fmaxf(acc, 0.f);
}

// ---------- decoder GEMM v3: 8m x 64n tile, per-wave K-split x4, ping-pong float4 B batches ----------
template <int ACT>
__global__ __launch_bounds__(256) void mlp3_k(const float* __restrict__ A,
                                              const float* __restrict__ Bm,
                                              const float* __restrict__ bias,
                                              float* __restrict__ C, int N, int K) {
    extern __shared__ float Asm[];                    // 8*(K+4) floats; tail-reused for reduce
    const int t = threadIdx.x;
    const int m0 = blockIdx.y * 8, n0 = blockIdx.x * 64;
    const int RS = K + 4;
    const int k4 = K >> 2;
    for (int i = t; i < 8 * k4; i += 256) {           // stage A tile, float4 units
        const int r = i / k4, c = i - r * k4;
        *(float4*)&Asm[r * RS + c * 4] = *(const float4*)&A[(size_t)(m0 + r) * K + c * 4];
    }
    __syncthreads();
    const int lane = t & 63, w = t >> 6;
    const int mq = lane >> 4, nq = lane & 15;
    const int n = n0 + nq * 4;
    const int ncl = (n + 3 < N) ? n : (N - 4);        // clamp base col (16B-aligned, safe)
    const float* bp = Bm + ncl;
    const float* asA = &Asm[(mq * 2 + 0) * RS];
    const float* asB = &Asm[(mq * 2 + 1) * RS];
    const int kQ = K >> 2;                            // per-wave chunk (128 or 256)
    const int kBeg = w * kQ;
    const int nBat2 = kQ >> 4;                        // double-batches of 16 k
    float4 acc0 = {0.f, 0.f, 0.f, 0.f}, acc1 = {0.f, 0.f, 0.f, 0.f};
    float4 ba[8], bb[8];
#pragma unroll
    for (int d = 0; d < 8; ++d) ba[d] = *(const float4*)&bp[(size_t)(kBeg + d) * N];

#define MLP3_FMA(BATCH, KB)                                                       \
    _Pragma("unroll")                                                             \
    for (int d = 0; d < 8; ++d) {                                                 \
        const float4 b = BATCH[d];                                                \
        const float a0 = asA[(KB) + d];                                           \
        const float a1 = asB[(KB) + d];                                           \
        acc0.x = fmaf(a0, b.x, acc0.x); acc0.y = fmaf(a0, b.y, acc0.y);           \
        acc0.z = fmaf(a0, b.z, acc0.z); acc0.w = fmaf(a0, b.w, acc0.w);           \
        acc1.x = fmaf(a1, b.x, acc1.x); acc1.y = fmaf(a1, b.y, acc1.y);           \
        acc1.z = fmaf(a1, b.z, acc1.z); acc1.w = fmaf(a1, b.w, acc1.w);           \
    }

    int k = kBeg;
#pragma unroll 1
    for (int it = 0; it < nBat2; ++it) {
#pragma unroll
        for (int d = 0; d < 8; ++d) bb[d] = *(const float4*)&bp[(size_t)(k + 8 + d) * N];
        MLP3_FMA(ba, k)
        if (it + 1 < nBat2) {
#pragma unroll
            for (int d = 0; d < 8; ++d) ba[d] = *(const float4*)&bp[(size_t)(k + 16 + d) * N];
        }
        MLP3_FMA(bb, k + 8)
        k += 16;
    }
#undef MLP3_FMA

    // cross-wave k-quarter reduce via LDS (reuses Asm; 4*64*8 floats = 8 KB)
    __syncthreads();                                  // all waves done reading Asm
    float* red = Asm;
    float* my = &red[(size_t)(w * 64 + lane) * 8];
    my[0] = acc0.x; my[1] = acc0.y; my[2] = acc0.z; my[3] = acc0.w;
    my[4] = acc1.x; my[5] = acc1.y; my[6] = acc1.z; my[7] = acc1.w;
    __syncthreads();
    if (t < 64) {
        float o[8];
#pragma unroll
        for (int x = 0; x < 8; ++x)
            o[x] = red[(size_t)t * 8 + x] + red[(size_t)(64 + t) * 8 + x]
                 + red[(size_t)(128 + t) * 8 + x] + red[(size_t)(192 + t) * 8 + x];
        const int nn = n0 + (t & 15) * 4;
#pragma unroll
        for (int rm = 0; rm < 2; ++rm) {
            const int m = m0 + (t >> 4) * 2 + rm;
#pragma unroll
            for (int rn = 0; rn < 4; ++rn) {
                const int ncol = nn + rn;
                if (ncol < N) {
                    float v = o[rm * 4 + rn] + bias[ncol];
                    if (ACT == 0) v = fmaxf(v, 0.f);
                    else v = 1.f / (1.f + expf(-v));
                    C[(size_t)m * N + ncol] = v;
                }
            }
        }
    }
}

// ---------- launcher ----------
extern "C" void kernel_launch(void* const* d_in, const int* in_sizes, int n_in,
                              void* d_out, int out_size, void* d_ws, size_t ws_size,
                              hipStream_t stream) {
    const float* x   = (const float*)d_in[0];
    const float* w1  = (const float*)d_in[1];
    const float* b1  = (const float*)d_in[2];
    const float* w2  = (const float*)d_in[3];
    const float* b2  = (const float*)d_in[4];
    const float* Wc  = (const float*)d_in[5];
    const float* dw1 = (const float*)d_in[6];
    const float* db1 = (const float*)d_in[7];
    const float* dw2 = (const float*)d_in[8];
    const float* db2 = (const float*)d_in[9];
    const float* dw3 = (const float*)d_in[10];
    const float* db3 = (const float*)d_in[11];
    float* out = (float*)d_out;

    char* ws = (char*)d_ws;
    unsigned char* H1T8 = (unsigned char*)(ws + 0);            // 26,214,400 B fp8
    unsigned char* W2T8 = (unsigned char*)(ws + 26214400);     //  5,308,416 B fp8 (x16)
    unsigned short* PART = (unsigned short*)(ws + 31522816);   // 18,874,368 B bf16, z=4
    unsigned int*   UHAT = (unsigned int*)(ws + 0);            // 47,185,920 B fp8 b-major (aliases dead staging)
    float* U    = (float*)(ws + 50397184);                     //  9,437,184 B (after PART; dead after uhat_k)
    float* BL   = (float*)(ws + 59834368);                     // 11,796,480 B (live within route_all)
    float* S2   = (float*)(ws + 71958528);                     //    163,840 B (written by route_all)
    float* H1D  = (float*)(ws + 59834368);                     //    524,288 B (dead-BL space, after route_all)
    float* H2D  = (float*)(ws + 60358656);                     //  1,048,576 B

    prep_k<<<1024, 256, 0, stream>>>(x, w1, b1, w2, H1T8, W2T8);
    conv2_k<<<576, 256, 0, stream>>>(H1T8, W2T8, PART);
    squash_u_k<<<512, 256, 0, stream>>>(PART, b2, U);
    uhat_k<<<1152, 256, 0, stream>>>(Wc, U, UHAT);
    route_all_k<<<256, 256, 0, stream>>>(UHAT, BL, S2);
    final_k<<<256, 512, 0, stream>>>(S2, dw1, db1, out, H1D);
    mlp3_k<0><<<dim3(16, 32), 256, 8 * 516 * 4, stream>>>(H1D, dw2, db2, H2D, 1024, 512);
    mlp3_k<1><<<dim3(13, 32), 256, 8 * 1028 * 4, stream>>>(H2D, dw3, db3, out + 2560, 784, 1024);
}

// Round 15
// 311.873 us; speedup vs baseline: 1.6613x; 1.0039x over previous
//
#include <hip/hip_runtime.h>
#include <cstdint>
#include <cstddef>

// ---------- types / helpers ----------
typedef __bf16 bf16x8 __attribute__((ext_vector_type(8)));
typedef short  shortx8 __attribute__((ext_vector_type(8)));
typedef float  floatx4 __attribute__((ext_vector_type(4)));
typedef float  floatx2 __attribute__((ext_vector_type(2)));
typedef float  floatx16 __attribute__((ext_vector_type(16)));
typedef int    intx4v __attribute__((ext_vector_type(4)));
typedef int    intx8 __attribute__((ext_vector_type(8)));
typedef unsigned short ushort8 __attribute__((ext_vector_type(8)));
typedef unsigned short ushort4v __attribute__((ext_vector_type(4)));

__device__ __forceinline__ float bflo(unsigned int u) {
    union { unsigned int u32; float f; } x; x.u32 = u << 16; return x.f;
}
__device__ __forceinline__ float bfhi(unsigned int u) {
    union { unsigned int u32; float f; } x; x.u32 = u & 0xffff0000u; return x.f;
}
__device__ __forceinline__ unsigned short f2bf(float f) {
    union { float f; unsigned int u; } x; x.f = f;
    unsigned int u = x.u;
    unsigned int r = (u + 0x7fffu + ((u >> 16) & 1u)) >> 16;   // RNE
    return (unsigned short)r;
}
__device__ __forceinline__ unsigned char f2fp8(float f) {
    unsigned int pk = __builtin_amdgcn_cvt_pk_fp8_f32(f, f, 0, false);
    return (unsigned char)(pk & 0xff);
}
// decode 4 fp8(e4m3) packed in u32 -> 4 floats
__device__ __forceinline__ void fp8x4_dec(unsigned int u, float* f) {
    floatx2 lo = __builtin_amdgcn_cvt_pk_f32_fp8(u, false);
    floatx2 hi = __builtin_amdgcn_cvt_pk_f32_fp8(u, true);
    f[0] = lo[0]; f[1] = lo[1]; f[2] = hi[0]; f[3] = hi[1];
}

#define GLOBAL_U32 const __attribute__((address_space(1))) unsigned int*
#define LDS_U32 __attribute__((address_space(3))) unsigned int*
__device__ __forceinline__ void async_cp16(const void* g, void* l) {
    __builtin_amdgcn_global_load_lds((GLOBAL_U32)g, (LDS_U32)l, 16, 0, 0);
}

#define UHAT_SCALE 64.0f
#define UHAT_INV   (1.0f / 64.0f)
#define W2_SCALE   16.0f
#define W2_INV     (1.0f / 16.0f)

// ---------- prep: conv1 via bf16 MFMA (blocks 0..511) + w2t fp8 (512..1023) ----------
__global__ __launch_bounds__(256) void prep_k(const float* __restrict__ x,
                                              const float* __restrict__ w1c,
                                              const float* __restrict__ b1c,
                                              const float* __restrict__ w2,
                                              unsigned char* __restrict__ h1t8,
                                              unsigned char* __restrict__ w2t8) {
    const int blk = blockIdx.x, t = threadIdx.x;
    if (blk < 512) {
        // block = (image b, ch-half): M=400 spatial, N=128 ch, K=96 (81 real taps)
        __shared__ float xs[1024];                    // 28x28 image + zero pad
        __shared__ unsigned short wb[96 * 132];       // [tap][ch-local] bf16, stride 132
        const int b = blk >> 1, ch0 = (blk & 1) * 128;
        for (int i = t; i < 1024; i += 256) xs[i] = (i < 784) ? x[b * 784 + i] : 0.f;
        for (int i = t; i < 96 * 132; i += 256) wb[i] = 0;
        __syncthreads();
        for (int i = t; i < 81 * 128; i += 256) {
            const int tap = i >> 7, chl = i & 127;
            wb[tap * 132 + chl] = f2bf(w1c[(size_t)(ch0 + chl) * 81 + tap]);
        }
        __syncthreads();
        const int lane = t & 63, l15 = lane & 15, g = lane >> 4;
        const int wave = t >> 6;
        const int n0l = wave * 32;                    // wave owns 32 local ch (2 N-tiles)
        int xoff[3][8];
#pragma unroll
        for (int kk = 0; kk < 3; ++kk)
#pragma unroll
            for (int e = 0; e < 8; ++e) {
                const int tap = kk * 32 + g * 8 + e;
                const int kh = tap / 9, kw = tap - 9 * kh;
                xoff[kk][e] = kh * 28 + kw;
            }
        shortx8 bF[2][3];
#pragma unroll
        for (int nt = 0; nt < 2; ++nt)
#pragma unroll
            for (int kk = 0; kk < 3; ++kk) {
                shortx8 v;
#pragma unroll
                for (int e = 0; e < 8; ++e) {
                    const int tap = kk * 32 + g * 8 + e;
                    v[e] = (short)wb[tap * 132 + n0l + nt * 16 + l15];
                }
                bF[nt][kk] = v;
            }
        float bv[2][4];
#pragma unroll
        for (int nt = 0; nt < 2; ++nt)
#pragma unroll
            for (int r = 0; r < 4; ++r)
                bv[nt][r] = b1c[ch0 + n0l + nt * 16 + g * 4 + r];
        for (int mt = 0; mt < 25; ++mt) {
            const int s = mt * 16 + l15;              // spatial: A-load row AND D col
            const int oh = s / 20, ow = s - 20 * oh;
            const int s2 = oh * 28 + ow;
            shortx8 aF[3];
#pragma unroll
            for (int kk = 0; kk < 3; ++kk) {
                shortx8 v;
#pragma unroll
                for (int e = 0; e < 8; ++e) v[e] = (short)f2bf(xs[s2 + xoff[kk][e]]);
                aF[kk] = v;
            }
            const size_t sbase = ((size_t)(b * 20 + oh) * 20 + ow) * 256 + ch0 + n0l + g * 4;
#pragma unroll
            for (int nt = 0; nt < 2; ++nt) {
                floatx4 acc = (floatx4){0.f, 0.f, 0.f, 0.f};
#pragma unroll
                for (int kk = 0; kk < 3; ++kk)
                    acc = __builtin_amdgcn_mfma_f32_16x16x32_bf16(bF[nt][kk], aF[kk], acc, 0, 0, 0);
                unsigned int w = 0;
                w = __builtin_amdgcn_cvt_pk_fp8_f32(acc[0] + bv[nt][0], acc[1] + bv[nt][1], w, false);
                w = __builtin_amdgcn_cvt_pk_fp8_f32(acc[2] + bv[nt][2], acc[3] + bv[nt][3], w, true);
                *(unsigned int*)(h1t8 + sbase + nt * 16) = w;
            }
        }
    } else {
        // w2 transform: OIHW fp32 [oc][ic][81] -> fp8 [oc][tap*256+ic], x16 scale
        __shared__ float shm[10368];
        const int id = blk - 512;
        const int oc = id >> 1, half = id & 1;
        const float* src = w2 + (size_t)oc * 20736 + half * 128 * 81;
        for (int idx = t; idx < 10368; idx += 256) shm[idx] = src[idx];
        __syncthreads();
        unsigned char* dst = w2t8 + (size_t)oc * 20736 + half * 128;
        for (int idx = t; idx < 10368; idx += 256) {
            const int tap = idx >> 7, icl = idx & 127;
            dst[tap * 256 + icl] = f2fp8(shm[icl * 81 + tap] * W2_SCALE);
        }
    }
}

// ---------- conv2 implicit GEMM, MX-scaled fp8 MFMA (unit scales): proven-best structure ----------
__device__ __forceinline__ int c2_rowbase(int m) {
    const int b = m / 36, sp = m % 36;
    const int oh = sp / 6, ow = sp % 6;
    return (b * 400 + oh * 40 + ow * 2) * 256;        // byte offset into h1t8 (1 B/elem)
}

__global__ __launch_bounds__(256) void conv2_k(const unsigned char* __restrict__ h1t8,
                                               const unsigned char* __restrict__ w2t8,
                                               unsigned short* __restrict__ part) {
    const int t = threadIdx.x;
    const int id = blockIdx.x;                        // 0..575
    const int G = id >> 4;                            // 0..35
    const int bx = (id >> 3) & 1;                     // 0..1 (128-oc tile)
    const int s = id & 7;
    const int by = 2 * G + (s >> 2);                  // 0..71
    const int z  = ((s & 3) + by) & 3;                // 0..3
    __shared__ unsigned char At[128 * 128];           // m rows, 128 fp8 (16 KB)
    __shared__ unsigned char Bt[128 * 128];           // oc rows (16 KB)

    const int oc0 = bx * 128;

    int aRB[4], bBase[4];
#pragma unroll
    for (int k = 0; k < 4; ++k) {
        const int a = t + 256 * k;
        const int r = a >> 3, sg = a & 7;
        const int u = sg ^ (r & 7);
        aRB[k] = c2_rowbase(by * 128 + r) + u * 16;
        bBase[k] = (oc0 + r) * 20736 + u * 16;
    }

    const int lane = t & 63, l31 = lane & 31, h = lane >> 5;
    const int wave = t >> 6;
    const int wM = (wave & 1) * 64, wOC = (wave >> 1) * 64;

    int aO[2][2][2], bO[2][2][2];
#pragma unroll
    for (int i = 0; i < 2; ++i) {
        const int Ra = wOC + i * 32 + l31;            // oc row (A-operand from Bt)
        const int Rb = wM + i * 32 + l31;             // m row  (B-operand from At)
#pragma unroll
        for (int st = 0; st < 2; ++st)
#pragma unroll
            for (int p = 0; p < 2; ++p) {
                const int c = st * 4 + h * 2 + p;
                aO[st][i][p] = Ra * 128 + ((c ^ (Ra & 7)) << 4);
                bO[st][i][p] = Rb * 128 + ((c ^ (Rb & 7)) << 4);
            }
    }

    floatx16 acc[2][2];                               // [oc-tile][m-tile]
#pragma unroll
    for (int i = 0; i < 2; ++i)
#pragma unroll
        for (int j = 0; j < 2; ++j)
#pragma unroll
            for (int r = 0; r < 16; ++r) acc[i][j][r] = 0.f;

    const int q0 = (162 * z) >> 2, q1 = (162 * (z + 1)) >> 2;
    for (int q = q0; q < q1; ++q) {
        const int tap = q >> 1;                       // BK=128 = half a tap; never crosses
        const int kh = tap / 9, kw = tap - 9 * kh;
        const int aoffB = (kh * 20 + kw) * 256 + (q & 1) * 128;
        __syncthreads();
#pragma unroll
        for (int k = 0; k < 4; ++k)
            async_cp16(h1t8 + aRB[k] + aoffB, At + (t + 256 * k) * 16);
#pragma unroll
        for (int k = 0; k < 4; ++k)
            async_cp16(w2t8 + bBase[k] + q * 128, Bt + (t + 256 * k) * 16);
        __syncthreads();
#pragma unroll
        for (int st = 0; st < 2; ++st) {
            intx8 aF[2], bF[2];
#pragma unroll
            for (int i = 0; i < 2; ++i) {
                const intx4v alo = *(const intx4v*)(Bt + aO[st][i][0]);
                const intx4v ahi = *(const intx4v*)(Bt + aO[st][i][1]);
                aF[i] = (intx8){alo[0], alo[1], alo[2], alo[3], ahi[0], ahi[1], ahi[2], ahi[3]};
                const intx4v blo = *(const intx4v*)(At + bO[st][i][0]);
                const intx4v bhi = *(const intx4v*)(At + bO[st][i][1]);
                bF[i] = (intx8){blo[0], blo[1], blo[2], blo[3], bhi[0], bhi[1], bhi[2], bhi[3]};
            }
#pragma unroll
            for (int i = 0; i < 2; ++i)
#pragma unroll
                for (int j = 0; j < 2; ++j)
                    acc[i][j] = __builtin_amdgcn_mfma_scale_f32_32x32x64_f8f6f4(
                        aF[i], bF[j], acc[i][j], 0, 0, 0, 127, 0, 127);
        }
    }

    // epilogue: D col(lane&31)=m, row=(reg&3)+8*(reg>>2)+4*h = oc; undo W2 scale
    unsigned short* pz = part + (size_t)z * 2359296;
#pragma unroll
    for (int i = 0; i < 2; ++i) {
#pragma unroll
        for (int j = 0; j < 2; ++j) {
            const int m = by * 128 + wM + j * 32 + l31;
#pragma unroll
            for (int rg = 0; rg < 4; ++rg) {
                const int oc = oc0 + wOC + i * 32 + rg * 8 + 4 * h;
                ushort4v pk;
#pragma unroll
                for (int rr = 0; rr < 4; ++rr) pk[rr] = f2bf(acc[i][j][rg * 4 + rr] * W2_INV);
                *(ushort4v*)(pz + (size_t)m * 256 + oc) = pk;
            }
        }
    }
}

// ---------- reduce split-K(bf16 x4) + bias + squash(axis=w) -> u[b][1152][8] (half-split x2) ----------
__global__ __launch_bounds__(256) void squash_u_k(const unsigned short* __restrict__ part,
                                                  const float* __restrict__ bias,
                                                  float* __restrict__ u) {
    const int bb = blockIdx.x, t = threadIdx.x;
    const int b = bb >> 1, h = bb & 1;
    __shared__ float hs[4608];
    const size_t base = (size_t)b * 9216 + h * 4608;
    for (int q = t; q < 2304; q += 256) {
        const int idx = q * 2;
        float v0 = bias[idx & 255], v1 = bias[(idx + 1) & 255];
#pragma unroll
        for (int z = 0; z < 4; ++z) {
            const unsigned int uu = *(const unsigned int*)(part + (size_t)z * 2359296 + base + idx);
            v0 += bflo(uu);
            v1 += bfhi(uu);
        }
        hs[idx] = v0; hs[idx + 1] = v1;
    }
    __syncthreads();
    for (int gq = t; gq < 768; gq += 256) {           // groups (c, oh-local), squash over ow(6)
        const int c = gq / 3, ohl = gq % 3;
        const int oh = h * 3 + ohl;
        float s[6], sq = 0.f;
#pragma unroll
        for (int ow = 0; ow < 6; ++ow) { s[ow] = hs[(ohl * 6 + ow) * 256 + c]; sq = fmaf(s[ow], s[ow], sq); }
        const float norm = sqrtf(sq);
        const float f = (sq / (1.0f + sq)) / (norm + 1e-7f);
        float* up = u + (size_t)b * 9216 + c * 36 + oh * 6;
#pragma unroll
        for (int ow = 0; ow < 6; ++ow) up[ow] = s[ow] * f;
    }
}

// ---------- u_hat fp8, B-MAJOR layout: uhat8[b][i][40 u32] = e4m3(64 * W_i u_b) ----------
__global__ __launch_bounds__(256) void uhat_k(const float* __restrict__ Wc,
                                              const float* __restrict__ u,
                                              unsigned int* __restrict__ uhat8) {
    const int i = blockIdx.x, t = threadIdx.x;       // t = b
    __shared__ float Wl[1280];                       // [o][d*8+e]
    __shared__ __align__(16) unsigned int Ust[256 * 40];   // 40 KB staging [b][40]
    for (int idx = t; idx < 1280; idx += 256) {
        const int o = idx >> 7, r = idx & 127;
        Wl[idx] = Wc[((size_t)o * 1152 + i) * 128 + r];
    }
    float ur[8];
    *(float4*)&ur[0] = *(const float4*)(u + (size_t)t * 9216 + i * 8);
    *(float4*)&ur[4] = *(const float4*)(u + (size_t)t * 9216 + i * 8 + 4);
    __syncthreads();
    unsigned int* myrow = Ust + t * 40;
#pragma unroll 1
    for (int o = 0; o < 10; ++o) {
        float vals[16];
#pragma unroll
        for (int d = 0; d < 16; ++d) {
            const float* wp = &Wl[o * 128 + d * 8];
            float a = 0.f;
#pragma unroll
            for (int e = 0; e < 8; ++e) a = fmaf(wp[e], ur[e], a);
            vals[d] = a * UHAT_SCALE;
        }
        uint4 pk;
        unsigned int w;
#pragma unroll
        for (int q = 0; q < 4; ++q) {
            w = 0;
            w = __builtin_amdgcn_cvt_pk_fp8_f32(vals[q * 4 + 0], vals[q * 4 + 1], w, false);
            w = __builtin_amdgcn_cvt_pk_fp8_f32(vals[q * 4 + 2], vals[q * 4 + 3], w, true);
            if (q == 0) pk.x = w; else if (q == 1) pk.y = w; else if (q == 2) pk.z = w; else pk.w = w;
        }
        *(uint4*)(myrow + o * 4) = pk;
    }
    __syncthreads();
    // copy-out: unit u2 = b*10 + q -> uhat8[b][i][q*4..q*4+3]
    for (int u2 = t; u2 < 2560; u2 += 256) {
        const int bb = u2 / 10, q = u2 - bb * 10;
        *(uint4*)(uhat8 + (size_t)bb * 46080 + (size_t)i * 40 + q * 4) = *(const uint4*)(Ust + u2 * 4);
    }
}

// ---------- fused routing (all 3 iterations), one block (512 thr, 8 waves) per image b ----------
// b-major UHAT streamed sequentially 3x in 128-i chunks, double-buffered. 512 threads halve
// every phase's per-lane serial work and double waves/SIMD for latency overlap.
__global__ __launch_bounds__(512) void route_all_k(const unsigned int* __restrict__ uhat8,
                                                   float* __restrict__ BL,
                                                   float* __restrict__ S2out) {
    const int b = blockIdx.x, t = threadIdx.x;
    __shared__ __align__(16) unsigned int Ul8[2][128 * 40];  // 2 x 20.5 KB chunk buffers
    __shared__ float Vl[160];
    __shared__ float cT[10 * 132];
    __shared__ float dots[1920];                      // p1a output (1280) / reduce scratch (1920)

    // p2 roles: 480 active lanes = 6 k-segments x 2 halves x 40 od-quads
    const int seg = t / 80, rr = t - seg * 80;
    const int hi = rr / 40, th = rr - hi * 40;
    const int oq = th >> 2;
    const bool p2act = (t < 480);
    const int lo = (seg * 64) / 6, hiE = ((seg + 1) * 64) / 6;   // ~10-11 i each
    // p1a roles: 500 active
    const int o = t % 10, sidx = t / 10;

    const unsigned int* ubase = uhat8 + (size_t)b * 46080;   // b-major slab
    auto stage = [&](int buf, int chunk) {
        const unsigned int* ub = ubase + (size_t)chunk * 5120;  // 128 rows x 40 u32
        for (int c = t; c < 1280; c += 512)
            async_cp16(ub + (size_t)c * 4, (char*)Ul8[buf] + c * 16);
    };

    // ---- iteration 0: S0 = (0.1/64) * sum_i dec(uhat) ----
    float a0 = 0.f, a1 = 0.f, a2 = 0.f, a3 = 0.f;
    stage(0, 0);
    __syncthreads();
    for (int ck = 0; ck < 9; ++ck) {
        const int cur = ck & 1;
        if (ck + 1 < 9) stage(cur ^ 1, ck + 1);
        if (p2act) {
            const unsigned int* base = Ul8[cur] + hi * 64 * 40 + th;
            for (int ii = lo; ii < hiE; ++ii) {
                float f[4];
                fp8x4_dec(base[ii * 40], f);
                a0 += f[0]; a1 += f[1]; a2 += f[2]; a3 += f[3];
            }
        }
        __syncthreads();                              // buf[cur] free + prefetch landed
    }
    if (p2act) {
        const int rb = seg * 320 + hi * 160 + 4 * th;
        dots[rb + 0] = a0; dots[rb + 1] = a1; dots[rb + 2] = a2; dots[rb + 3] = a3;
    }
    __syncthreads();
    if (t < 160) {
        float xv = 0.f;
#pragma unroll
        for (int j = 0; j < 12; ++j) xv += dots[j * 160 + t];
        xv *= 0.1f * UHAT_INV;
        float sq = xv * xv;
        sq += __shfl_xor(sq, 1, 16);
        sq += __shfl_xor(sq, 2, 16);
        sq += __shfl_xor(sq, 4, 16);
        sq += __shfl_xor(sq, 8, 16);
        const float norm = sqrtf(sq);
        const float f = (sq / (1.f + sq)) / (norm + 1e-7f);
        Vl[t] = xv * f;
    }
    __syncthreads();

    // ---- iterations 1 and 2 ----
    for (int it = 1; it <= 2; ++it) {
        float vr[16];
        if (t < 500) {
#pragma unroll
            for (int q = 0; q < 4; ++q)
                *(float4*)&vr[q * 4] = *(const float4*)(&Vl[o * 16 + q * 4]);
        }
        a0 = a1 = a2 = a3 = 0.f;
        stage(0, 0);
        __syncthreads();
        for (int ck = 0; ck < 9; ++ck) {
            const int cur = ck & 1;
            if (ck + 1 < 9) stage(cur ^ 1, ck + 1);
            // p1a: dots[i][o] = (1/64) * uhat[i,o,:] . v[o,:]  (500 lanes, 3 reps)
            if (t < 500) {
#pragma unroll
                for (int rep = 0; rep < 3; ++rep) {
                    const int i = sidx + 50 * rep;
                    if (i < 128) {
                        const uint4 uu = *(const uint4*)(Ul8[cur] + i * 40 + o * 4);
                        float f[16];
                        fp8x4_dec(uu.x, f);
                        fp8x4_dec(uu.y, f + 4);
                        fp8x4_dec(uu.z, f + 8);
                        fp8x4_dec(uu.w, f + 12);
                        float dot = 0.f;
#pragma unroll
                        for (int d = 0; d < 16; ++d) dot = fmaf(f[d], vr[d], dot);
                        dots[i * 10 + o] = dot * UHAT_INV;
                    }
                }
            }
            __syncthreads();
            // p1b: logits + softmax -> cT[o][i_local]
            if (t < 128) {
                float bl[10];
#pragma unroll
                for (int oo = 0; oo < 10; ++oo) bl[oo] = dots[t * 10 + oo];
                const size_t blb = (size_t)b * 11520 + (size_t)ck * 128 + t;
                if (it == 1) {
#pragma unroll
                    for (int oo = 0; oo < 10; ++oo) BL[blb + (size_t)oo * 1152] = bl[oo];
                } else {
#pragma unroll
                    for (int oo = 0; oo < 10; ++oo) bl[oo] += BL[blb + (size_t)oo * 1152];
                }
                float mx = bl[0];
#pragma unroll
                for (int oo = 1; oo < 10; ++oo) mx = fmaxf(mx, bl[oo]);
                float ex[10], sum = 0.f;
#pragma unroll
                for (int oo = 0; oo < 10; ++oo) { ex[oo] = expf(bl[oo] - mx); sum += ex[oo]; }
                const float inv = 1.f / sum;
#pragma unroll
                for (int oo = 0; oo < 10; ++oo) cT[oo * 132 + t] = ex[oo] * inv;
            }
            __syncthreads();
            // p2: accumulate S += c[i][o] * dec(uhat[i][od])
            if (p2act) {
                const unsigned int* base = Ul8[cur] + hi * 64 * 40 + th;
                const float* cb = &cT[oq * 132 + hi * 64];
                for (int ii = lo; ii < hiE; ++ii) {
                    const float c = cb[ii];
                    float f[4];
                    fp8x4_dec(base[ii * 40], f);
                    a0 = fmaf(c, f[0], a0);
                    a1 = fmaf(c, f[1], a1);
                    a2 = fmaf(c, f[2], a2);
                    a3 = fmaf(c, f[3], a3);
                }
            }
            __syncthreads();
        }
        if (p2act) {
            const int rb = seg * 320 + hi * 160 + 4 * th;
            dots[rb + 0] = a0; dots[rb + 1] = a1; dots[rb + 2] = a2; dots[rb + 3] = a3;
        }
        __syncthreads();
        if (t < 160) {
            float sv = 0.f;
#pragma unroll
            for (int j = 0; j < 12; ++j) sv += dots[j * 160 + t];
            sv *= UHAT_INV;
            if (it == 1) {
                float sq = sv * sv;
                sq += __shfl_xor(sq, 1, 16);
                sq += __shfl_xor(sq, 2, 16);
                sq += __shfl_xor(sq, 4, 16);
                sq += __shfl_xor(sq, 8, 16);
                const float norm = sqrtf(sq);
                const float f = (sq / (1.f + sq)) / (norm + 1e-7f);
                Vl[t] = sv * f;
            } else {
                S2out[b * 160 + t] = sv;
            }
        }
        __syncthreads();
    }
}

// ---------- final: squash S2 -> lengths, argmax + fused decoder layer 1 ----------
__global__ __launch_bounds__(512) void final_k(const float* __restrict__ S,
                                               const float* __restrict__ w1,
                                               const float* __restrict__ b1,
                                               float* __restrict__ out_len,
                                               float* __restrict__ h1d) {
    const int b = blockIdx.x, t = threadIdx.x;
    __shared__ float v_s[160];
    __shared__ float len_s[10];
    __shared__ int sel_s;
    if (t < 160) {
        const float x = S[b * 160 + t];
        float sq = x * x;
        sq += __shfl_xor(sq, 1, 16);
        sq += __shfl_xor(sq, 2, 16);
        sq += __shfl_xor(sq, 4, 16);
        sq += __shfl_xor(sq, 8, 16);
        const float norm = sqrtf(sq);
        const float f = (sq / (1.f + sq)) / (norm + 1e-7f);
        v_s[t] = x * f;
        if ((t & 15) == 0) {
            const float len = f * norm;
            len_s[t >> 4] = len;
            out_len[b * 10 + (t >> 4)] = len;
        }
    }
    __syncthreads();
    if (t == 0) {
        float best = len_s[0]; int bi = 0;
        for (int oo = 1; oo < 10; ++oo) if (len_s[oo] > best) { best = len_s[oo]; bi = oo; }
        sel_s = bi;
    }
    __syncthreads();
    const int s = sel_s;
    float acc = b1[t];
    const float* wrow = w1 + (size_t)(s * 16) * 512 + t;
#pragma unroll
    for (int j = 0; j < 16; ++j) acc = fmaf(v_s[s * 16 + j], wrow[j * 512], acc);
    h1d[(size_t)b * 512 + t] = fmaxf(acc, 0.f);
}

// ---------- decoder GEMM v3: 8m x 64n tile, per-wave K-split x4, ping-pong float4 B batches ----------
template <int ACT>
__global__ __launch_bounds__(256) void mlp3_k(const float* __restrict__ A,
                                              const float* __restrict__ Bm,
                                              const float* __restrict__ bias,
                                              float* __restrict__ C, int N, int K) {
    extern __shared__ float Asm[];                    // 8*(K+4) floats; tail-reused for reduce
    const int t = threadIdx.x;
    const int m0 = blockIdx.y * 8, n0 = blockIdx.x * 64;
    const int RS = K + 4;
    const int k4 = K >> 2;
    for (int i = t; i < 8 * k4; i += 256) {           // stage A tile, float4 units
        const int r = i / k4, c = i - r * k4;
        *(float4*)&Asm[r * RS + c * 4] = *(const float4*)&A[(size_t)(m0 + r) * K + c * 4];
    }
    __syncthreads();
    const int lane = t & 63, w = t >> 6;
    const int mq = lane >> 4, nq = lane & 15;
    const int n = n0 + nq * 4;
    const int ncl = (n + 3 < N) ? n : (N - 4);        // clamp base col (16B-aligned, safe)
    const float* bp = Bm + ncl;
    const float* asA = &Asm[(mq * 2 + 0) * RS];
    const float* asB = &Asm[(mq * 2 + 1) * RS];
    const int kQ = K >> 2;                            // per-wave chunk (128 or 256)
    const int kBeg = w * kQ;
    const int nBat2 = kQ >> 4;                        // double-batches of 16 k
    float4 acc0 = {0.f, 0.f, 0.f, 0.f}, acc1 = {0.f, 0.f, 0.f, 0.f};
    float4 ba[8], bb[8];
#pragma unroll
    for (int d = 0; d < 8; ++d) ba[d] = *(const float4*)&bp[(size_t)(kBeg + d) * N];

#define MLP3_FMA(BATCH, KB)                                                       \
    _Pragma("unroll")                                                             \
    for (int d = 0; d < 8; ++d) {                                                 \
        const float4 b = BATCH[d];                                                \
        const float a0 = asA[(KB) + d];                                           \
        const float a1 = asB[(KB) + d];                                           \
        acc0.x = fmaf(a0, b.x, acc0.x); acc0.y = fmaf(a0, b.y, acc0.y);           \
        acc0.z = fmaf(a0, b.z, acc0.z); acc0.w = fmaf(a0, b.w, acc0.w);           \
        acc1.x = fmaf(a1, b.x, acc1.x); acc1.y = fmaf(a1, b.y, acc1.y);           \
        acc1.z = fmaf(a1, b.z, acc1.z); acc1.w = fmaf(a1, b.w, acc1.w);           \
    }

    int k = kBeg;
#pragma unroll 1
    for (int it = 0; it < nBat2; ++it) {
#pragma unroll
        for (int d = 0; d < 8; ++d) bb[d] = *(const float4*)&bp[(size_t)(k + 8 + d) * N];
        MLP3_FMA(ba, k)
        if (it + 1 < nBat2) {
#pragma unroll
            for (int d = 0; d < 8; ++d) ba[d] = *(const float4*)&bp[(size_t)(k + 16 + d) * N];
        }
        MLP3_FMA(bb, k + 8)
        k += 16;
    }
#undef MLP3_FMA

    // cross-wave k-quarter reduce via LDS (reuses Asm; 4*64*8 floats = 8 KB)
    __syncthreads();                                  // all waves done reading Asm
    float* red = Asm;
    float* my = &red[(size_t)(w * 64 + lane) * 8];
    my[0] = acc0.x; my[1] = acc0.y; my[2] = acc0.z; my[3] = acc0.w;
    my[4] = acc1.x; my[5] = acc1.y; my[6] = acc1.z; my[7] = acc1.w;
    __syncthreads();
    if (t < 64) {
        float o[8];
#pragma unroll
        for (int x = 0; x < 8; ++x)
            o[x] = red[(size_t)t * 8 + x] + red[(size_t)(64 + t) * 8 + x]
                 + red[(size_t)(128 + t) * 8 + x] + red[(size_t)(192 + t) * 8 + x];
        const int nn = n0 + (t & 15) * 4;
#pragma unroll
        for (int rm = 0; rm < 2; ++rm) {
            const int m = m0 + (t >> 4) * 2 + rm;
#pragma unroll
            for (int rn = 0; rn < 4; ++rn) {
                const int ncol = nn + rn;
                if (ncol < N) {
                    float v = o[rm * 4 + rn] + bias[ncol];
                    if (ACT == 0) v = fmaxf(v, 0.f);
                    else v = 1.f / (1.f + expf(-v));
                    C[(size_t)m * N + ncol] = v;
                }
            }
        }
    }
}

// ---------- launcher ----------
extern "C" void kernel_launch(void* const* d_in, const int* in_sizes, int n_in,
                              void* d_out, int out_size, void* d_ws, size_t ws_size,
                              hipStream_t stream) {
    const float* x   = (const float*)d_in[0];
    const float* w1  = (const float*)d_in[1];
    const float* b1  = (const float*)d_in[2];
    const float* w2  = (const float*)d_in[3];
    const float* b2  = (const float*)d_in[4];
    const float* Wc  = (const float*)d_in[5];
    const float* dw1 = (const float*)d_in[6];
    const float* db1 = (const float*)d_in[7];
    const float* dw2 = (const float*)d_in[8];
    const float* db2 = (const float*)d_in[9];
    const float* dw3 = (const float*)d_in[10];
    const float* db3 = (const float*)d_in[11];
    float* out = (float*)d_out;

    char* ws = (char*)d_ws;
    unsigned char* H1T8 = (unsigned char*)(ws + 0);            // 26,214,400 B fp8
    unsigned char* W2T8 = (unsigned char*)(ws + 26214400);     //  5,308,416 B fp8 (x16)
    unsigned short* PART = (unsigned short*)(ws + 31522816);   // 18,874,368 B bf16, z=4
    unsigned int*   UHAT = (unsigned int*)(ws + 0);            // 47,185,920 B fp8 b-major (aliases dead staging)
    float* U    = (float*)(ws + 50397184);                     //  9,437,184 B (after PART; dead after uhat_k)
    float* BL   = (float*)(ws + 59834368);                     // 11,796,480 B (live within route_all)
    float* S2   = (float*)(ws + 71958528);                     //    163,840 B (written by route_all)
    float* H1D  = (float*)(ws + 59834368);                     //    524,288 B (dead-BL space, after route_all)
    float* H2D  = (float*)(ws + 60358656);                     //  1,048,576 B

    prep_k<<<1024, 256, 0, stream>>>(x, w1, b1, w2, H1T8, W2T8);
    conv2_k<<<576, 256, 0, stream>>>(H1T8, W2T8, PART);
    squash_u_k<<<512, 256, 0, stream>>>(PART, b2, U);
    uhat_k<<<1152, 256, 0, stream>>>(Wc, U, UHAT);
    route_all_k<<<256, 512, 0, stream>>>(UHAT, BL, S2);
    final_k<<<256, 512, 0, stream>>>(S2, dw1, db1, out, H1D);
    mlp3_k<0><<<dim3(16, 32), 256, 8 * 516 * 4, stream>>>(H1D, dw2, db2, H2D, 1024, 512);
    mlp3_k<1><<<dim3(13, 32), 256, 8 * 1028 * 4, stream>>>(H2D, dw3, db3, out + 2560, 784, 1024);
}

// Round 16
// 295.805 us; speedup vs baseline: 1.7516x; 1.0543x over previous
//
#include <hip/hip_runtime.h>
#include <cstdint>
#include <cstddef>

// ---------- types / helpers ----------
typedef __bf16 bf16x8 __attribute__((ext_vector_type(8)));
typedef short  shortx8 __attribute__((ext_vector_type(8)));
typedef float  floatx4 __attribute__((ext_vector_type(4)));
typedef float  floatx2 __attribute__((ext_vector_type(2)));
typedef float  floatx16 __attribute__((ext_vector_type(16)));
typedef int    intx4v __attribute__((ext_vector_type(4)));
typedef int    intx8 __attribute__((ext_vector_type(8)));
typedef unsigned short ushort8 __attribute__((ext_vector_type(8)));
typedef unsigned short ushort4v __attribute__((ext_vector_type(4)));

__device__ __forceinline__ float bflo(unsigned int u) {
    union { unsigned int u32; float f; } x; x.u32 = u << 16; return x.f;
}
__device__ __forceinline__ float bfhi(unsigned int u) {
    union { unsigned int u32; float f; } x; x.u32 = u & 0xffff0000u; return x.f;
}
__device__ __forceinline__ unsigned short f2bf(float f) {
    union { float f; unsigned int u; } x; x.f = f;
    unsigned int u = x.u;
    unsigned int r = (u + 0x7fffu + ((u >> 16) & 1u)) >> 16;   // RNE
    return (unsigned short)r;
}
__device__ __forceinline__ unsigned char f2fp8(float f) {
    unsigned int pk = __builtin_amdgcn_cvt_pk_fp8_f32(f, f, 0, false);
    return (unsigned char)(pk & 0xff);
}
// decode 4 fp8(e4m3) packed in u32 -> 4 floats
__device__ __forceinline__ void fp8x4_dec(unsigned int u, float* f) {
    floatx2 lo = __builtin_amdgcn_cvt_pk_f32_fp8(u, false);
    floatx2 hi = __builtin_amdgcn_cvt_pk_f32_fp8(u, true);
    f[0] = lo[0]; f[1] = lo[1]; f[2] = hi[0]; f[3] = hi[1];
}

#define GLOBAL_U32 const __attribute__((address_space(1))) unsigned int*
#define LDS_U32 __attribute__((address_space(3))) unsigned int*
__device__ __forceinline__ void async_cp16(const void* g, void* l) {
    __builtin_amdgcn_global_load_lds((GLOBAL_U32)g, (LDS_U32)l, 16, 0, 0);
}

#define UHAT_SCALE 64.0f
#define UHAT_INV   (1.0f / 64.0f)
#define W2_SCALE   16.0f
#define W2_INV     (1.0f / 16.0f)

// ---------- prep: conv1 via bf16 MFMA (blocks 0..511) + w2t fp8 (512..1023) ----------
__global__ __launch_bounds__(256) void prep_k(const float* __restrict__ x,
                                              const float* __restrict__ w1c,
                                              const float* __restrict__ b1c,
                                              const float* __restrict__ w2,
                                              unsigned char* __restrict__ h1t8,
                                              unsigned char* __restrict__ w2t8) {
    const int blk = blockIdx.x, t = threadIdx.x;
    if (blk < 512) {
        // block = (image b, ch-half): M=400 spatial, N=128 ch, K=96 (81 real taps)
        __shared__ float xs[1024];                    // 28x28 image + zero pad
        __shared__ unsigned short wb[96 * 132];       // [tap][ch-local] bf16, stride 132
        const int b = blk >> 1, ch0 = (blk & 1) * 128;
        for (int i = t; i < 1024; i += 256) xs[i] = (i < 784) ? x[b * 784 + i] : 0.f;
        for (int i = t; i < 96 * 132; i += 256) wb[i] = 0;
        __syncthreads();
        for (int i = t; i < 81 * 128; i += 256) {
            const int tap = i >> 7, chl = i & 127;
            wb[tap * 132 + chl] = f2bf(w1c[(size_t)(ch0 + chl) * 81 + tap]);
        }
        __syncthreads();
        const int lane = t & 63, l15 = lane & 15, g = lane >> 4;
        const int wave = t >> 6;
        const int n0l = wave * 32;                    // wave owns 32 local ch (2 N-tiles)
        int xoff[3][8];
#pragma unroll
        for (int kk = 0; kk < 3; ++kk)
#pragma unroll
            for (int e = 0; e < 8; ++e) {
                const int tap = kk * 32 + g * 8 + e;
                const int kh = tap / 9, kw = tap - 9 * kh;
                xoff[kk][e] = kh * 28 + kw;
            }
        shortx8 bF[2][3];
#pragma unroll
        for (int nt = 0; nt < 2; ++nt)
#pragma unroll
            for (int kk = 0; kk < 3; ++kk) {
                shortx8 v;
#pragma unroll
                for (int e = 0; e < 8; ++e) {
                    const int tap = kk * 32 + g * 8 + e;
                    v[e] = (short)wb[tap * 132 + n0l + nt * 16 + l15];
                }
                bF[nt][kk] = v;
            }
        float bv[2][4];
#pragma unroll
        for (int nt = 0; nt < 2; ++nt)
#pragma unroll
            for (int r = 0; r < 4; ++r)
                bv[nt][r] = b1c[ch0 + n0l + nt * 16 + g * 4 + r];
        for (int mt = 0; mt < 25; ++mt) {
            const int s = mt * 16 + l15;              // spatial: A-load row AND D col
            const int oh = s / 20, ow = s - 20 * oh;
            const int s2 = oh * 28 + ow;
            shortx8 aF[3];
#pragma unroll
            for (int kk = 0; kk < 3; ++kk) {
                shortx8 v;
#pragma unroll
                for (int e = 0; e < 8; ++e) v[e] = (short)f2bf(xs[s2 + xoff[kk][e]]);
                aF[kk] = v;
            }
            const size_t sbase = ((size_t)(b * 20 + oh) * 20 + ow) * 256 + ch0 + n0l + g * 4;
#pragma unroll
            for (int nt = 0; nt < 2; ++nt) {
                floatx4 acc = (floatx4){0.f, 0.f, 0.f, 0.f};
#pragma unroll
                for (int kk = 0; kk < 3; ++kk)
                    acc = __builtin_amdgcn_mfma_f32_16x16x32_bf16(bF[nt][kk], aF[kk], acc, 0, 0, 0);
                unsigned int w = 0;
                w = __builtin_amdgcn_cvt_pk_fp8_f32(acc[0] + bv[nt][0], acc[1] + bv[nt][1], w, false);
                w = __builtin_amdgcn_cvt_pk_fp8_f32(acc[2] + bv[nt][2], acc[3] + bv[nt][3], w, true);
                *(unsigned int*)(h1t8 + sbase + nt * 16) = w;
            }
        }
    } else {
        // w2 transform: OIHW fp32 [oc][ic][81] -> fp8 [oc][tap*256+ic], x16 scale
        __shared__ float shm[10368];
        const int id = blk - 512;
        const int oc = id >> 1, half = id & 1;
        const float* src = w2 + (size_t)oc * 20736 + half * 128 * 81;
        for (int idx = t; idx < 10368; idx += 256) shm[idx] = src[idx];
        __syncthreads();
        unsigned char* dst = w2t8 + (size_t)oc * 20736 + half * 128;
        for (int idx = t; idx < 10368; idx += 256) {
            const int tap = idx >> 7, icl = idx & 127;
            dst[tap * 256 + icl] = f2fp8(shm[icl * 81 + tap] * W2_SCALE);
        }
    }
}

// ---------- conv2 implicit GEMM, MX-scaled fp8 MFMA (unit scales): proven-best structure ----------
__device__ __forceinline__ int c2_rowbase(int m) {
    const int b = m / 36, sp = m % 36;
    const int oh = sp / 6, ow = sp % 6;
    return (b * 400 + oh * 40 + ow * 2) * 256;        // byte offset into h1t8 (1 B/elem)
}

__global__ __launch_bounds__(256) void conv2_k(const unsigned char* __restrict__ h1t8,
                                               const unsigned char* __restrict__ w2t8,
                                               unsigned short* __restrict__ part) {
    const int t = threadIdx.x;
    const int id = blockIdx.x;                        // 0..575
    const int G = id >> 4;                            // 0..35
    const int bx = (id >> 3) & 1;                     // 0..1 (128-oc tile)
    const int s = id & 7;
    const int by = 2 * G + (s >> 2);                  // 0..71
    const int z  = ((s & 3) + by) & 3;                // 0..3
    __shared__ unsigned char At[128 * 128];           // m rows, 128 fp8 (16 KB)
    __shared__ unsigned char Bt[128 * 128];           // oc rows (16 KB)

    const int oc0 = bx * 128;

    int aRB[4], bBase[4];
#pragma unroll
    for (int k = 0; k < 4; ++k) {
        const int a = t + 256 * k;
        const int r = a >> 3, sg = a & 7;
        const int u = sg ^ (r & 7);
        aRB[k] = c2_rowbase(by * 128 + r) + u * 16;
        bBase[k] = (oc0 + r) * 20736 + u * 16;
    }

    const int lane = t & 63, l31 = lane & 31, h = lane >> 5;
    const int wave = t >> 6;
    const int wM = (wave & 1) * 64, wOC = (wave >> 1) * 64;

    int aO[2][2][2], bO[2][2][2];
#pragma unroll
    for (int i = 0; i < 2; ++i) {
        const int Ra = wOC + i * 32 + l31;            // oc row (A-operand from Bt)
        const int Rb = wM + i * 32 + l31;             // m row  (B-operand from At)
#pragma unroll
        for (int st = 0; st < 2; ++st)
#pragma unroll
            for (int p = 0; p < 2; ++p) {
                const int c = st * 4 + h * 2 + p;
                aO[st][i][p] = Ra * 128 + ((c ^ (Ra & 7)) << 4);
                bO[st][i][p] = Rb * 128 + ((c ^ (Rb & 7)) << 4);
            }
    }

    floatx16 acc[2][2];                               // [oc-tile][m-tile]
#pragma unroll
    for (int i = 0; i < 2; ++i)
#pragma unroll
        for (int j = 0; j < 2; ++j)
#pragma unroll
            for (int r = 0; r < 16; ++r) acc[i][j][r] = 0.f;

    const int q0 = (162 * z) >> 2, q1 = (162 * (z + 1)) >> 2;
    for (int q = q0; q < q1; ++q) {
        const int tap = q >> 1;                       // BK=128 = half a tap; never crosses
        const int kh = tap / 9, kw = tap - 9 * kh;
        const int aoffB = (kh * 20 + kw) * 256 + (q & 1) * 128;
        __syncthreads();
#pragma unroll
        for (int k = 0; k < 4; ++k)
            async_cp16(h1t8 + aRB[k] + aoffB, At + (t + 256 * k) * 16);
#pragma unroll
        for (int k = 0; k < 4; ++k)
            async_cp16(w2t8 + bBase[k] + q * 128, Bt + (t + 256 * k) * 16);
        __syncthreads();
#pragma unroll
        for (int st = 0; st < 2; ++st) {
            intx8 aF[2], bF[2];
#pragma unroll
            for (int i = 0; i < 2; ++i) {
                const intx4v alo = *(const intx4v*)(Bt + aO[st][i][0]);
                const intx4v ahi = *(const intx4v*)(Bt + aO[st][i][1]);
                aF[i] = (intx8){alo[0], alo[1], alo[2], alo[3], ahi[0], ahi[1], ahi[2], ahi[3]};
                const intx4v blo = *(const intx4v*)(At + bO[st][i][0]);
                const intx4v bhi = *(const intx4v*)(At + bO[st][i][1]);
                bF[i] = (intx8){blo[0], blo[1], blo[2], blo[3], bhi[0], bhi[1], bhi[2], bhi[3]};
            }
#pragma unroll
            for (int i = 0; i < 2; ++i)
#pragma unroll
                for (int j = 0; j < 2; ++j)
                    acc[i][j] = __builtin_amdgcn_mfma_scale_f32_32x32x64_f8f6f4(
                        aF[i], bF[j], acc[i][j], 0, 0, 0, 127, 0, 127);
        }
    }

    // epilogue: D col(lane&31)=m, row=(reg&3)+8*(reg>>2)+4*h = oc; undo W2 scale
    unsigned short* pz = part + (size_t)z * 2359296;
#pragma unroll
    for (int i = 0; i < 2; ++i) {
#pragma unroll
        for (int j = 0; j < 2; ++j) {
            const int m = by * 128 + wM + j * 32 + l31;
#pragma unroll
            for (int rg = 0; rg < 4; ++rg) {
                const int oc = oc0 + wOC + i * 32 + rg * 8 + 4 * h;
                ushort4v pk;
#pragma unroll
                for (int rr = 0; rr < 4; ++rr) pk[rr] = f2bf(acc[i][j][rg * 4 + rr] * W2_INV);
                *(ushort4v*)(pz + (size_t)m * 256 + oc) = pk;
            }
        }
    }
}

// ---------- reduce split-K(bf16 x4) + bias + squash(axis=w) -> u[b][1152][8] (half-split x2) ----------
__global__ __launch_bounds__(256) void squash_u_k(const unsigned short* __restrict__ part,
                                                  const float* __restrict__ bias,
                                                  float* __restrict__ u) {
    const int bb = blockIdx.x, t = threadIdx.x;
    const int b = bb >> 1, h = bb & 1;
    __shared__ float hs[4608];
    const size_t base = (size_t)b * 9216 + h * 4608;
    for (int q = t; q < 2304; q += 256) {
        const int idx = q * 2;
        float v0 = bias[idx & 255], v1 = bias[(idx + 1) & 255];
#pragma unroll
        for (int z = 0; z < 4; ++z) {
            const unsigned int uu = *(const unsigned int*)(part + (size_t)z * 2359296 + base + idx);
            v0 += bflo(uu);
            v1 += bfhi(uu);
        }
        hs[idx] = v0; hs[idx + 1] = v1;
    }
    __syncthreads();
    for (int gq = t; gq < 768; gq += 256) {           // groups (c, oh-local), squash over ow(6)
        const int c = gq / 3, ohl = gq % 3;
        const int oh = h * 3 + ohl;
        float s[6], sq = 0.f;
#pragma unroll
        for (int ow = 0; ow < 6; ++ow) { s[ow] = hs[(ohl * 6 + ow) * 256 + c]; sq = fmaf(s[ow], s[ow], sq); }
        const float norm = sqrtf(sq);
        const float f = (sq / (1.0f + sq)) / (norm + 1e-7f);
        float* up = u + (size_t)b * 9216 + c * 36 + oh * 6;
#pragma unroll
        for (int ow = 0; ow < 6; ++ow) up[ow] = s[ow] * f;
    }
}

// ---------- u_hat fp8, B-MAJOR layout: uhat8[b][i][40 u32] = e4m3(64 * W_i u_b) ----------
__global__ __launch_bounds__(256) void uhat_k(const float* __restrict__ Wc,
                                              const float* __restrict__ u,
                                              unsigned int* __restrict__ uhat8) {
    const int i = blockIdx.x, t = threadIdx.x;       // t = b
    __shared__ float Wl[1280];                       // [o][d*8+e]
    __shared__ __align__(16) unsigned int Ust[256 * 40];   // 40 KB staging [b][40]
    for (int idx = t; idx < 1280; idx += 256) {
        const int o = idx >> 7, r = idx & 127;
        Wl[idx] = Wc[((size_t)o * 1152 + i) * 128 + r];
    }
    float ur[8];
    *(float4*)&ur[0] = *(const float4*)(u + (size_t)t * 9216 + i * 8);
    *(float4*)&ur[4] = *(const float4*)(u + (size_t)t * 9216 + i * 8 + 4);
    __syncthreads();
    unsigned int* myrow = Ust + t * 40;
#pragma unroll 1
    for (int o = 0; o < 10; ++o) {
        float vals[16];
#pragma unroll
        for (int d = 0; d < 16; ++d) {
            const float* wp = &Wl[o * 128 + d * 8];
            float a = 0.f;
#pragma unroll
            for (int e = 0; e < 8; ++e) a = fmaf(wp[e], ur[e], a);
            vals[d] = a * UHAT_SCALE;
        }
        uint4 pk;
        unsigned int w;
#pragma unroll
        for (int q = 0; q < 4; ++q) {
            w = 0;
            w = __builtin_amdgcn_cvt_pk_fp8_f32(vals[q * 4 + 0], vals[q * 4 + 1], w, false);
            w = __builtin_amdgcn_cvt_pk_fp8_f32(vals[q * 4 + 2], vals[q * 4 + 3], w, true);
            if (q == 0) pk.x = w; else if (q == 1) pk.y = w; else if (q == 2) pk.z = w; else pk.w = w;
        }
        *(uint4*)(myrow + o * 4) = pk;
    }
    __syncthreads();
    // copy-out: unit u2 = b*10 + q -> uhat8[b][i][q*4..q*4+3]
    for (int u2 = t; u2 < 2560; u2 += 256) {
        const int bb = u2 / 10, q = u2 - bb * 10;
        *(uint4*)(uhat8 + (size_t)bb * 46080 + (size_t)i * 40 + q * 4) = *(const uint4*)(Ust + u2 * 4);
    }
}

// ---------- fused routing (all 3 iterations), one block (512 thr) per image b ----------
// 256-i chunks (5 per pass, tail 128): barrier phases per pass 15 (was 27), doubled
// staged bursts. Per-lane i-accumulation order identical to the 128-chunk version.
__global__ __launch_bounds__(512) void route_all_k(const unsigned int* __restrict__ uhat8,
                                                   float* __restrict__ BL,
                                                   float* __restrict__ S2out) {
    const int b = blockIdx.x, t = threadIdx.x;
    __shared__ __align__(16) unsigned int Ul8[2][256 * 40];  // 2 x 40 KB chunk buffers
    __shared__ float Vl[160];
    __shared__ float cT[10 * 264];                    // [o][i_local], stride 264
    __shared__ float dots[2560];                      // p1a out (2560) / reduce scratch (1920)

    // p2 roles: 480 active lanes = 6 k-segments x 2 halves x 40 od-quads
    const int seg = t / 80, rr = t - seg * 80;
    const int hi = rr / 40, th = rr - hi * 40;
    const int oq = th >> 2;
    const bool p2act = (t < 480);
    const int lo = (seg * 64) / 6, hiE = ((seg + 1) * 64) / 6;   // ~10-11 i each
    // p1a roles: 500 active
    const int o = t % 10, sidx = t / 10;

    const unsigned int* ubase = uhat8 + (size_t)b * 46080;   // b-major slab
    auto stage = [&](int buf, int ck, int nI) {
        const unsigned int* ub = ubase + (size_t)ck * 10240;  // 256 rows x 40 u32
        const int units = nI * 10;
        for (int c = t; c < units; c += 512)
            async_cp16(ub + (size_t)c * 4, (char*)Ul8[buf] + c * 16);
    };
    // chunk sizes: ck 0..3 -> 256, ck 4 -> 128
#define NI_OF(ck) ((ck) < 4 ? 256 : 128)

    // ---- iteration 0: S0 = (0.1/64) * sum_i dec(uhat) ----
    float a0 = 0.f, a1 = 0.f, a2 = 0.f, a3 = 0.f;
    stage(0, 0, 256);
    __syncthreads();
    for (int ck = 0; ck < 5; ++ck) {
        const int cur = ck & 1;
        const int nI = NI_OF(ck);
        if (ck + 1 < 5) stage(cur ^ 1, ck + 1, NI_OF(ck + 1));
        if (p2act) {
#pragma unroll
            for (int sc = 0; sc < 2; ++sc) {
                if (sc * 128 < nI) {
                    const unsigned int* base = Ul8[cur] + (sc * 128 + hi * 64) * 40 + th;
                    for (int ii = lo; ii < hiE; ++ii) {
                        float f[4];
                        fp8x4_dec(base[ii * 40], f);
                        a0 += f[0]; a1 += f[1]; a2 += f[2]; a3 += f[3];
                    }
                }
            }
        }
        __syncthreads();                              // buf[cur] free + prefetch landed
    }
    if (p2act) {
        const int rb = seg * 320 + hi * 160 + 4 * th;
        dots[rb + 0] = a0; dots[rb + 1] = a1; dots[rb + 2] = a2; dots[rb + 3] = a3;
    }
    __syncthreads();
    if (t < 160) {
        float xv = 0.f;
#pragma unroll
        for (int j = 0; j < 12; ++j) xv += dots[j * 160 + t];
        xv *= 0.1f * UHAT_INV;
        float sq = xv * xv;
        sq += __shfl_xor(sq, 1, 16);
        sq += __shfl_xor(sq, 2, 16);
        sq += __shfl_xor(sq, 4, 16);
        sq += __shfl_xor(sq, 8, 16);
        const float norm = sqrtf(sq);
        const float f = (sq / (1.f + sq)) / (norm + 1e-7f);
        Vl[t] = xv * f;
    }
    __syncthreads();

    // ---- iterations 1 and 2 ----
    for (int it = 1; it <= 2; ++it) {
        float vr[16];
        if (t < 500) {
#pragma unroll
            for (int q = 0; q < 4; ++q)
                *(float4*)&vr[q * 4] = *(const float4*)(&Vl[o * 16 + q * 4]);
        }
        a0 = a1 = a2 = a3 = 0.f;
        stage(0, 0, 256);
        __syncthreads();
        for (int ck = 0; ck < 5; ++ck) {
            const int cur = ck & 1;
            const int nI = NI_OF(ck);
            if (ck + 1 < 5) stage(cur ^ 1, ck + 1, NI_OF(ck + 1));
            // p1a: dots[i][o] = (1/64) * uhat[i,o,:] . v[o,:]  (500 lanes, up to 6 reps)
            if (t < 500) {
#pragma unroll
                for (int rep = 0; rep < 6; ++rep) {
                    const int i = sidx + 50 * rep;
                    if (i < nI) {
                        const uint4 uu = *(const uint4*)(Ul8[cur] + i * 40 + o * 4);
                        float f[16];
                        fp8x4_dec(uu.x, f);
                        fp8x4_dec(uu.y, f + 4);
                        fp8x4_dec(uu.z, f + 8);
                        fp8x4_dec(uu.w, f + 12);
                        float dot = 0.f;
#pragma unroll
                        for (int d = 0; d < 16; ++d) dot = fmaf(f[d], vr[d], dot);
                        dots[i * 10 + o] = dot * UHAT_INV;
                    }
                }
            }
            __syncthreads();
            // p1b: logits + softmax -> cT[o][i_local] (one i per lane, t < nI)
            if (t < nI) {
                float bl[10];
#pragma unroll
                for (int oo = 0; oo < 10; ++oo) bl[oo] = dots[t * 10 + oo];
                const size_t blb = (size_t)b * 11520 + (size_t)ck * 256 + t;
                if (it == 1) {
#pragma unroll
                    for (int oo = 0; oo < 10; ++oo) BL[blb + (size_t)oo * 1152] = bl[oo];
                } else {
#pragma unroll
                    for (int oo = 0; oo < 10; ++oo) bl[oo] += BL[blb + (size_t)oo * 1152];
                }
                float mx = bl[0];
#pragma unroll
                for (int oo = 1; oo < 10; ++oo) mx = fmaxf(mx, bl[oo]);
                float ex[10], sum = 0.f;
#pragma unroll
                for (int oo = 0; oo < 10; ++oo) { ex[oo] = expf(bl[oo] - mx); sum += ex[oo]; }
                const float inv = 1.f / sum;
#pragma unroll
                for (int oo = 0; oo < 10; ++oo) cT[oo * 264 + t] = ex[oo] * inv;
            }
            __syncthreads();
            // p2: accumulate S += c[i][o] * dec(uhat[i][od])
            if (p2act) {
#pragma unroll
                for (int sc = 0; sc < 2; ++sc) {
                    if (sc * 128 < nI) {
                        const unsigned int* base = Ul8[cur] + (sc * 128 + hi * 64) * 40 + th;
                        const float* cb = &cT[oq * 264 + sc * 128 + hi * 64];
                        for (int ii = lo; ii < hiE; ++ii) {
                            const float c = cb[ii];
                            float f[4];
                            fp8x4_dec(base[ii * 40], f);
                            a0 = fmaf(c, f[0], a0);
                            a1 = fmaf(c, f[1], a1);
                            a2 = fmaf(c, f[2], a2);
                            a3 = fmaf(c, f[3], a3);
                        }
                    }
                }
            }
            __syncthreads();
        }
        if (p2act) {
            const int rb = seg * 320 + hi * 160 + 4 * th;
            dots[rb + 0] = a0; dots[rb + 1] = a1; dots[rb + 2] = a2; dots[rb + 3] = a3;
        }
        __syncthreads();
        if (t < 160) {
            float sv = 0.f;
#pragma unroll
            for (int j = 0; j < 12; ++j) sv += dots[j * 160 + t];
            sv *= UHAT_INV;
            if (it == 1) {
                float sq = sv * sv;
                sq += __shfl_xor(sq, 1, 16);
                sq += __shfl_xor(sq, 2, 16);
                sq += __shfl_xor(sq, 4, 16);
                sq += __shfl_xor(sq, 8, 16);
                const float norm = sqrtf(sq);
                const float f = (sq / (1.f + sq)) / (norm + 1e-7f);
                Vl[t] = sv * f;
            } else {
                S2out[b * 160 + t] = sv;
            }
        }
        __syncthreads();
    }
#undef NI_OF
}

// ---------- final: squash S2 -> lengths, argmax + fused decoder layer 1 ----------
__global__ __launch_bounds__(512) void final_k(const float* __restrict__ S,
                                               const float* __restrict__ w1,
                                               const float* __restrict__ b1,
                                               float* __restrict__ out_len,
                                               float* __restrict__ h1d) {
    const int b = blockIdx.x, t = threadIdx.x;
    __shared__ float v_s[160];
    __shared__ float len_s[10];
    __shared__ int sel_s;
    if (t < 160) {
        const float x = S[b * 160 + t];
        float sq = x * x;
        sq += __shfl_xor(sq, 1, 16);
        sq += __shfl_xor(sq, 2, 16);
        sq += __shfl_xor(sq, 4, 16);
        sq += __shfl_xor(sq, 8, 16);
        const float norm = sqrtf(sq);
        const float f = (sq / (1.f + sq)) / (norm + 1e-7f);
        v_s[t] = x * f;
        if ((t & 15) == 0) {
            const float len = f * norm;
            len_s[t >> 4] = len;
            out_len[b * 10 + (t >> 4)] = len;
        }
    }
    __syncthreads();
    if (t == 0) {
        float best = len_s[0]; int bi = 0;
        for (int oo = 1; oo < 10; ++oo) if (len_s[oo] > best) { best = len_s[oo]; bi = oo; }
        sel_s = bi;
    }
    __syncthreads();
    const int s = sel_s;
    float acc = b1[t];
    const float* wrow = w1 + (size_t)(s * 16) * 512 + t;
#pragma unroll
    for (int j = 0; j < 16; ++j) acc = fmaf(v_s[s * 16 + j], wrow[j * 512], acc);
    h1d[(size_t)b * 512 + t] = fmaxf(acc, 0.f);
}

// ---------- decoder GEMM v3: 8m x 64n tile, per-wave K-split x4, ping-pong float4 B batches ----------
template <int ACT>
__global__ __launch_bounds__(256) void mlp3_k(const float* __restrict__ A,
                                              const float* __restrict__ Bm,
                                              const float* __restrict__ bias,
                                              float* __restrict__ C, int N, int K) {
    extern __shared__ float Asm[];                    // 8*(K+4) floats; tail-reused for reduce
    const int t = threadIdx.x;
    const int m0 = blockIdx.y * 8, n0 = blockIdx.x * 64;
    const int RS = K + 4;
    const int k4 = K >> 2;
    for (int i = t; i < 8 * k4; i += 256) {           // stage A tile, float4 units
        const int r = i / k4, c = i - r * k4;
        *(float4*)&Asm[r * RS + c * 4] = *(const float4*)&A[(size_t)(m0 + r) * K + c * 4];
    }
    __syncthreads();
    const int lane = t & 63, w = t >> 6;
    const int mq = lane >> 4, nq = lane & 15;
    const int n = n0 + nq * 4;
    const int ncl = (n + 3 < N) ? n : (N - 4);        // clamp base col (16B-aligned, safe)
    const float* bp = Bm + ncl;
    const float* asA = &Asm[(mq * 2 + 0) * RS];
    const float* asB = &Asm[(mq * 2 + 1) * RS];
    const int kQ = K >> 2;                            // per-wave chunk (128 or 256)
    const int kBeg = w * kQ;
    const int nBat2 = kQ >> 4;                        // double-batches of 16 k
    float4 acc0 = {0.f, 0.f, 0.f, 0.f}, acc1 = {0.f, 0.f, 0.f, 0.f};
    float4 ba[8], bb[8];
#pragma unroll
    for (int d = 0; d < 8; ++d) ba[d] = *(const float4*)&bp[(size_t)(kBeg + d) * N];

#define MLP3_FMA(BATCH, KB)                                                       \
    _Pragma("unroll")                                                             \
    for (int d = 0; d < 8; ++d) {                                                 \
        const float4 b = BATCH[d];                                                \
        const float a0 = asA[(KB) + d];                                           \
        const float a1 = asB[(KB) + d];                                           \
        acc0.x = fmaf(a0, b.x, acc0.x); acc0.y = fmaf(a0, b.y, acc0.y);           \
        acc0.z = fmaf(a0, b.z, acc0.z); acc0.w = fmaf(a0, b.w, acc0.w);           \
        acc1.x = fmaf(a1, b.x, acc1.x); acc1.y = fmaf(a1, b.y, acc1.y);           \
        acc1.z = fmaf(a1, b.z, acc1.z); acc1.w = fmaf(a1, b.w, acc1.w);           \
    }

    int k = kBeg;
#pragma unroll 1
    for (int it = 0; it < nBat2; ++it) {
#pragma unroll
        for (int d = 0; d < 8; ++d) bb[d] = *(const float4*)&bp[(size_t)(k + 8 + d) * N];
        MLP3_FMA(ba, k)
        if (it + 1 < nBat2) {
#pragma unroll
            for (int d = 0; d < 8; ++d) ba[d] = *(const float4*)&bp[(size_t)(k + 16 + d) * N];
        }
        MLP3_FMA(bb, k + 8)
        k += 16;
    }
#undef MLP3_FMA

    // cross-wave k-quarter reduce via LDS (reuses Asm; 4*64*8 floats = 8 KB)
    __syncthreads();                                  // all waves done reading Asm
    float* red = Asm;
    float* my = &red[(size_t)(w * 64 + lane) * 8];
    my[0] = acc0.x; my[1] = acc0.y; my[2] = acc0.z; my[3] = acc0.w;
    my[4] = acc1.x; my[5] = acc1.y; my[6] = acc1.z; my[7] = acc1.w;
    __syncthreads();
    if (t < 64) {
        float o[8];
#pragma unroll
        for (int x = 0; x < 8; ++x)
            o[x] = red[(size_t)t * 8 + x] + red[(size_t)(64 + t) * 8 + x]
                 + red[(size_t)(128 + t) * 8 + x] + red[(size_t)(192 + t) * 8 + x];
        const int nn = n0 + (t & 15) * 4;
#pragma unroll
        for (int rm = 0; rm < 2; ++rm) {
            const int m = m0 + (t >> 4) * 2 + rm;
#pragma unroll
            for (int rn = 0; rn < 4; ++rn) {
                const int ncol = nn + rn;
                if (ncol < N) {
                    float v = o[rm * 4 + rn] + bias[ncol];
                    if (ACT == 0) v = fmaxf(v, 0.f);
                    else v = 1.f / (1.f + expf(-v));
                    C[(size_t)m * N + ncol] = v;
                }
            }
        }
    }
}

// ---------- launcher ----------
extern "C" void kernel_launch(void* const* d_in, const int* in_sizes, int n_in,
                              void* d_out, int out_size, void* d_ws, size_t ws_size,
                              hipStream_t stream) {
    const float* x   = (const float*)d_in[0];
    const float* w1  = (const float*)d_in[1];
    const float* b1  = (const float*)d_in[2];
    const float* w2  = (const float*)d_in[3];
    const float* b2  = (const float*)d_in[4];
    const float* Wc  = (const float*)d_in[5];
    const float* dw1 = (const float*)d_in[6];
    const float* db1 = (const float*)d_in[7];
    const float* dw2 = (const float*)d_in[8];
    const float* db2 = (const float*)d_in[9];
    const float* dw3 = (const float*)d_in[10];
    const float* db3 = (const float*)d_in[11];
    float* out = (float*)d_out;

    char* ws = (char*)d_ws;
    unsigned char* H1T8 = (unsigned char*)(ws + 0);            // 26,214,400 B fp8
    unsigned char* W2T8 = (unsigned char*)(ws + 26214400);     //  5,308,416 B fp8 (x16)
    unsigned short* PART = (unsigned short*)(ws + 31522816);   // 18,874,368 B bf16, z=4
    unsigned int*   UHAT = (unsigned int*)(ws + 0);            // 47,185,920 B fp8 b-major (aliases dead staging)
    float* U    = (float*)(ws + 50397184);                     //  9,437,184 B (after PART; dead after uhat_k)
    float* BL   = (float*)(ws + 59834368);                     // 11,796,480 B (live within route_all)
    float* S2   = (float*)(ws + 71958528);                     //    163,840 B (written by route_all)
    float* H1D  = (float*)(ws + 59834368);                     //    524,288 B (dead-BL space, after route_all)
    float* H2D  = (float*)(ws + 60358656);                     //  1,048,576 B

    prep_k<<<1024, 256, 0, stream>>>(x, w1, b1, w2, H1T8, W2T8);
    conv2_k<<<576, 256, 0, stream>>>(H1T8, W2T8, PART);
    squash_u_k<<<512, 256, 0, stream>>>(PART, b2, U);
    uhat_k<<<1152, 256, 0, stream>>>(Wc, U, UHAT);
    route_all_k<<<256, 512, 0, stream>>>(UHAT, BL, S2);
    final_k<<<256, 512, 0, stream>>>(S2, dw1, db1, out, H1D);
    mlp3_k<0><<<dim3(16, 32), 256, 8 * 516 * 4, stream>>>(H1D, dw2, db2, H2D, 1024, 512);
    mlp3_k<1><<<dim3(13, 32), 256, 8 * 1028 * 4, stream>>>(H2D, dw3, db3, out + 2560, 784, 1024);
}

// Round 17
// 292.789 us; speedup vs baseline: 1.7696x; 1.0103x over previous
//
#include <hip/hip_runtime.h>
#include <cstdint>
#include <cstddef>

// ---------- types / helpers ----------
typedef __bf16 bf16x8 __attribute__((ext_vector_type(8)));
typedef short  shortx8 __attribute__((ext_vector_type(8)));
typedef float  floatx4 __attribute__((ext_vector_type(4)));
typedef float  floatx2 __attribute__((ext_vector_type(2)));
typedef float  floatx16 __attribute__((ext_vector_type(16)));
typedef int    intx4v __attribute__((ext_vector_type(4)));
typedef int    intx8 __attribute__((ext_vector_type(8)));
typedef unsigned short ushort8 __attribute__((ext_vector_type(8)));
typedef unsigned short ushort4v __attribute__((ext_vector_type(4)));

__device__ __forceinline__ float bflo(unsigned int u) {
    union { unsigned int u32; float f; } x; x.u32 = u << 16; return x.f;
}
__device__ __forceinline__ float bfhi(unsigned int u) {
    union { unsigned int u32; float f; } x; x.u32 = u & 0xffff0000u; return x.f;
}
__device__ __forceinline__ unsigned short f2bf(float f) {
    union { float f; unsigned int u; } x; x.f = f;
    unsigned int u = x.u;
    unsigned int r = (u + 0x7fffu + ((u >> 16) & 1u)) >> 16;   // RNE
    return (unsigned short)r;
}
__device__ __forceinline__ unsigned char f2fp8(float f) {
    unsigned int pk = __builtin_amdgcn_cvt_pk_fp8_f32(f, f, 0, false);
    return (unsigned char)(pk & 0xff);
}
// decode 4 fp8(e4m3) packed in u32 -> 4 floats
__device__ __forceinline__ void fp8x4_dec(unsigned int u, float* f) {
    floatx2 lo = __builtin_amdgcn_cvt_pk_f32_fp8(u, false);
    floatx2 hi = __builtin_amdgcn_cvt_pk_f32_fp8(u, true);
    f[0] = lo[0]; f[1] = lo[1]; f[2] = hi[0]; f[3] = hi[1];
}

#define GLOBAL_U32 const __attribute__((address_space(1))) unsigned int*
#define LDS_U32 __attribute__((address_space(3))) unsigned int*
__device__ __forceinline__ void async_cp16(const void* g, void* l) {
    __builtin_amdgcn_global_load_lds((GLOBAL_U32)g, (LDS_U32)l, 16, 0, 0);
}

#define UHAT_SCALE 64.0f
#define UHAT_INV   (1.0f / 64.0f)
#define W2_SCALE   16.0f
#define W2_INV     (1.0f / 16.0f)

// ---------- prep: conv1 via bf16 MFMA (blocks 0..511) + w2t fp8 (512..1023) ----------
__global__ __launch_bounds__(256) void prep_k(const float* __restrict__ x,
                                              const float* __restrict__ w1c,
                                              const float* __restrict__ b1c,
                                              const float* __restrict__ w2,
                                              unsigned char* __restrict__ h1t8,
                                              unsigned char* __restrict__ w2t8) {
    const int blk = blockIdx.x, t = threadIdx.x;
    if (blk < 512) {
        // block = (image b, ch-half): M=400 spatial, N=128 ch, K=96 (81 real taps)
        __shared__ float xs[1024];                    // 28x28 image + zero pad
        __shared__ unsigned short wb[96 * 132];       // [tap][ch-local] bf16, stride 132
        const int b = blk >> 1, ch0 = (blk & 1) * 128;
        for (int i = t; i < 1024; i += 256) xs[i] = (i < 784) ? x[b * 784 + i] : 0.f;
        for (int i = t; i < 96 * 132; i += 256) wb[i] = 0;
        __syncthreads();
        for (int i = t; i < 81 * 128; i += 256) {
            const int tap = i >> 7, chl = i & 127;
            wb[tap * 132 + chl] = f2bf(w1c[(size_t)(ch0 + chl) * 81 + tap]);
        }
        __syncthreads();
        const int lane = t & 63, l15 = lane & 15, g = lane >> 4;
        const int wave = t >> 6;
        const int n0l = wave * 32;                    // wave owns 32 local ch (2 N-tiles)
        int xoff[3][8];
#pragma unroll
        for (int kk = 0; kk < 3; ++kk)
#pragma unroll
            for (int e = 0; e < 8; ++e) {
                const int tap = kk * 32 + g * 8 + e;
                const int kh = tap / 9, kw = tap - 9 * kh;
                xoff[kk][e] = kh * 28 + kw;
            }
        shortx8 bF[2][3];
#pragma unroll
        for (int nt = 0; nt < 2; ++nt)
#pragma unroll
            for (int kk = 0; kk < 3; ++kk) {
                shortx8 v;
#pragma unroll
                for (int e = 0; e < 8; ++e) {
                    const int tap = kk * 32 + g * 8 + e;
                    v[e] = (short)wb[tap * 132 + n0l + nt * 16 + l15];
                }
                bF[nt][kk] = v;
            }
        float bv[2][4];
#pragma unroll
        for (int nt = 0; nt < 2; ++nt)
#pragma unroll
            for (int r = 0; r < 4; ++r)
                bv[nt][r] = b1c[ch0 + n0l + nt * 16 + g * 4 + r];
        for (int mt = 0; mt < 25; ++mt) {
            const int s = mt * 16 + l15;              // spatial: A-load row AND D col
            const int oh = s / 20, ow = s - 20 * oh;
            const int s2 = oh * 28 + ow;
            shortx8 aF[3];
#pragma unroll
            for (int kk = 0; kk < 3; ++kk) {
                shortx8 v;
#pragma unroll
                for (int e = 0; e < 8; ++e) v[e] = (short)f2bf(xs[s2 + xoff[kk][e]]);
                aF[kk] = v;
            }
            const size_t sbase = ((size_t)(b * 20 + oh) * 20 + ow) * 256 + ch0 + n0l + g * 4;
#pragma unroll
            for (int nt = 0; nt < 2; ++nt) {
                floatx4 acc = (floatx4){0.f, 0.f, 0.f, 0.f};
#pragma unroll
                for (int kk = 0; kk < 3; ++kk)
                    acc = __builtin_amdgcn_mfma_f32_16x16x32_bf16(bF[nt][kk], aF[kk], acc, 0, 0, 0);
                unsigned int w = 0;
                w = __builtin_amdgcn_cvt_pk_fp8_f32(acc[0] + bv[nt][0], acc[1] + bv[nt][1], w, false);
                w = __builtin_amdgcn_cvt_pk_fp8_f32(acc[2] + bv[nt][2], acc[3] + bv[nt][3], w, true);
                *(unsigned int*)(h1t8 + sbase + nt * 16) = w;
            }
        }
    } else {
        // w2 transform: OIHW fp32 [oc][ic][81] -> fp8 [oc][tap*256+ic], x16 scale
        __shared__ float shm[10368];
        const int id = blk - 512;
        const int oc = id >> 1, half = id & 1;
        const float* src = w2 + (size_t)oc * 20736 + half * 128 * 81;
        for (int idx = t; idx < 10368; idx += 256) shm[idx] = src[idx];
        __syncthreads();
        unsigned char* dst = w2t8 + (size_t)oc * 20736 + half * 128;
        for (int idx = t; idx < 10368; idx += 256) {
            const int tap = idx >> 7, icl = idx & 127;
            dst[tap * 256 + icl] = f2fp8(shm[icl * 81 + tap] * W2_SCALE);
        }
    }
}

// ---------- conv2 implicit GEMM, MX-scaled fp8 MFMA (unit scales): proven-best structure ----------
__device__ __forceinline__ int c2_rowbase(int m) {
    const int b = m / 36, sp = m % 36;
    const int oh = sp / 6, ow = sp % 6;
    return (b * 400 + oh * 40 + ow * 2) * 256;        // byte offset into h1t8 (1 B/elem)
}

__global__ __launch_bounds__(256) void conv2_k(const unsigned char* __restrict__ h1t8,
                                               const unsigned char* __restrict__ w2t8,
                                               unsigned short* __restrict__ part) {
    const int t = threadIdx.x;
    const int id = blockIdx.x;                        // 0..575
    const int G = id >> 4;                            // 0..35
    const int bx = (id >> 3) & 1;                     // 0..1 (128-oc tile)
    const int s = id & 7;
    const int by = 2 * G + (s >> 2);                  // 0..71
    const int z  = ((s & 3) + by) & 3;                // 0..3
    __shared__ unsigned char At[128 * 128];           // m rows, 128 fp8 (16 KB)
    __shared__ unsigned char Bt[128 * 128];           // oc rows (16 KB)

    const int oc0 = bx * 128;

    int aRB[4], bBase[4];
#pragma unroll
    for (int k = 0; k < 4; ++k) {
        const int a = t + 256 * k;
        const int r = a >> 3, sg = a & 7;
        const int u = sg ^ (r & 7);
        aRB[k] = c2_rowbase(by * 128 + r) + u * 16;
        bBase[k] = (oc0 + r) * 20736 + u * 16;
    }

    const int lane = t & 63, l31 = lane & 31, h = lane >> 5;
    const int wave = t >> 6;
    const int wM = (wave & 1) * 64, wOC = (wave >> 1) * 64;

    int aO[2][2][2], bO[2][2][2];
#pragma unroll
    for (int i = 0; i < 2; ++i) {
        const int Ra = wOC + i * 32 + l31;            // oc row (A-operand from Bt)
        const int Rb = wM + i * 32 + l31;             // m row  (B-operand from At)
#pragma unroll
        for (int st = 0; st < 2; ++st)
#pragma unroll
            for (int p = 0; p < 2; ++p) {
                const int c = st * 4 + h * 2 + p;
                aO[st][i][p] = Ra * 128 + ((c ^ (Ra & 7)) << 4);
                bO[st][i][p] = Rb * 128 + ((c ^ (Rb & 7)) << 4);
            }
    }

    floatx16 acc[2][2];                               // [oc-tile][m-tile]
#pragma unroll
    for (int i = 0; i < 2; ++i)
#pragma unroll
        for (int j = 0; j < 2; ++j)
#pragma unroll
            for (int r = 0; r < 16; ++r) acc[i][j][r] = 0.f;

    const int q0 = (162 * z) >> 2, q1 = (162 * (z + 1)) >> 2;
    for (int q = q0; q < q1; ++q) {
        const int tap = q >> 1;                       // BK=128 = half a tap; never crosses
        const int kh = tap / 9, kw = tap - 9 * kh;
        const int aoffB = (kh * 20 + kw) * 256 + (q & 1) * 128;
        __syncthreads();
#pragma unroll
        for (int k = 0; k < 4; ++k)
            async_cp16(h1t8 + aRB[k] + aoffB, At + (t + 256 * k) * 16);
#pragma unroll
        for (int k = 0; k < 4; ++k)
            async_cp16(w2t8 + bBase[k] + q * 128, Bt + (t + 256 * k) * 16);
        __syncthreads();
#pragma unroll
        for (int st = 0; st < 2; ++st) {
            intx8 aF[2], bF[2];
#pragma unroll
            for (int i = 0; i < 2; ++i) {
                const intx4v alo = *(const intx4v*)(Bt + aO[st][i][0]);
                const intx4v ahi = *(const intx4v*)(Bt + aO[st][i][1]);
                aF[i] = (intx8){alo[0], alo[1], alo[2], alo[3], ahi[0], ahi[1], ahi[2], ahi[3]};
                const intx4v blo = *(const intx4v*)(At + bO[st][i][0]);
                const intx4v bhi = *(const intx4v*)(At + bO[st][i][1]);
                bF[i] = (intx8){blo[0], blo[1], blo[2], blo[3], bhi[0], bhi[1], bhi[2], bhi[3]};
            }
#pragma unroll
            for (int i = 0; i < 2; ++i)
#pragma unroll
                for (int j = 0; j < 2; ++j)
                    acc[i][j] = __builtin_amdgcn_mfma_scale_f32_32x32x64_f8f6f4(
                        aF[i], bF[j], acc[i][j], 0, 0, 0, 127, 0, 127);
        }
    }

    // epilogue: D col(lane&31)=m, row=(reg&3)+8*(reg>>2)+4*h = oc; undo W2 scale
    unsigned short* pz = part + (size_t)z * 2359296;
#pragma unroll
    for (int i = 0; i < 2; ++i) {
#pragma unroll
        for (int j = 0; j < 2; ++j) {
            const int m = by * 128 + wM + j * 32 + l31;
#pragma unroll
            for (int rg = 0; rg < 4; ++rg) {
                const int oc = oc0 + wOC + i * 32 + rg * 8 + 4 * h;
                ushort4v pk;
#pragma unroll
                for (int rr = 0; rr < 4; ++rr) pk[rr] = f2bf(acc[i][j][rg * 4 + rr] * W2_INV);
                *(ushort4v*)(pz + (size_t)m * 256 + oc) = pk;
            }
        }
    }
}

// ---------- reduce split-K(bf16 x4) + bias + squash(axis=w) -> u[b][1152][8] (half-split x2) ----------
__global__ __launch_bounds__(256) void squash_u_k(const unsigned short* __restrict__ part,
                                                  const float* __restrict__ bias,
                                                  float* __restrict__ u) {
    const int bb = blockIdx.x, t = threadIdx.x;
    const int b = bb >> 1, h = bb & 1;
    __shared__ float hs[4608];
    const size_t base = (size_t)b * 9216 + h * 4608;
    for (int q = t; q < 2304; q += 256) {
        const int idx = q * 2;
        float v0 = bias[idx & 255], v1 = bias[(idx + 1) & 255];
#pragma unroll
        for (int z = 0; z < 4; ++z) {
            const unsigned int uu = *(const unsigned int*)(part + (size_t)z * 2359296 + base + idx);
            v0 += bflo(uu);
            v1 += bfhi(uu);
        }
        hs[idx] = v0; hs[idx + 1] = v1;
    }
    __syncthreads();
    for (int gq = t; gq < 768; gq += 256) {           // groups (c, oh-local), squash over ow(6)
        const int c = gq / 3, ohl = gq % 3;
        const int oh = h * 3 + ohl;
        float s[6], sq = 0.f;
#pragma unroll
        for (int ow = 0; ow < 6; ++ow) { s[ow] = hs[(ohl * 6 + ow) * 256 + c]; sq = fmaf(s[ow], s[ow], sq); }
        const float norm = sqrtf(sq);
        const float f = (sq / (1.0f + sq)) / (norm + 1e-7f);
        float* up = u + (size_t)b * 9216 + c * 36 + oh * 6;
#pragma unroll
        for (int ow = 0; ow < 6; ++ow) up[ow] = s[ow] * f;
    }
}

// ---------- u_hat fp8, B-MAJOR layout: uhat8[b][i][40 u32] = e4m3(64 * W_i u_b) ----------
__global__ __launch_bounds__(256) void uhat_k(const float* __restrict__ Wc,
                                              const float* __restrict__ u,
                                              unsigned int* __restrict__ uhat8) {
    const int i = blockIdx.x, t = threadIdx.x;       // t = b
    __shared__ float Wl[1280];                       // [o][d*8+e]
    __shared__ __align__(16) unsigned int Ust[256 * 40];   // 40 KB staging [b][40]
    for (int idx = t; idx < 1280; idx += 256) {
        const int o = idx >> 7, r = idx & 127;
        Wl[idx] = Wc[((size_t)o * 1152 + i) * 128 + r];
    }
    float ur[8];
    *(float4*)&ur[0] = *(const float4*)(u + (size_t)t * 9216 + i * 8);
    *(float4*)&ur[4] = *(const float4*)(u + (size_t)t * 9216 + i * 8 + 4);
    __syncthreads();
    unsigned int* myrow = Ust + t * 40;
#pragma unroll 1
    for (int o = 0; o < 10; ++o) {
        float vals[16];
#pragma unroll
        for (int d = 0; d < 16; ++d) {
            const float* wp = &Wl[o * 128 + d * 8];
            float a = 0.f;
#pragma unroll
            for (int e = 0; e < 8; ++e) a = fmaf(wp[e], ur[e], a);
            vals[d] = a * UHAT_SCALE;
        }
        uint4 pk;
        unsigned int w;
#pragma unroll
        for (int q = 0; q < 4; ++q) {
            w = 0;
            w = __builtin_amdgcn_cvt_pk_fp8_f32(vals[q * 4 + 0], vals[q * 4 + 1], w, false);
            w = __builtin_amdgcn_cvt_pk_fp8_f32(vals[q * 4 + 2], vals[q * 4 + 3], w, true);
            if (q == 0) pk.x = w; else if (q == 1) pk.y = w; else if (q == 2) pk.z = w; else pk.w = w;
        }
        *(uint4*)(myrow + o * 4) = pk;
    }
    __syncthreads();
    // copy-out: unit u2 = b*10 + q -> uhat8[b][i][q*4..q*4+3]
    for (int u2 = t; u2 < 2560; u2 += 256) {
        const int bb = u2 / 10, q = u2 - bb * 10;
        *(uint4*)(uhat8 + (size_t)bb * 46080 + (size_t)i * 40 + q * 4) = *(const uint4*)(Ust + u2 * 4);
    }
}

// ---------- fused routing (3 iters) + final squash/argmax + decoder L1, one block per b ----------
// 256-i chunks (5/pass, tail 128), double-buffered. Tail does final_k's work in-place:
// S2 squash -> lengths (out) + argmax + decoder layer-1 (H1D). Same op order as the old
// final_k -> bit-identical outputs; removes a dispatch and the S2 round-trip.
__global__ __launch_bounds__(512) void route_all_k(const unsigned int* __restrict__ uhat8,
                                                   float* __restrict__ BL,
                                                   const float* __restrict__ w1,
                                                   const float* __restrict__ b1,
                                                   float* __restrict__ out_len,
                                                   float* __restrict__ h1d) {
    const int b = blockIdx.x, t = threadIdx.x;
    __shared__ __align__(16) unsigned int Ul8[2][256 * 40];  // 2 x 40 KB chunk buffers
    __shared__ float Vl[160];                         // v (iters) / v_s (final)
    __shared__ float cT[10 * 264];                    // [o][i_local], stride 264
    __shared__ float dots[2560];                      // p1a out / reduce scratch / len_s
    __shared__ int sel_s;

    // p2 roles: 480 active lanes = 6 k-segments x 2 halves x 40 od-quads
    const int seg = t / 80, rr = t - seg * 80;
    const int hi = rr / 40, th = rr - hi * 40;
    const int oq = th >> 2;
    const bool p2act = (t < 480);
    const int lo = (seg * 64) / 6, hiE = ((seg + 1) * 64) / 6;   // ~10-11 i each
    // p1a roles: 500 active
    const int o = t % 10, sidx = t / 10;

    const unsigned int* ubase = uhat8 + (size_t)b * 46080;   // b-major slab
    auto stage = [&](int buf, int ck, int nI) {
        const unsigned int* ub = ubase + (size_t)ck * 10240;  // 256 rows x 40 u32
        const int units = nI * 10;
        for (int c = t; c < units; c += 512)
            async_cp16(ub + (size_t)c * 4, (char*)Ul8[buf] + c * 16);
    };
#define NI_OF(ck) ((ck) < 4 ? 256 : 128)

    // ---- iteration 0: S0 = (0.1/64) * sum_i dec(uhat) ----
    float a0 = 0.f, a1 = 0.f, a2 = 0.f, a3 = 0.f;
    stage(0, 0, 256);
    __syncthreads();
    for (int ck = 0; ck < 5; ++ck) {
        const int cur = ck & 1;
        const int nI = NI_OF(ck);
        if (ck + 1 < 5) stage(cur ^ 1, ck + 1, NI_OF(ck + 1));
        if (p2act) {
#pragma unroll
            for (int sc = 0; sc < 2; ++sc) {
                if (sc * 128 < nI) {
                    const unsigned int* base = Ul8[cur] + (sc * 128 + hi * 64) * 40 + th;
                    for (int ii = lo; ii < hiE; ++ii) {
                        float f[4];
                        fp8x4_dec(base[ii * 40], f);
                        a0 += f[0]; a1 += f[1]; a2 += f[2]; a3 += f[3];
                    }
                }
            }
        }
        __syncthreads();                              // buf[cur] free + prefetch landed
    }
    if (p2act) {
        const int rb = seg * 320 + hi * 160 + 4 * th;
        dots[rb + 0] = a0; dots[rb + 1] = a1; dots[rb + 2] = a2; dots[rb + 3] = a3;
    }
    __syncthreads();
    if (t < 160) {
        float xv = 0.f;
#pragma unroll
        for (int j = 0; j < 12; ++j) xv += dots[j * 160 + t];
        xv *= 0.1f * UHAT_INV;
        float sq = xv * xv;
        sq += __shfl_xor(sq, 1, 16);
        sq += __shfl_xor(sq, 2, 16);
        sq += __shfl_xor(sq, 4, 16);
        sq += __shfl_xor(sq, 8, 16);
        const float norm = sqrtf(sq);
        const float f = (sq / (1.f + sq)) / (norm + 1e-7f);
        Vl[t] = xv * f;
    }
    __syncthreads();

    // ---- iterations 1 and 2 ----
    for (int it = 1; it <= 2; ++it) {
        float vr[16];
        if (t < 500) {
#pragma unroll
            for (int q = 0; q < 4; ++q)
                *(float4*)&vr[q * 4] = *(const float4*)(&Vl[o * 16 + q * 4]);
        }
        a0 = a1 = a2 = a3 = 0.f;
        stage(0, 0, 256);
        __syncthreads();
        for (int ck = 0; ck < 5; ++ck) {
            const int cur = ck & 1;
            const int nI = NI_OF(ck);
            if (ck + 1 < 5) stage(cur ^ 1, ck + 1, NI_OF(ck + 1));
            // p1a: dots[i][o] = (1/64) * uhat[i,o,:] . v[o,:]  (500 lanes, up to 6 reps)
            if (t < 500) {
#pragma unroll
                for (int rep = 0; rep < 6; ++rep) {
                    const int i = sidx + 50 * rep;
                    if (i < nI) {
                        const uint4 uu = *(const uint4*)(Ul8[cur] + i * 40 + o * 4);
                        float f[16];
                        fp8x4_dec(uu.x, f);
                        fp8x4_dec(uu.y, f + 4);
                        fp8x4_dec(uu.z, f + 8);
                        fp8x4_dec(uu.w, f + 12);
                        float dot = 0.f;
#pragma unroll
                        for (int d = 0; d < 16; ++d) dot = fmaf(f[d], vr[d], dot);
                        dots[i * 10 + o] = dot * UHAT_INV;
                    }
                }
            }
            __syncthreads();
            // p1b: logits + softmax -> cT[o][i_local] (one i per lane, t < nI)
            if (t < nI) {
                float bl[10];
#pragma unroll
                for (int oo = 0; oo < 10; ++oo) bl[oo] = dots[t * 10 + oo];
                const size_t blb = (size_t)b * 11520 + (size_t)ck * 256 + t;
                if (it == 1) {
#pragma unroll
                    for (int oo = 0; oo < 10; ++oo) BL[blb + (size_t)oo * 1152] = bl[oo];
                } else {
#pragma unroll
                    for (int oo = 0; oo < 10; ++oo) bl[oo] += BL[blb + (size_t)oo * 1152];
                }
                float mx = bl[0];
#pragma unroll
                for (int oo = 1; oo < 10; ++oo) mx = fmaxf(mx, bl[oo]);
                float ex[10], sum = 0.f;
#pragma unroll
                for (int oo = 0; oo < 10; ++oo) { ex[oo] = expf(bl[oo] - mx); sum += ex[oo]; }
                const float inv = 1.f / sum;
#pragma unroll
                for (int oo = 0; oo < 10; ++oo) cT[oo * 264 + t] = ex[oo] * inv;
            }
            __syncthreads();
            // p2: accumulate S += c[i][o] * dec(uhat[i][od])
            if (p2act) {
#pragma unroll
                for (int sc = 0; sc < 2; ++sc) {
                    if (sc * 128 < nI) {
                        const unsigned int* base = Ul8[cur] + (sc * 128 + hi * 64) * 40 + th;
                        const float* cb = &cT[oq * 264 + sc * 128 + hi * 64];
                        for (int ii = lo; ii < hiE; ++ii) {
                            const float c = cb[ii];
                            float f[4];
                            fp8x4_dec(base[ii * 40], f);
                            a0 = fmaf(c, f[0], a0);
                            a1 = fmaf(c, f[1], a1);
                            a2 = fmaf(c, f[2], a2);
                            a3 = fmaf(c, f[3], a3);
                        }
                    }
                }
            }
            __syncthreads();
        }
        if (p2act) {
            const int rb = seg * 320 + hi * 160 + 4 * th;
            dots[rb + 0] = a0; dots[rb + 1] = a1; dots[rb + 2] = a2; dots[rb + 3] = a3;
        }
        __syncthreads();
        if (t < 160) {
            float sv = 0.f;
#pragma unroll
            for (int j = 0; j < 12; ++j) sv += dots[j * 160 + t];
            sv *= UHAT_INV;
            float sq = sv * sv;
            sq += __shfl_xor(sq, 1, 16);
            sq += __shfl_xor(sq, 2, 16);
            sq += __shfl_xor(sq, 4, 16);
            sq += __shfl_xor(sq, 8, 16);
            const float norm = sqrtf(sq);
            const float f = (sq / (1.f + sq)) / (norm + 1e-7f);
            Vl[t] = sv * f;                           // v (it=1) or v_s (it=2)
            if (it == 2 && (t & 15) == 0) {
                const float len = f * norm;
                dots[t >> 4] = len;                   // len_s
                out_len[b * 10 + (t >> 4)] = len;
            }
        }
        __syncthreads();
    }
#undef NI_OF

    // ---- fused final: argmax + decoder layer 1 (identical op order to old final_k) ----
    if (t == 0) {
        float best = dots[0]; int bi = 0;
        for (int oo = 1; oo < 10; ++oo) if (dots[oo] > best) { best = dots[oo]; bi = oo; }
        sel_s = bi;
    }
    __syncthreads();
    const int s = sel_s;
    float acc = b1[t];
    const float* wrow = w1 + (size_t)(s * 16) * 512 + t;
#pragma unroll
    for (int j = 0; j < 16; ++j) acc = fmaf(Vl[s * 16 + j], wrow[j * 512], acc);
    h1d[(size_t)b * 512 + t] = fmaxf(acc, 0.f);
}

// ---------- decoder GEMM v3: 8m x 64n tile, per-wave K-split x4, ping-pong float4 B batches ----------
template <int ACT>
__global__ __launch_bounds__(256) void mlp3_k(const float* __restrict__ A,
                                              const float* __restrict__ Bm,
                                              const float* __restrict__ bias,
                                              float* __restrict__ C, int N, int K) {
    extern __shared__ float Asm[];                    // 8*(K+4) floats; tail-reused for reduce
    const int t = threadIdx.x;
    const int m0 = blockIdx.y * 8, n0 = blockIdx.x * 64;
    const int RS = K + 4;
    const int k4 = K >> 2;
    for (int i = t; i < 8 * k4; i += 256) {           // stage A tile, float4 units
        const int r = i / k4, c = i - r * k4;
        *(float4*)&Asm[r * RS + c * 4] = *(const float4*)&A[(size_t)(m0 + r) * K + c * 4];
    }
    __syncthreads();
    const int lane = t & 63, w = t >> 6;
    const int mq = lane >> 4, nq = lane & 15;
    const int n = n0 + nq * 4;
    const int ncl = (n + 3 < N) ? n : (N - 4);        // clamp base col (16B-aligned, safe)
    const float* bp = Bm + ncl;
    const float* asA = &Asm[(mq * 2 + 0) * RS];
    const float* asB = &Asm[(mq * 2 + 1) * RS];
    const int kQ = K >> 2;                            // per-wave chunk (128 or 256)
    const int kBeg = w * kQ;
    const int nBat2 = kQ >> 4;                        // double-batches of 16 k
    float4 acc0 = {0.f, 0.f, 0.f, 0.f}, acc1 = {0.f, 0.f, 0.f, 0.f};
    float4 ba[8], bb[8];
#pragma unroll
    for (int d = 0; d < 8; ++d) ba[d] = *(const float4*)&bp[(size_t)(kBeg + d) * N];

#define MLP3_FMA(BATCH, KB)                                                       \
    _Pragma("unroll")                                                             \
    for (int d = 0; d < 8; ++d) {                                                 \
        const float4 b = BATCH[d];                                                \
        const float a0 = asA[(KB) + d];                                           \
        const float a1 = asB[(KB) + d];                                           \
        acc0.x = fmaf(a0, b.x, acc0.x); acc0.y = fmaf(a0, b.y, acc0.y);           \
        acc0.z = fmaf(a0, b.z, acc0.z); acc0.w = fmaf(a0, b.w, acc0.w);           \
        acc1.x = fmaf(a1, b.x, acc1.x); acc1.y = fmaf(a1, b.y, acc1.y);           \
        acc1.z = fmaf(a1, b.z, acc1.z); acc1.w = fmaf(a1, b.w, acc1.w);           \
    }

    int k = kBeg;
#pragma unroll 1
    for (int it = 0; it < nBat2; ++it) {
#pragma unroll
        for (int d = 0; d < 8; ++d) bb[d] = *(const float4*)&bp[(size_t)(k + 8 + d) * N];
        MLP3_FMA(ba, k)
        if (it + 1 < nBat2) {
#pragma unroll
            for (int d = 0; d < 8; ++d) ba[d] = *(const float4*)&bp[(size_t)(k + 16 + d) * N];
        }
        MLP3_FMA(bb, k + 8)
        k += 16;
    }
#undef MLP3_FMA

    // cross-wave k-quarter reduce via LDS (reuses Asm; 4*64*8 floats = 8 KB)
    __syncthreads();                                  // all waves done reading Asm
    float* red = Asm;
    float* my = &red[(size_t)(w * 64 + lane) * 8];
    my[0] = acc0.x; my[1] = acc0.y; my[2] = acc0.z; my[3] = acc0.w;
    my[4] = acc1.x; my[5] = acc1.y; my[6] = acc1.z; my[7] = acc1.w;
    __syncthreads();
    if (t < 64) {
        float o[8];
#pragma unroll
        for (int x = 0; x < 8; ++x)
            o[x] = red[(size_t)t * 8 + x] + red[(size_t)(64 + t) * 8 + x]
                 + red[(size_t)(128 + t) * 8 + x] + red[(size_t)(192 + t) * 8 + x];
        const int nn = n0 + (t & 15) * 4;
#pragma unroll
        for (int rm = 0; rm < 2; ++rm) {
            const int m = m0 + (t >> 4) * 2 + rm;
#pragma unroll
            for (int rn = 0; rn < 4; ++rn) {
                const int ncol = nn + rn;
                if (ncol < N) {
                    float v = o[rm * 4 + rn] + bias[ncol];
                    if (ACT == 0) v = fmaxf(v, 0.f);
                    else v = 1.f / (1.f + expf(-v));
                    C[(size_t)m * N + ncol] = v;
                }
            }
        }
    }
}

// ---------- launcher ----------
extern "C" void kernel_launch(void* const* d_in, const int* in_sizes, int n_in,
                              void* d_out, int out_size, void* d_ws, size_t ws_size,
                              hipStream_t stream) {
    const float* x   = (const float*)d_in[0];
    const float* w1  = (const float*)d_in[1];
    const float* b1  = (const float*)d_in[2];
    const float* w2  = (const float*)d_in[3];
    const float* b2  = (const float*)d_in[4];
    const float* Wc  = (const float*)d_in[5];
    const float* dw1 = (const float*)d_in[6];
    const float* db1 = (const float*)d_in[7];
    const float* dw2 = (const float*)d_in[8];
    const float* db2 = (const float*)d_in[9];
    const float* dw3 = (const float*)d_in[10];
    const float* db3 = (const float*)d_in[11];
    float* out = (float*)d_out;

    char* ws = (char*)d_ws;
    unsigned char* H1T8 = (unsigned char*)(ws + 0);            // 26,214,400 B fp8
    unsigned char* W2T8 = (unsigned char*)(ws + 26214400);     //  5,308,416 B fp8 (x16)
    unsigned short* PART = (unsigned short*)(ws + 31522816);   // 18,874,368 B bf16, z=4
    unsigned int*   UHAT = (unsigned int*)(ws + 0);            // 47,185,920 B fp8 b-major (aliases dead staging)
    float* U    = (float*)(ws + 50397184);                     //  9,437,184 B (after PART; dead after uhat_k)
    float* BL   = (float*)(ws + 59834368);                     // 11,796,480 B (live within route_all)
    float* H1D  = (float*)(ws + 71630848);                     //    524,288 B (fresh region; BL still live)
    float* H2D  = (float*)(ws + 60358656);                     //  1,048,576 B (dead-BL space, after route_all)

    prep_k<<<1024, 256, 0, stream>>>(x, w1, b1, w2, H1T8, W2T8);
    conv2_k<<<576, 256, 0, stream>>>(H1T8, W2T8, PART);
    squash_u_k<<<512, 256, 0, stream>>>(PART, b2, U);
    uhat_k<<<1152, 256, 0, stream>>>(Wc, U, UHAT);
    route_all_k<<<256, 512, 0, stream>>>(UHAT, BL, dw1, db1, out, H1D);
    mlp3_k<0><<<dim3(16, 32), 256, 8 * 516 * 4, stream>>>(H1D, dw2, db2, H2D, 1024, 512);
    mlp3_k<1><<<dim3(13, 32), 256, 8 * 1028 * 4, stream>>>(H2D, dw3, db3, out + 2560, 784, 1024);
}